// Round 2
// baseline (2080.266 us; speedup 1.0000x reference)
//
#include <hip/hip_runtime.h>

// Problem constants
#define B_   16
#define C_   512     // e_dim
#define HW_  1024    // 32*32
#define N_   16384   // B*H*W
#define K_   8192    // n_e

// Workspace layout (in floats)
#define QC_OFF    0
#define QC_SZ     (K_ * C_)          // 4,194,304
#define QN_OFF    (QC_OFF + QC_SZ)
#define QN_SZ     K_
#define NKB       16                 // k-partials per row
#define PD_OFF    (QN_OFF + QN_SZ)
#define PD_SZ     (NKB * N_)
#define PI_OFF    (PD_OFF + PD_SZ)
#define PI_SZ     (NKB * N_)
#define IDXF_OFF  (PI_OFF + PI_SZ)
#define IDXF_SZ   N_
#define ZN_OFF    (IDXF_OFF + IDXF_SZ)
#define ZN_SZ     N_
#define LOSS_OFF  (ZN_OFF + ZN_SZ)

// Output layout (floats)
#define OUT_ZQ    0
#define OUT_LOSS  8388608
#define OUT_IDX   8388609

// ---------------------------------------------------------------------------
// Kernel A: qc[k,c] = sum_d emb[k,d] * W[c,d] + b[c]   (8192x512, K=512)
// 64x64 tile, 256 threads, 4x4 per thread, fp32. Accumulation is a single
// sequential-FMA chain over d=0..511 per output element (matches BLAS
// microkernel per-element k-sequential accumulation).
// ---------------------------------------------------------------------------
__global__ __launch_bounds__(256) void qc_gemm(const float* __restrict__ emb,
                                               const float* __restrict__ W,
                                               const float* __restrict__ bias,
                                               float* __restrict__ qc) {
    __shared__ float As[16][64];   // [d_local][k_local]
    __shared__ float Bs[16][64];   // [d_local][c_local]
    const int t  = threadIdx.x;
    const int k0 = blockIdx.x * 64;
    const int c0 = blockIdx.y * 64;
    const int ty = t >> 4, tx = t & 15;
    const int rl = t >> 2;          // 0..63 (row for loads)
    const int go = (t & 3) * 4;     // d-offset 0/4/8/12

    float acc[4][4] = {};
    for (int d0 = 0; d0 < 512; d0 += 16) {
        float4 a = *(const float4*)&emb[(size_t)(k0 + rl) * 512 + d0 + go];
        float4 b = *(const float4*)&W  [(size_t)(c0 + rl) * 512 + d0 + go];
        __syncthreads();
        As[go + 0][rl] = a.x; As[go + 1][rl] = a.y; As[go + 2][rl] = a.z; As[go + 3][rl] = a.w;
        Bs[go + 0][rl] = b.x; Bs[go + 1][rl] = b.y; Bs[go + 2][rl] = b.z; Bs[go + 3][rl] = b.w;
        __syncthreads();
#pragma unroll
        for (int dd = 0; dd < 16; ++dd) {
            float4 av = *(const float4*)&As[dd][ty * 4];
            float4 bv = *(const float4*)&Bs[dd][tx * 4];
            float aa[4] = {av.x, av.y, av.z, av.w};
            float bb[4] = {bv.x, bv.y, bv.z, bv.w};
#pragma unroll
            for (int i = 0; i < 4; ++i)
#pragma unroll
                for (int j = 0; j < 4; ++j)
                    acc[i][j] += aa[i] * bb[j];   // fma chain, d ascending
        }
    }
#pragma unroll
    for (int i = 0; i < 4; ++i)
#pragma unroll
        for (int j = 0; j < 4; ++j)
            qc[(size_t)(k0 + ty * 4 + i) * 512 + c0 + tx * 4 + j] =
                acc[i][j] + bias[c0 + tx * 4 + j];
}

// ---------------------------------------------------------------------------
// Kernel Zn: zn[n] = ||z_flat[n]||^2 with numpy pairwise-summation structure:
//   S512 = (S128_0 + S128_1) + (S128_2 + S128_3)
//   S128 = 8 accumulators r[j] over a[8i+j], combined
//          ((r0+r1)+(r2+r3)) + ((r4+r5)+(r6+r7))
// Squares are rounded BEFORE adding (contract off) to match numpy's
// materialized z**2 followed by np.sum.
// ---------------------------------------------------------------------------
__global__ __launch_bounds__(256) void znorm_pairwise(const float* __restrict__ z,
                                                      float* __restrict__ zn) {
#pragma clang fp contract(off)
    const int n = blockIdx.x * 256 + threadIdx.x;
    const int b = n >> 10, m = n & 1023;
    const float* base = z + (size_t)b * C_ * HW_ + m;
    float s128[4];
#pragma unroll
    for (int blk = 0; blk < 4; ++blk) {
        float r[8];
#pragma unroll
        for (int j = 0; j < 8; ++j) {
            float v = base[(size_t)(blk * 128 + j) * HW_];
            r[j] = v * v;
        }
#pragma unroll 1
        for (int i = 8; i < 128; i += 8) {
#pragma unroll
            for (int j = 0; j < 8; ++j) {
                float v = base[(size_t)(blk * 128 + i + j) * HW_];
                float sq = v * v;
                r[j] = r[j] + sq;
            }
        }
        s128[blk] = ((r[0] + r[1]) + (r[2] + r[3])) + ((r[4] + r[5]) + (r[6] + r[7]));
    }
    zn[n] = (s128[0] + s128[1]) + (s128[2] + s128[3]);
}

// ---------------------------------------------------------------------------
// Kernel Qn: qn[k] = ||qc[k]||^2, same numpy pairwise structure (row contiguous)
// ---------------------------------------------------------------------------
__global__ __launch_bounds__(256) void qnorm_pairwise(const float* __restrict__ qc,
                                                      float* __restrict__ qn) {
#pragma clang fp contract(off)
    const int k = blockIdx.x * 256 + threadIdx.x;
    const float* row = qc + (size_t)k * C_;
    float s128[4];
#pragma unroll
    for (int blk = 0; blk < 4; ++blk) {
        float r[8];
#pragma unroll
        for (int j = 0; j < 8; ++j) {
            float v = row[blk * 128 + j];
            r[j] = v * v;
        }
#pragma unroll 1
        for (int i = 8; i < 128; i += 8) {
#pragma unroll
            for (int j = 0; j < 8; ++j) {
                float v = row[blk * 128 + i + j];
                float sq = v * v;
                r[j] = r[j] + sq;
            }
        }
        s128[blk] = ((r[0] + r[1]) + (r[2] + r[3])) + ((r[4] + r[5]) + (r[6] + r[7]));
    }
    qn[k] = (s128[0] + s128[1]) + (s128[2] + s128[3]);
}

// ---------------------------------------------------------------------------
// Kernel P1: per 64-row z tile x 512-code chunk: d = fl(fl(zn + qn) - 2*dot),
// keep per-row argmin (first-min tie-break) -> partials.
// ---------------------------------------------------------------------------
__global__ __launch_bounds__(256) void dist_argmin(const float* __restrict__ z,
                                                   const float* __restrict__ qc,
                                                   const float* __restrict__ qn,
                                                   const float* __restrict__ zn,
                                                   float* __restrict__ pdist,
                                                   int* __restrict__ pidx) {
    __shared__ float As[16][64];   // [c_local][n_local]
    __shared__ float Bs[16][64];   // [c_local][k_local]
    const int t  = threadIdx.x;
    const int n0 = blockIdx.x * 64;
    const int bb = n0 >> 10;
    const int m0 = n0 & 1023;
    const float* zbase = z + (size_t)bb * C_ * HW_ + m0;
    const int ty = t >> 4, tx = t & 15;
    const int rl = t >> 2;            // B-load row (k_local)
    const int go = (t & 3) * 4;       // B-load c offset
    const int cl = t >> 4;            // A-load c row
    const int no = (t & 15) * 4;      // A-load n offset

    float zn_r[4];
#pragma unroll
    for (int i = 0; i < 4; ++i) zn_r[i] = zn[n0 + ty * 4 + i];

    float best_d[4];
    int   best_i[4];
#pragma unroll
    for (int i = 0; i < 4; ++i) { best_d[i] = 1e30f; best_i[i] = 0; }

    for (int kt = 0; kt < 8; ++kt) {
        const int k0 = blockIdx.y * 512 + kt * 64;
        float acc[4][4] = {};
        for (int c0 = 0; c0 < 512; c0 += 16) {
            float4 a  = *(const float4*)&zbase[(size_t)(c0 + cl) * HW_ + no];
            float4 bq = *(const float4*)&qc[(size_t)(k0 + rl) * 512 + c0 + go];
            __syncthreads();
            *(float4*)&As[cl][no] = a;
            Bs[go + 0][rl] = bq.x; Bs[go + 1][rl] = bq.y;
            Bs[go + 2][rl] = bq.z; Bs[go + 3][rl] = bq.w;
            __syncthreads();
#pragma unroll
            for (int dd = 0; dd < 16; ++dd) {
                float4 av = *(const float4*)&As[dd][ty * 4];
                float4 bv = *(const float4*)&Bs[dd][tx * 4];
                float aa[4] = {av.x, av.y, av.z, av.w};
                float bb2[4] = {bv.x, bv.y, bv.z, bv.w};
#pragma unroll
                for (int i = 0; i < 4; ++i)
#pragma unroll
                    for (int j = 0; j < 4; ++j)
                        acc[i][j] += aa[i] * bb2[j];   // fma chain, c ascending
            }
        }
        // epilogue: d = fl(fl(zn + qn) - 2*acc); per-row min over 64-col tile
#pragma unroll
        for (int i = 0; i < 4; ++i) {
            float dmin = 1e30f;
            int   imin = 0;
#pragma unroll
            for (int j = 0; j < 4; ++j) {
                int   k = k0 + tx * 4 + j;
                float T = zn_r[i] + qn[k];          // fp32 add at ~512 scale (replicates ref)
                float d = T - 2.0f * acc[i][j];     // 2*acc exact; single rounding
                if (d < dmin) { dmin = d; imin = k; }   // ascending j keeps earliest on tie
            }
#pragma unroll
            for (int m = 1; m <= 8; m <<= 1) {
                float od = __shfl_xor(dmin, m, 64);
                int   oi = __shfl_xor(imin, m, 64);
                if (od < dmin || (od == dmin && oi < imin)) { dmin = od; imin = oi; }
            }
            if (dmin < best_d[i] || (dmin == best_d[i] && imin < best_i[i])) {
                best_d[i] = dmin; best_i[i] = imin;
            }
        }
    }
    if (tx == 0) {
#pragma unroll
        for (int i = 0; i < 4; ++i) {
            pdist[(size_t)blockIdx.y * N_ + n0 + ty * 4 + i] = best_d[i];
            pidx [(size_t)blockIdx.y * N_ + n0 + ty * 4 + i] = best_i[i];
        }
    }
}

// ---------------------------------------------------------------------------
// Kernel P2: reduce NKB partials per row -> final index; write index output.
// ---------------------------------------------------------------------------
__global__ __launch_bounds__(256) void reduce_idx(const float* __restrict__ pdist,
                                                  const int* __restrict__ pidx,
                                                  int* __restrict__ idxf,
                                                  float* __restrict__ out_idx) {
    const int n = blockIdx.x * 256 + threadIdx.x;
    float bd = pdist[n];
    int   bi = pidx[n];
#pragma unroll
    for (int kb = 1; kb < NKB; ++kb) {
        float d  = pdist[(size_t)kb * N_ + n];
        int   ii = pidx [(size_t)kb * N_ + n];
        if (d < bd || (d == bd && ii < bi)) { bd = d; bi = ii; }
    }
    idxf[n]    = bi;
    out_idx[n] = (float)bi;
}

// ---------------------------------------------------------------------------
// Kernel G: gather z_q = qc[idx], transpose-write to [B,C,H,W], fused loss.
// ---------------------------------------------------------------------------
__global__ __launch_bounds__(256) void gather_out(const float* __restrict__ z,
                                                  const float* __restrict__ qc,
                                                  const int* __restrict__ idxf,
                                                  float* __restrict__ zq_out,
                                                  float* __restrict__ loss_acc) {
    __shared__ int   idxs[64];
    __shared__ float zqs[64][65];   // [m_local][c_local], pad 65 -> conflict-free
    __shared__ float wsum[4];
    const int t  = threadIdx.x;
    const int mc = blockIdx.x;   // 0..15  (64 m's)
    const int cc = blockIdx.y;   // 0..7   (64 c's)
    const int bz = blockIdx.z;   // batch

    if (t < 64) idxs[t] = idxf[bz * 1024 + mc * 64 + t];
    __syncthreads();

    {   // load 64 codebook rows (64 c's each) into LDS
        const int row  = t >> 2;
        const int coff = (t & 3) * 16;
        const float* src = qc + (size_t)idxs[row] * 512 + cc * 64 + coff;
#pragma unroll
        for (int v = 0; v < 4; ++v) {
            float4 q = *(const float4*)&src[v * 4];
            zqs[row][coff + v * 4 + 0] = q.x;
            zqs[row][coff + v * 4 + 1] = q.y;
            zqs[row][coff + v * 4 + 2] = q.z;
            zqs[row][coff + v * 4 + 3] = q.w;
        }
    }
    __syncthreads();

    float ls = 0.f;
    {   // transpose out of LDS; coalesced global write; fused loss
        const int c_local = t >> 2;
        const int mg      = (t & 3) * 16;
        const size_t gbase = ((size_t)(bz * 512 + cc * 64 + c_local)) * 1024 + mc * 64 + mg;
#pragma unroll
        for (int v = 0; v < 4; ++v) {
            const int m = mg + v * 4;
            float4 w;
            w.x = zqs[m + 0][c_local];
            w.y = zqs[m + 1][c_local];
            w.z = zqs[m + 2][c_local];
            w.w = zqs[m + 3][c_local];
            float4 zv = *(const float4*)&z[gbase + v * 4];
            float dx = w.x - zv.x, dy = w.y - zv.y, dz = w.z - zv.z, dw = w.w - zv.w;
            ls += dx * dx + dy * dy + dz * dz + dw * dw;
            *(float4*)&zq_out[gbase + v * 4] = w;
        }
    }
#pragma unroll
    for (int m = 32; m; m >>= 1) ls += __shfl_xor(ls, m, 64);
    const int lane = t & 63, wv = t >> 6;
    if (lane == 0) wsum[wv] = ls;
    __syncthreads();
    if (t == 0) atomicAdd(loss_acc, wsum[0] + wsum[1] + wsum[2] + wsum[3]);
}

__global__ void zero_loss(float* __restrict__ loss_acc) { loss_acc[0] = 0.f; }

__global__ void finalize(const float* __restrict__ loss_acc,
                         float* __restrict__ out_loss) {
    out_loss[0] = 1.25f * loss_acc[0] / 8388608.0f;
}

// ---------------------------------------------------------------------------
extern "C" void kernel_launch(void* const* d_in, const int* in_sizes, int n_in,
                              void* d_out, int out_size, void* d_ws, size_t ws_size,
                              hipStream_t stream) {
    const float* z    = (const float*)d_in[0];
    const float* emb  = (const float*)d_in[1];
    const float* W    = (const float*)d_in[2];
    const float* bias = (const float*)d_in[3];
    float* ws = (float*)d_ws;

    float* qc       = ws + QC_OFF;
    float* qn       = ws + QN_OFF;
    float* pdist    = ws + PD_OFF;
    int*   pidx     = (int*)(ws + PI_OFF);
    int*   idxf     = (int*)(ws + IDXF_OFF);
    float* zn       = ws + ZN_OFF;
    float* loss_acc = ws + LOSS_OFF;
    float* out      = (float*)d_out;

    zero_loss<<<1, 1, 0, stream>>>(loss_acc);
    qc_gemm<<<dim3(K_ / 64, C_ / 64), 256, 0, stream>>>(emb, W, bias, qc);
    znorm_pairwise<<<N_ / 256, 256, 0, stream>>>(z, zn);
    qnorm_pairwise<<<K_ / 256, 256, 0, stream>>>(qc, qn);
    dist_argmin<<<dim3(N_ / 64, NKB), 256, 0, stream>>>(z, qc, qn, zn, pdist, pidx);
    reduce_idx<<<N_ / 256, 256, 0, stream>>>(pdist, pidx, idxf, out + OUT_IDX);
    gather_out<<<dim3(16, 8, B_), 256, 0, stream>>>(z, qc, idxf, out + OUT_ZQ, loss_acc);
    finalize<<<1, 1, 0, stream>>>(loss_acc, out + OUT_LOSS);
}

// Round 3
// 708.482 us; speedup vs baseline: 2.9362x; 2.9362x over previous
//
#include <hip/hip_runtime.h>

typedef unsigned int uint;
typedef unsigned short ushort;
typedef __attribute__((ext_vector_type(8))) short short8;
typedef __attribute__((ext_vector_type(4))) float f32x4;

// Problem constants
#define B_   16
#define C_   512     // e_dim
#define HW_  1024    // 32*32
#define N_   16384   // B*H*W
#define K_   8192    // n_e
#define EPS_ 0.25f   // candidate margin (|d~ - d| <~ 0.05 @10sigma; 2*delta << EPS)

// Workspace layout (in float units)
#define QC_OFF    0u
#define QC_SZ     (K_ * C_)            // 4,194,304
#define QN_OFF    (QC_OFF + QC_SZ)
#define QN_SZ     K_
#define ZN_OFF    (QN_OFF + QN_SZ)
#define ZN_SZ     N_
#define ZF_OFF    (ZN_OFF + ZN_SZ)     // z_flat f32 [N][C]
#define ZF_SZ     (N_ * C_)            // 8,388,608
#define ZH_OFF    (ZF_OFF + ZF_SZ)     // z bf16 [N][C] (2 per float)
#define ZH_SZ     (N_ * C_ / 2)
#define QH_OFF    (ZH_OFF + ZH_SZ)     // qc bf16 [K][C]
#define QH_SZ     (K_ * C_ / 2)
#define WT_OFF    (QH_OFF + QH_SZ)     // wtop [64 windows][N] float4 {v1,k1,v2,k2}
#define WT_SZ     (64 * N_ * 4)
#define CK_OFF    (WT_OFF + WT_SZ)     // cand_k [N][16] int
#define CK_SZ     (N_ * 16)
#define CC_OFF    (CK_OFF + CK_SZ)     // cand_cnt [N]
#define CC_SZ     N_
#define IDXF_OFF  (CC_OFF + CC_SZ)
#define IDXF_SZ   N_
#define LOSS_OFF  (IDXF_OFF + IDXF_SZ)

// Output layout (floats)
#define OUT_ZQ    0
#define OUT_LOSS  8388608
#define OUT_IDX   8388609

__device__ __forceinline__ ushort f2bf(float f) {   // RNE f32 -> bf16 (finite data)
    uint x = __float_as_uint(f);
    uint r = x + 0x7fffu + ((x >> 16) & 1u);
    return (ushort)(r >> 16);
}

// ---------------------------------------------------------------------------
// Transpose: z [B][C][HW] f32 -> z_flat [N][C] f32 (exact copy) + zh bf16
// ---------------------------------------------------------------------------
__global__ __launch_bounds__(256) void transpose_z(const float* __restrict__ z,
                                                   float* __restrict__ zf,
                                                   ushort* __restrict__ zh) {
    __shared__ float ld[64][65];
    const int t = threadIdx.x;
    const int mt = blockIdx.x, ct = blockIdx.y, b = blockIdx.z;
    {
        const int cl = t >> 4, m4 = (t & 15) * 4;
#pragma unroll
        for (int cc = 0; cc < 4; ++cc) {
            const int c = ct * 64 + cc * 16 + cl;
            float4 v = *(const float4*)&z[((size_t)(b * 512 + c)) * 1024 + mt * 64 + m4];
            ld[cc * 16 + cl][m4 + 0] = v.x; ld[cc * 16 + cl][m4 + 1] = v.y;
            ld[cc * 16 + cl][m4 + 2] = v.z; ld[cc * 16 + cl][m4 + 3] = v.w;
        }
    }
    __syncthreads();
    {
        const int nl = t >> 4, c4 = (t & 15) * 4;
#pragma unroll
        for (int nn = 0; nn < 4; ++nn) {
            const int n_local = nn * 16 + nl;
            const size_t n = (size_t)b * 1024 + mt * 64 + n_local;
            float4 w;
            w.x = ld[c4 + 0][n_local]; w.y = ld[c4 + 1][n_local];
            w.z = ld[c4 + 2][n_local]; w.w = ld[c4 + 3][n_local];
            *(float4*)&zf[n * 512 + ct * 64 + c4] = w;
            ushort4 h; h.x = f2bf(w.x); h.y = f2bf(w.y); h.z = f2bf(w.z); h.w = f2bf(w.w);
            *(ushort4*)&zh[n * 512 + ct * 64 + c4] = h;
        }
    }
}

// ---------------------------------------------------------------------------
// qc GEMM (UNCHANGED math from passing round-2 kernel): sequential-FMA chain.
// ---------------------------------------------------------------------------
__global__ __launch_bounds__(256) void qc_gemm(const float* __restrict__ emb,
                                               const float* __restrict__ W,
                                               const float* __restrict__ bias,
                                               float* __restrict__ qc) {
    __shared__ float As[16][64];
    __shared__ float Bs[16][64];
    const int t  = threadIdx.x;
    const int k0 = blockIdx.x * 64;
    const int c0 = blockIdx.y * 64;
    const int ty = t >> 4, tx = t & 15;
    const int rl = t >> 2;
    const int go = (t & 3) * 4;

    float acc[4][4] = {};
    for (int d0 = 0; d0 < 512; d0 += 16) {
        float4 a = *(const float4*)&emb[(size_t)(k0 + rl) * 512 + d0 + go];
        float4 b = *(const float4*)&W  [(size_t)(c0 + rl) * 512 + d0 + go];
        __syncthreads();
        As[go + 0][rl] = a.x; As[go + 1][rl] = a.y; As[go + 2][rl] = a.z; As[go + 3][rl] = a.w;
        Bs[go + 0][rl] = b.x; Bs[go + 1][rl] = b.y; Bs[go + 2][rl] = b.z; Bs[go + 3][rl] = b.w;
        __syncthreads();
#pragma unroll
        for (int dd = 0; dd < 16; ++dd) {
            float4 av = *(const float4*)&As[dd][ty * 4];
            float4 bv = *(const float4*)&Bs[dd][tx * 4];
            float aa[4] = {av.x, av.y, av.z, av.w};
            float bb[4] = {bv.x, bv.y, bv.z, bv.w};
#pragma unroll
            for (int i = 0; i < 4; ++i)
#pragma unroll
                for (int j = 0; j < 4; ++j)
                    acc[i][j] += aa[i] * bb[j];
        }
    }
#pragma unroll
    for (int i = 0; i < 4; ++i)
#pragma unroll
        for (int j = 0; j < 4; ++j)
            qc[(size_t)(k0 + ty * 4 + i) * 512 + c0 + tx * 4 + j] =
                acc[i][j] + bias[c0 + tx * 4 + j];
}

// qc f32 -> qh bf16
__global__ __launch_bounds__(256) void qh_conv(const float* __restrict__ qc,
                                               ushort* __restrict__ qh) {
    const size_t i = ((size_t)blockIdx.x * 256 + threadIdx.x) * 4;
    float4 v = *(const float4*)&qc[i];
    ushort4 h; h.x = f2bf(v.x); h.y = f2bf(v.y); h.z = f2bf(v.z); h.w = f2bf(v.w);
    *(ushort4*)&qh[i] = h;
}

// ---------------------------------------------------------------------------
// Row norms, numpy pairwise structure (UNCHANGED rounding from round 2).
// ---------------------------------------------------------------------------
__device__ __forceinline__ float pairwise512(const float* __restrict__ row) {
#pragma clang fp contract(off)
    float s128[4];
#pragma unroll
    for (int blk = 0; blk < 4; ++blk) {
        float r[8];
#pragma unroll
        for (int j = 0; j < 8; ++j) { float v = row[blk * 128 + j]; r[j] = v * v; }
#pragma unroll 1
        for (int i = 8; i < 128; i += 8) {
#pragma unroll
            for (int j = 0; j < 8; ++j) {
                float v = row[blk * 128 + i + j];
                float sq = v * v;
                r[j] = r[j] + sq;
            }
        }
        s128[blk] = ((r[0] + r[1]) + (r[2] + r[3])) + ((r[4] + r[5]) + (r[6] + r[7]));
    }
    return (s128[0] + s128[1]) + (s128[2] + s128[3]);
}

__global__ __launch_bounds__(256) void qnorm_pairwise(const float* __restrict__ qc,
                                                      float* __restrict__ qn) {
    const int k = blockIdx.x * 256 + threadIdx.x;
    qn[k] = pairwise512(qc + (size_t)k * C_);
}

__global__ __launch_bounds__(256) void znorm_pairwise(const float* __restrict__ zf,
                                                      float* __restrict__ zn) {
    const int n = blockIdx.x * 256 + threadIdx.x;
    zn[n] = pairwise512(zf + (size_t)n * C_);
}

// ---------------------------------------------------------------------------
// Phase A: MFMA bf16 distance tiles, top-2 per (row n, 128-code window).
// A = qh (codes, MFMA rows), B = zh (pixels, MFMA cols), both [.][c] bf16.
// d~[k][n] = qn[k] - 2 * sum_c qh[k][c]*zh[n][c]
// ---------------------------------------------------------------------------
__global__ __launch_bounds__(256) void phaseA(const ushort* __restrict__ qh,
                                              const ushort* __restrict__ zh,
                                              const float* __restrict__ qn,
                                              float* __restrict__ wtop) {
    __shared__ short lq[128 * 64];   // [k_local][c 64] bf16
    __shared__ short lz[128 * 64];   // [n_local][c 64] bf16
    const int t    = threadIdx.x;
    const int lane = t & 63;
    const int wv   = t >> 6;
    const int wk   = wv >> 1, wn = wv & 1;
    const int n0   = blockIdx.x * 128;
    const int k0   = blockIdx.y * 128;

    f32x4 acc[4][4];
#pragma unroll
    for (int i = 0; i < 4; ++i)
#pragma unroll
        for (int j = 0; j < 4; ++j) acc[i][j] = (f32x4){0.f, 0.f, 0.f, 0.f};

    for (int c0 = 0; c0 < 512; c0 += 64) {
#pragma unroll
        for (int p = 0; p < 4; ++p) {
            const int ch  = t + p * 256;            // 0..1023 16B-chunks
            const int row = ch >> 3;
            const int c8  = (ch & 7) * 8;
            __builtin_amdgcn_global_load_lds(
                (const __attribute__((address_space(1))) uint*)(qh + (size_t)(k0 + row) * 512 + c0 + c8),
                (__attribute__((address_space(3))) uint*)&lq[ch * 8], 16, 0, 0);
            __builtin_amdgcn_global_load_lds(
                (const __attribute__((address_space(1))) uint*)(zh + (size_t)(n0 + row) * 512 + c0 + c8),
                (__attribute__((address_space(3))) uint*)&lz[ch * 8], 16, 0, 0);
        }
        __syncthreads();
#pragma unroll
        for (int kk = 0; kk < 64; kk += 32) {
            const int co = kk + ((lane >> 4) << 3);
            short8 af[4], bf[4];
#pragma unroll
            for (int i = 0; i < 4; ++i) {
                af[i] = *(const short8*)&lq[(wk * 64 + i * 16 + (lane & 15)) * 64 + co];
                bf[i] = *(const short8*)&lz[(wn * 64 + i * 16 + (lane & 15)) * 64 + co];
            }
#pragma unroll
            for (int i = 0; i < 4; ++i)
#pragma unroll
                for (int j = 0; j < 4; ++j)
                    acc[i][j] = __builtin_amdgcn_mfma_f32_16x16x32_bf16(af[i], bf[j], acc[i][j], 0, 0, 0);
        }
        __syncthreads();
    }

    // Epilogue: per n-column top-2 over this wave's 64 k's
    const int q4 = (lane >> 4) * 4;
    float qv[4][4];
#pragma unroll
    for (int ik = 0; ik < 4; ++ik)
#pragma unroll
        for (int r = 0; r < 4; ++r)
            qv[ik][r] = qn[k0 + wk * 64 + ik * 16 + q4 + r];

    float v1[4], v2[4];
    int   k1[4], k2[4];
#pragma unroll
    for (int in = 0; in < 4; ++in) {
        v1[in] = 1e30f; v2[in] = 1e30f; k1[in] = 0; k2[in] = 0;
#pragma unroll
        for (int ik = 0; ik < 4; ++ik) {
#pragma unroll
            for (int r = 0; r < 4; ++r) {
                const float val = qv[ik][r] - 2.0f * acc[ik][in][r];
                const int   kg  = k0 + wk * 64 + ik * 16 + q4 + r;
                if (val < v1[in]) { v2[in] = v1[in]; k2[in] = k1[in]; v1[in] = val; k1[in] = kg; }
                else if (val < v2[in]) { v2[in] = val; k2[in] = kg; }
            }
        }
    }
    // butterfly across the 4 k-subgroups (lane>>4)
#pragma unroll
    for (int m = 16; m <= 32; m <<= 1) {
#pragma unroll
        for (int in = 0; in < 4; ++in) {
            const float ov1 = __shfl_xor(v1[in], m, 64);
            const int   ok1 = __shfl_xor(k1[in], m, 64);
            const float ov2 = __shfl_xor(v2[in], m, 64);
            const int   ok2 = __shfl_xor(k2[in], m, 64);
            float nv1, nv2; int nk1, nk2;
            if (ov1 < v1[in]) {
                nv1 = ov1; nk1 = ok1;
                if (v1[in] < ov2) { nv2 = v1[in]; nk2 = k1[in]; } else { nv2 = ov2; nk2 = ok2; }
            } else {
                nv1 = v1[in]; nk1 = k1[in];
                if (ov1 < v2[in]) { nv2 = ov1; nk2 = ok1; } else { nv2 = v2[in]; nk2 = k2[in]; }
            }
            v1[in] = nv1; k1[in] = nk1; v2[in] = nv2; k2[in] = nk2;
        }
    }
    // cross-wave (wk) merge through LDS
    float* sb = (float*)lq;   // 2 * 128 * 4 floats
    if ((lane >> 4) == 0) {
#pragma unroll
        for (int in = 0; in < 4; ++in) {
            const int n_local = wn * 64 + in * 16 + (lane & 15);
            float* sp = sb + (wk * 128 + n_local) * 4;
            sp[0] = v1[in]; sp[1] = __int_as_float(k1[in]);
            sp[2] = v2[in]; sp[3] = __int_as_float(k2[in]);
        }
    }
    __syncthreads();
    if (t < 128) {
        float4 A  = *(float4*)&sb[t * 4];
        float4 Bv = *(float4*)&sb[(128 + t) * 4];
        float r1, r2; int rk1, rk2;
        if (Bv.x < A.x) {
            r1 = Bv.x; rk1 = __float_as_int(Bv.y);
            if (A.x < Bv.z) { r2 = A.x; rk2 = __float_as_int(A.y); }
            else            { r2 = Bv.z; rk2 = __float_as_int(Bv.w); }
        } else {
            r1 = A.x; rk1 = __float_as_int(A.y);
            if (Bv.x < A.z) { r2 = Bv.x; rk2 = __float_as_int(Bv.y); }
            else            { r2 = A.z; rk2 = __float_as_int(A.w); }
        }
        float4 o; o.x = r1; o.y = __int_as_float(rk1); o.z = r2; o.w = __int_as_float(rk2);
        *(float4*)&wtop[((size_t)blockIdx.y * N_ + n0 + t) * 4] = o;
    }
}

// ---------------------------------------------------------------------------
// Phase B: rowmin over windows; collect candidates within EPS of rowmin.
// ---------------------------------------------------------------------------
__global__ __launch_bounds__(256) void phaseB(const float* __restrict__ wtop,
                                              int* __restrict__ cand_k,
                                              int* __restrict__ cand_cnt) {
    const int n = blockIdx.x * 256 + threadIdx.x;
    float rmin = 1e30f;
    for (int w = 0; w < 64; ++w)
        rmin = fminf(rmin, wtop[((size_t)w * N_ + n) * 4]);
    const float thr = rmin + EPS_;
    int cnt = 0;
    for (int w = 0; w < 64; ++w) {
        float4 e = *(const float4*)&wtop[((size_t)w * N_ + n) * 4];
        if (e.x <= thr && cnt < 16) cand_k[n * 16 + cnt++] = __float_as_int(e.y);
        if (e.z <= thr && cnt < 16) cand_k[n * 16 + cnt++] = __float_as_int(e.w);
    }
    cand_cnt[n] = cnt;
}

// ---------------------------------------------------------------------------
// Phase C: exact recheck. Sequential-FMA chain identical (bit-for-bit) to the
// round-2 passing kernel's accumulation: single accumulator, c ascending.
// ---------------------------------------------------------------------------
__global__ __launch_bounds__(256) void phaseC(const float* __restrict__ zf,
                                              const float* __restrict__ qc,
                                              const float* __restrict__ zn,
                                              const float* __restrict__ qn,
                                              const int* __restrict__ cand_k,
                                              const int* __restrict__ cand_cnt,
                                              int* __restrict__ idxf,
                                              float* __restrict__ out_idx) {
    __shared__ float zr[4][512];
    const int wv   = threadIdx.x >> 6;
    const int lane = threadIdx.x & 63;
    const int r    = blockIdx.x * 4 + wv;
    *(float4*)&zr[wv][lane * 8]     = *(const float4*)&zf[(size_t)r * 512 + lane * 8];
    *(float4*)&zr[wv][lane * 8 + 4] = *(const float4*)&zf[(size_t)r * 512 + lane * 8 + 4];
    __syncthreads();
    const int cnt = cand_cnt[r];
    const float znr = zn[r];
    float bd = 1e30f;
    int   bi = 0x7fffffff;
    for (int ci = 0; ci < cnt; ++ci) {
        const int k = cand_k[r * 16 + ci];
        const float* q = qc + (size_t)k * 512;
        float acc = 0.f;
#pragma unroll 8
        for (int c = 0; c < 512; ++c)
            acc = fmaf(zr[wv][c], q[c], acc);
        const float T = znr + qn[k];
        const float d = T - 2.0f * acc;
        if (d < bd || (d == bd && k < bi)) { bd = d; bi = k; }
    }
    if (lane == 0) { idxf[r] = bi; out_idx[r] = (float)bi; }
}

// ---------------------------------------------------------------------------
// Gather z_q = qc[idx], transpose-write to [B,C,H,W], fused loss. (unchanged)
// ---------------------------------------------------------------------------
__global__ __launch_bounds__(256) void gather_out(const float* __restrict__ z,
                                                  const float* __restrict__ qc,
                                                  const int* __restrict__ idxf,
                                                  float* __restrict__ zq_out,
                                                  float* __restrict__ loss_acc) {
    __shared__ int   idxs[64];
    __shared__ float zqs[64][65];
    __shared__ float wsum[4];
    const int t  = threadIdx.x;
    const int mc = blockIdx.x;
    const int cc = blockIdx.y;
    const int bz = blockIdx.z;

    if (t < 64) idxs[t] = idxf[bz * 1024 + mc * 64 + t];
    __syncthreads();
    {
        const int row  = t >> 2;
        const int coff = (t & 3) * 16;
        const float* src = qc + (size_t)idxs[row] * 512 + cc * 64 + coff;
#pragma unroll
        for (int v = 0; v < 4; ++v) {
            float4 q = *(const float4*)&src[v * 4];
            zqs[row][coff + v * 4 + 0] = q.x;
            zqs[row][coff + v * 4 + 1] = q.y;
            zqs[row][coff + v * 4 + 2] = q.z;
            zqs[row][coff + v * 4 + 3] = q.w;
        }
    }
    __syncthreads();

    float ls = 0.f;
    {
        const int c_local = t >> 2;
        const int mg      = (t & 3) * 16;
        const size_t gbase = ((size_t)(bz * 512 + cc * 64 + c_local)) * 1024 + mc * 64 + mg;
#pragma unroll
        for (int v = 0; v < 4; ++v) {
            const int m = mg + v * 4;
            float4 w;
            w.x = zqs[m + 0][c_local];
            w.y = zqs[m + 1][c_local];
            w.z = zqs[m + 2][c_local];
            w.w = zqs[m + 3][c_local];
            float4 zv = *(const float4*)&z[gbase + v * 4];
            float dx = w.x - zv.x, dy = w.y - zv.y, dz = w.z - zv.z, dw = w.w - zv.w;
            ls += dx * dx + dy * dy + dz * dz + dw * dw;
            *(float4*)&zq_out[gbase + v * 4] = w;
        }
    }
#pragma unroll
    for (int m = 32; m; m >>= 1) ls += __shfl_xor(ls, m, 64);
    const int lane = t & 63, wvv = t >> 6;
    if (lane == 0) wsum[wvv] = ls;
    __syncthreads();
    if (t == 0) atomicAdd(loss_acc, wsum[0] + wsum[1] + wsum[2] + wsum[3]);
}

__global__ void zero_loss(float* __restrict__ loss_acc) { loss_acc[0] = 0.f; }

__global__ void finalize(const float* __restrict__ loss_acc,
                         float* __restrict__ out_loss) {
    out_loss[0] = 1.25f * loss_acc[0] / 8388608.0f;
}

// ---------------------------------------------------------------------------
extern "C" void kernel_launch(void* const* d_in, const int* in_sizes, int n_in,
                              void* d_out, int out_size, void* d_ws, size_t ws_size,
                              hipStream_t stream) {
    const float* z    = (const float*)d_in[0];
    const float* emb  = (const float*)d_in[1];
    const float* W    = (const float*)d_in[2];
    const float* bias = (const float*)d_in[3];
    float* ws = (float*)d_ws;

    float*  qc       = ws + QC_OFF;
    float*  qn       = ws + QN_OFF;
    float*  zn       = ws + ZN_OFF;
    float*  zf       = ws + ZF_OFF;
    ushort* zh       = (ushort*)(ws + ZH_OFF);
    ushort* qh       = (ushort*)(ws + QH_OFF);
    float*  wtop     = ws + WT_OFF;
    int*    cand_k   = (int*)(ws + CK_OFF);
    int*    cand_cnt = (int*)(ws + CC_OFF);
    int*    idxf     = (int*)(ws + IDXF_OFF);
    float*  loss_acc = ws + LOSS_OFF;
    float*  out      = (float*)d_out;

    zero_loss<<<1, 1, 0, stream>>>(loss_acc);
    transpose_z<<<dim3(16, 8, 16), 256, 0, stream>>>(z, zf, zh);
    qc_gemm<<<dim3(K_ / 64, C_ / 64), 256, 0, stream>>>(emb, W, bias, qc);
    qh_conv<<<(K_ * C_) / 1024, 256, 0, stream>>>(qc, qh);
    qnorm_pairwise<<<K_ / 256, 256, 0, stream>>>(qc, qn);
    znorm_pairwise<<<N_ / 256, 256, 0, stream>>>(zf, zn);
    phaseA<<<dim3(N_ / 128, K_ / 128), 256, 0, stream>>>(qh, zh, qn, wtop);
    phaseB<<<N_ / 256, 256, 0, stream>>>(wtop, cand_k, cand_cnt);
    phaseC<<<N_ / 4, 256, 0, stream>>>(zf, qc, zn, qn, cand_k, cand_cnt, idxf, out + OUT_IDX);
    gather_out<<<dim3(16, 8, B_), 256, 0, stream>>>(z, qc, idxf, out + OUT_ZQ, loss_acc);
    finalize<<<1, 1, 0, stream>>>(loss_acc, out + OUT_LOSS);
}

// Round 4
// 670.670 us; speedup vs baseline: 3.1018x; 1.0564x over previous
//
#include <hip/hip_runtime.h>

typedef unsigned int uint;
typedef unsigned short ushort;
typedef __attribute__((ext_vector_type(8))) short short8;
typedef __attribute__((ext_vector_type(4))) float f32x4;

// Problem constants
#define B_   16
#define C_   512     // e_dim
#define HW_  1024    // 32*32
#define N_   16384   // B*H*W
#define K_   8192    // n_e
#define EPS_ 0.25f   // candidate margin (|d~ - d| <~ 0.05 @10sigma; 2*delta << EPS)

// Workspace layout (in float units)
#define QC_OFF    0u
#define QC_SZ     (K_ * C_)            // 4,194,304
#define QN_OFF    (QC_OFF + QC_SZ)
#define QN_SZ     K_
#define ZN_OFF    (QN_OFF + QN_SZ)
#define ZN_SZ     N_
#define ZF_OFF    (ZN_OFF + ZN_SZ)     // z_flat f32 [N][C]
#define ZF_SZ     (N_ * C_)            // 8,388,608
#define ZH_OFF    (ZF_OFF + ZF_SZ)     // z bf16 [N][C] (2 per float)
#define ZH_SZ     (N_ * C_ / 2)
#define QH_OFF    (ZH_OFF + ZH_SZ)     // qc bf16 [K][C]
#define QH_SZ     (K_ * C_ / 2)
#define WT_OFF    (QH_OFF + QH_SZ)     // wtop [64 windows][N] float4 {v1,k1,v2,k2}
#define WT_SZ     (64 * N_ * 4)
#define CK_OFF    (WT_OFF + WT_SZ)     // cand_k [N][16] int
#define CK_SZ     (N_ * 16)
#define CC_OFF    (CK_OFF + CK_SZ)     // cand_cnt [N]
#define CC_SZ     N_
#define IDXF_OFF  (CC_OFF + CC_SZ)
#define IDXF_SZ   N_
#define LOSS_OFF  (IDXF_OFF + IDXF_SZ)

// Output layout (floats)
#define OUT_ZQ    0
#define OUT_LOSS  8388608
#define OUT_IDX   8388609

__device__ __forceinline__ ushort f2bf(float f) {   // RNE f32 -> bf16 (finite data)
    uint x = __float_as_uint(f);
    uint r = x + 0x7fffu + ((x >> 16) & 1u);
    return (ushort)(r >> 16);
}

// ---------------------------------------------------------------------------
// Transpose: z [B][C][HW] f32 -> z_flat [N][C] f32 (exact copy) + zh bf16
// ---------------------------------------------------------------------------
__global__ __launch_bounds__(256) void transpose_z(const float* __restrict__ z,
                                                   float* __restrict__ zf,
                                                   ushort* __restrict__ zh) {
    __shared__ float ld[64][65];
    const int t = threadIdx.x;
    const int mt = blockIdx.x, ct = blockIdx.y, b = blockIdx.z;
    {
        const int cl = t >> 4, m4 = (t & 15) * 4;
#pragma unroll
        for (int cc = 0; cc < 4; ++cc) {
            const int c = ct * 64 + cc * 16 + cl;
            float4 v = *(const float4*)&z[((size_t)(b * 512 + c)) * 1024 + mt * 64 + m4];
            ld[cc * 16 + cl][m4 + 0] = v.x; ld[cc * 16 + cl][m4 + 1] = v.y;
            ld[cc * 16 + cl][m4 + 2] = v.z; ld[cc * 16 + cl][m4 + 3] = v.w;
        }
    }
    __syncthreads();
    {
        const int nl = t >> 4, c4 = (t & 15) * 4;
#pragma unroll
        for (int nn = 0; nn < 4; ++nn) {
            const int n_local = nn * 16 + nl;
            const size_t n = (size_t)b * 1024 + mt * 64 + n_local;
            float4 w;
            w.x = ld[c4 + 0][n_local]; w.y = ld[c4 + 1][n_local];
            w.z = ld[c4 + 2][n_local]; w.w = ld[c4 + 3][n_local];
            *(float4*)&zf[n * 512 + ct * 64 + c4] = w;
            ushort4 h; h.x = f2bf(w.x); h.y = f2bf(w.y); h.z = f2bf(w.z); h.w = f2bf(w.w);
            *(ushort4*)&zh[n * 512 + ct * 64 + c4] = h;
        }
    }
}

// ---------------------------------------------------------------------------
// qc GEMM v2: 128x128 tile, 8x8 per thread (split 4+4 at +64 to keep LDS
// reads 2-way-conflict-free). Per-element math IDENTICAL to the passing
// round-2/3 kernel: single accumulator, d ascending, FMA chain. Fused qh
// (bf16) output.
// ---------------------------------------------------------------------------
__global__ __launch_bounds__(256) void qc_gemm(const float* __restrict__ emb,
                                               const float* __restrict__ W,
                                               const float* __restrict__ bias,
                                               float* __restrict__ qc,
                                               ushort* __restrict__ qh) {
    __shared__ float As[16][132];   // [d_local][k_local], pad 132
    __shared__ float Bs[16][132];   // [d_local][c_local]
    const int t   = threadIdx.x;
    const int k0  = blockIdx.x * 128;
    const int c0  = blockIdx.y * 128;
    const int ty  = t >> 4, tx = t & 15;
    const int row = t >> 1;          // 0..127 (staging row)
    const int dq  = (t & 1) * 8;     // staging d-offset 0/8

    const float* pa = emb + (size_t)(k0 + row) * 512 + dq;
    const float* pb = W   + (size_t)(c0 + row) * 512 + dq;
    float4 ra0 = *(const float4*)&pa[0];
    float4 ra1 = *(const float4*)&pa[4];
    float4 rb0 = *(const float4*)&pb[0];
    float4 rb1 = *(const float4*)&pb[4];

    float acc[2][2][4][4] = {};   // [ih][jh][i][j]
    for (int d0 = 0; d0 < 512; d0 += 16) {
        __syncthreads();
        As[dq + 0][row] = ra0.x; As[dq + 1][row] = ra0.y;
        As[dq + 2][row] = ra0.z; As[dq + 3][row] = ra0.w;
        As[dq + 4][row] = ra1.x; As[dq + 5][row] = ra1.y;
        As[dq + 6][row] = ra1.z; As[dq + 7][row] = ra1.w;
        Bs[dq + 0][row] = rb0.x; Bs[dq + 1][row] = rb0.y;
        Bs[dq + 2][row] = rb0.z; Bs[dq + 3][row] = rb0.w;
        Bs[dq + 4][row] = rb1.x; Bs[dq + 5][row] = rb1.y;
        Bs[dq + 6][row] = rb1.z; Bs[dq + 7][row] = rb1.w;
        if (d0 + 16 < 512) {   // issue next-tile loads early; consumed next iter
            ra0 = *(const float4*)&pa[d0 + 16];
            ra1 = *(const float4*)&pa[d0 + 20];
            rb0 = *(const float4*)&pb[d0 + 16];
            rb1 = *(const float4*)&pb[d0 + 20];
        }
        __syncthreads();
#pragma unroll
        for (int dd = 0; dd < 16; ++dd) {
            float4 a0 = *(const float4*)&As[dd][ty * 4];
            float4 a1 = *(const float4*)&As[dd][64 + ty * 4];
            float4 b0 = *(const float4*)&Bs[dd][tx * 4];
            float4 b1 = *(const float4*)&Bs[dd][64 + tx * 4];
            float aa[2][4] = {{a0.x, a0.y, a0.z, a0.w}, {a1.x, a1.y, a1.z, a1.w}};
            float bb[2][4] = {{b0.x, b0.y, b0.z, b0.w}, {b1.x, b1.y, b1.z, b1.w}};
#pragma unroll
            for (int ih = 0; ih < 2; ++ih)
#pragma unroll
                for (int jh = 0; jh < 2; ++jh)
#pragma unroll
                    for (int i = 0; i < 4; ++i)
#pragma unroll
                        for (int j = 0; j < 4; ++j)
                            acc[ih][jh][i][j] += aa[ih][i] * bb[jh][j];  // fma, d asc
        }
    }
#pragma unroll
    for (int ih = 0; ih < 2; ++ih)
#pragma unroll
        for (int i = 0; i < 4; ++i) {
            const size_t kr = (size_t)(k0 + ih * 64 + ty * 4 + i) * 512;
#pragma unroll
            for (int jh = 0; jh < 2; ++jh) {
                const int cb = c0 + jh * 64 + tx * 4;
                float4 v;
                v.x = acc[ih][jh][i][0] + bias[cb + 0];
                v.y = acc[ih][jh][i][1] + bias[cb + 1];
                v.z = acc[ih][jh][i][2] + bias[cb + 2];
                v.w = acc[ih][jh][i][3] + bias[cb + 3];
                *(float4*)&qc[kr + cb] = v;
                ushort4 h; h.x = f2bf(v.x); h.y = f2bf(v.y); h.z = f2bf(v.z); h.w = f2bf(v.w);
                *(ushort4*)&qh[kr + cb] = h;
            }
        }
}

// ---------------------------------------------------------------------------
// Row norms, numpy pairwise structure (UNCHANGED rounding).
// ---------------------------------------------------------------------------
__device__ __forceinline__ float pairwise512(const float* __restrict__ row) {
#pragma clang fp contract(off)
    float s128[4];
#pragma unroll
    for (int blk = 0; blk < 4; ++blk) {
        float r[8];
#pragma unroll
        for (int j = 0; j < 8; ++j) { float v = row[blk * 128 + j]; r[j] = v * v; }
#pragma unroll 1
        for (int i = 8; i < 128; i += 8) {
#pragma unroll
            for (int j = 0; j < 8; ++j) {
                float v = row[blk * 128 + i + j];
                float sq = v * v;
                r[j] = r[j] + sq;
            }
        }
        s128[blk] = ((r[0] + r[1]) + (r[2] + r[3])) + ((r[4] + r[5]) + (r[6] + r[7]));
    }
    return (s128[0] + s128[1]) + (s128[2] + s128[3]);
}

__global__ __launch_bounds__(256) void qnorm_pairwise(const float* __restrict__ qc,
                                                      float* __restrict__ qn) {
    const int k = blockIdx.x * 256 + threadIdx.x;
    qn[k] = pairwise512(qc + (size_t)k * C_);
}

__global__ __launch_bounds__(256) void znorm_pairwise(const float* __restrict__ zf,
                                                      float* __restrict__ zn) {
    const int n = blockIdx.x * 256 + threadIdx.x;
    zn[n] = pairwise512(zf + (size_t)n * C_);
}

// ---------------------------------------------------------------------------
// Phase A: MFMA bf16 distance tiles, top-2 per (row n, 128-code window).
// LDS tiles use a st-style XOR swizzle: LDS stays linear for global_load_lds;
// the global SOURCE chunk is permuted (chunk ^ (row&7)) and the ds_read
// applies the same XOR -> 16-way bank conflict becomes 2-way (free).
// ---------------------------------------------------------------------------
__global__ __launch_bounds__(256) void phaseA(const ushort* __restrict__ qh,
                                              const ushort* __restrict__ zh,
                                              const float* __restrict__ qn,
                                              float* __restrict__ wtop) {
    __shared__ short lq[128 * 64];   // [k_local][c 64] bf16, swizzled
    __shared__ short lz[128 * 64];   // [n_local][c 64] bf16, swizzled
    const int t    = threadIdx.x;
    const int lane = t & 63;
    const int wv   = t >> 6;
    const int wk   = wv >> 1, wn = wv & 1;
    const int n0   = blockIdx.x * 128;
    const int k0   = blockIdx.y * 128;

    f32x4 acc[4][4];
#pragma unroll
    for (int i = 0; i < 4; ++i)
#pragma unroll
        for (int j = 0; j < 4; ++j) acc[i][j] = (f32x4){0.f, 0.f, 0.f, 0.f};

    for (int c0 = 0; c0 < 512; c0 += 64) {
#pragma unroll
        for (int p = 0; p < 4; ++p) {
            const int ch  = t + p * 256;            // LDS 16B-chunk index
            const int row = ch >> 3;
            const int cs  = ((ch ^ row) & 7) * 8;   // swizzled SOURCE elem offset
            __builtin_amdgcn_global_load_lds(
                (const __attribute__((address_space(1))) uint*)(qh + (size_t)(k0 + row) * 512 + c0 + cs),
                (__attribute__((address_space(3))) uint*)&lq[ch * 8], 16, 0, 0);
            __builtin_amdgcn_global_load_lds(
                (const __attribute__((address_space(1))) uint*)(zh + (size_t)(n0 + row) * 512 + c0 + cs),
                (__attribute__((address_space(3))) uint*)&lz[ch * 8], 16, 0, 0);
        }
        __syncthreads();
#pragma unroll
        for (int kk = 0; kk < 64; kk += 32) {
            const int co = kk + ((lane >> 4) << 3);   // logical elem offset
            short8 af[4], bf[4];
#pragma unroll
            for (int i = 0; i < 4; ++i) {
                const int rA = wk * 64 + i * 16 + (lane & 15);
                const int rB = wn * 64 + i * 16 + (lane & 15);
                af[i] = *(const short8*)&lq[rA * 64 + (co ^ ((rA & 7) << 3))];
                bf[i] = *(const short8*)&lz[rB * 64 + (co ^ ((rB & 7) << 3))];
            }
#pragma unroll
            for (int i = 0; i < 4; ++i)
#pragma unroll
                for (int j = 0; j < 4; ++j)
                    acc[i][j] = __builtin_amdgcn_mfma_f32_16x16x32_bf16(af[i], bf[j], acc[i][j], 0, 0, 0);
        }
        __syncthreads();
    }

    // Epilogue: per n-column top-2 over this wave's 64 k's
    const int q4 = (lane >> 4) * 4;
    float qv[4][4];
#pragma unroll
    for (int ik = 0; ik < 4; ++ik)
#pragma unroll
        for (int r = 0; r < 4; ++r)
            qv[ik][r] = qn[k0 + wk * 64 + ik * 16 + q4 + r];

    float v1[4], v2[4];
    int   k1[4], k2[4];
#pragma unroll
    for (int in = 0; in < 4; ++in) {
        v1[in] = 1e30f; v2[in] = 1e30f; k1[in] = 0; k2[in] = 0;
#pragma unroll
        for (int ik = 0; ik < 4; ++ik) {
#pragma unroll
            for (int r = 0; r < 4; ++r) {
                const float val = qv[ik][r] - 2.0f * acc[ik][in][r];
                const int   kg  = k0 + wk * 64 + ik * 16 + q4 + r;
                if (val < v1[in]) { v2[in] = v1[in]; k2[in] = k1[in]; v1[in] = val; k1[in] = kg; }
                else if (val < v2[in]) { v2[in] = val; k2[in] = kg; }
            }
        }
    }
    // butterfly across the 4 k-subgroups (lane>>4)
#pragma unroll
    for (int m = 16; m <= 32; m <<= 1) {
#pragma unroll
        for (int in = 0; in < 4; ++in) {
            const float ov1 = __shfl_xor(v1[in], m, 64);
            const int   ok1 = __shfl_xor(k1[in], m, 64);
            const float ov2 = __shfl_xor(v2[in], m, 64);
            const int   ok2 = __shfl_xor(k2[in], m, 64);
            float nv1, nv2; int nk1, nk2;
            if (ov1 < v1[in]) {
                nv1 = ov1; nk1 = ok1;
                if (v1[in] < ov2) { nv2 = v1[in]; nk2 = k1[in]; } else { nv2 = ov2; nk2 = ok2; }
            } else {
                nv1 = v1[in]; nk1 = k1[in];
                if (ov1 < v2[in]) { nv2 = ov1; nk2 = ok1; } else { nv2 = v2[in]; nk2 = k2[in]; }
            }
            v1[in] = nv1; k1[in] = nk1; v2[in] = nv2; k2[in] = nk2;
        }
    }
    // cross-wave (wk) merge through LDS
    float* sb = (float*)lq;
    if ((lane >> 4) == 0) {
#pragma unroll
        for (int in = 0; in < 4; ++in) {
            const int n_local = wn * 64 + in * 16 + (lane & 15);
            float* sp = sb + (wk * 128 + n_local) * 4;
            sp[0] = v1[in]; sp[1] = __int_as_float(k1[in]);
            sp[2] = v2[in]; sp[3] = __int_as_float(k2[in]);
        }
    }
    __syncthreads();
    if (t < 128) {
        float4 A  = *(float4*)&sb[t * 4];
        float4 Bv = *(float4*)&sb[(128 + t) * 4];
        float r1, r2; int rk1, rk2;
        if (Bv.x < A.x) {
            r1 = Bv.x; rk1 = __float_as_int(Bv.y);
            if (A.x < Bv.z) { r2 = A.x; rk2 = __float_as_int(A.y); }
            else            { r2 = Bv.z; rk2 = __float_as_int(Bv.w); }
        } else {
            r1 = A.x; rk1 = __float_as_int(A.y);
            if (Bv.x < A.z) { r2 = Bv.x; rk2 = __float_as_int(Bv.y); }
            else            { r2 = A.z; rk2 = __float_as_int(A.w); }
        }
        float4 o; o.x = r1; o.y = __int_as_float(rk1); o.z = r2; o.w = __int_as_float(rk2);
        *(float4*)&wtop[((size_t)blockIdx.y * N_ + n0 + t) * 4] = o;
    }
}

// ---------------------------------------------------------------------------
// Phase B: rowmin over windows; collect candidates within EPS of rowmin.
// ---------------------------------------------------------------------------
__global__ __launch_bounds__(256) void phaseB(const float* __restrict__ wtop,
                                              int* __restrict__ cand_k,
                                              int* __restrict__ cand_cnt) {
    const int n = blockIdx.x * 256 + threadIdx.x;
    float rmin = 1e30f;
    for (int w = 0; w < 64; ++w)
        rmin = fminf(rmin, wtop[((size_t)w * N_ + n) * 4]);
    const float thr = rmin + EPS_;
    int cnt = 0;
    for (int w = 0; w < 64; ++w) {
        float4 e = *(const float4*)&wtop[((size_t)w * N_ + n) * 4];
        if (e.x <= thr && cnt < 16) cand_k[n * 16 + cnt++] = __float_as_int(e.y);
        if (e.z <= thr && cnt < 16) cand_k[n * 16 + cnt++] = __float_as_int(e.w);
    }
    cand_cnt[n] = cnt;
}

// ---------------------------------------------------------------------------
// Phase C: exact recheck. Sequential-FMA chain identical (bit-for-bit) to the
// round-2 passing kernel's accumulation.
// ---------------------------------------------------------------------------
__global__ __launch_bounds__(256) void phaseC(const float* __restrict__ zf,
                                              const float* __restrict__ qc,
                                              const float* __restrict__ zn,
                                              const float* __restrict__ qn,
                                              const int* __restrict__ cand_k,
                                              const int* __restrict__ cand_cnt,
                                              int* __restrict__ idxf,
                                              float* __restrict__ out_idx) {
    __shared__ float zr[4][512];
    const int wv   = threadIdx.x >> 6;
    const int lane = threadIdx.x & 63;
    const int r    = blockIdx.x * 4 + wv;
    *(float4*)&zr[wv][lane * 8]     = *(const float4*)&zf[(size_t)r * 512 + lane * 8];
    *(float4*)&zr[wv][lane * 8 + 4] = *(const float4*)&zf[(size_t)r * 512 + lane * 8 + 4];
    __syncthreads();
    const int cnt = cand_cnt[r];
    const float znr = zn[r];
    float bd = 1e30f;
    int   bi = 0x7fffffff;
    for (int ci = 0; ci < cnt; ++ci) {
        const int k = cand_k[r * 16 + ci];
        const float* q = qc + (size_t)k * 512;
        float acc = 0.f;
#pragma unroll 8
        for (int c = 0; c < 512; ++c)
            acc = fmaf(zr[wv][c], q[c], acc);
        const float T = znr + qn[k];
        const float d = T - 2.0f * acc;
        if (d < bd || (d == bd && k < bi)) { bd = d; bi = k; }
    }
    if (lane == 0) { idxf[r] = bi; out_idx[r] = (float)bi; }
}

// ---------------------------------------------------------------------------
// Gather z_q = qc[idx], transpose-write to [B,C,H,W], fused loss.
// ---------------------------------------------------------------------------
__global__ __launch_bounds__(256) void gather_out(const float* __restrict__ z,
                                                  const float* __restrict__ qc,
                                                  const int* __restrict__ idxf,
                                                  float* __restrict__ zq_out,
                                                  float* __restrict__ loss_acc) {
    __shared__ int   idxs[64];
    __shared__ float zqs[64][65];
    __shared__ float wsum[4];
    const int t  = threadIdx.x;
    const int mc = blockIdx.x;
    const int cc = blockIdx.y;
    const int bz = blockIdx.z;

    if (t < 64) idxs[t] = idxf[bz * 1024 + mc * 64 + t];
    __syncthreads();
    {
        const int row  = t >> 2;
        const int coff = (t & 3) * 16;
        const float* src = qc + (size_t)idxs[row] * 512 + cc * 64 + coff;
#pragma unroll
        for (int v = 0; v < 4; ++v) {
            float4 q = *(const float4*)&src[v * 4];
            zqs[row][coff + v * 4 + 0] = q.x;
            zqs[row][coff + v * 4 + 1] = q.y;
            zqs[row][coff + v * 4 + 2] = q.z;
            zqs[row][coff + v * 4 + 3] = q.w;
        }
    }
    __syncthreads();

    float ls = 0.f;
    {
        const int c_local = t >> 2;
        const int mg      = (t & 3) * 16;
        const size_t gbase = ((size_t)(bz * 512 + cc * 64 + c_local)) * 1024 + mc * 64 + mg;
#pragma unroll
        for (int v = 0; v < 4; ++v) {
            const int m = mg + v * 4;
            float4 w;
            w.x = zqs[m + 0][c_local];
            w.y = zqs[m + 1][c_local];
            w.z = zqs[m + 2][c_local];
            w.w = zqs[m + 3][c_local];
            float4 zv = *(const float4*)&z[gbase + v * 4];
            float dx = w.x - zv.x, dy = w.y - zv.y, dz = w.z - zv.z, dw = w.w - zv.w;
            ls += dx * dx + dy * dy + dz * dz + dw * dw;
            *(float4*)&zq_out[gbase + v * 4] = w;
        }
    }
#pragma unroll
    for (int m = 32; m; m >>= 1) ls += __shfl_xor(ls, m, 64);
    const int lane = t & 63, wvv = t >> 6;
    if (lane == 0) wsum[wvv] = ls;
    __syncthreads();
    if (t == 0) atomicAdd(loss_acc, wsum[0] + wsum[1] + wsum[2] + wsum[3]);
}

__global__ void zero_loss(float* __restrict__ loss_acc) { loss_acc[0] = 0.f; }

__global__ void finalize(const float* __restrict__ loss_acc,
                         float* __restrict__ out_loss) {
    out_loss[0] = 1.25f * loss_acc[0] / 8388608.0f;
}

// ---------------------------------------------------------------------------
extern "C" void kernel_launch(void* const* d_in, const int* in_sizes, int n_in,
                              void* d_out, int out_size, void* d_ws, size_t ws_size,
                              hipStream_t stream) {
    const float* z    = (const float*)d_in[0];
    const float* emb  = (const float*)d_in[1];
    const float* W    = (const float*)d_in[2];
    const float* bias = (const float*)d_in[3];
    float* ws = (float*)d_ws;

    float*  qc       = ws + QC_OFF;
    float*  qn       = ws + QN_OFF;
    float*  zn       = ws + ZN_OFF;
    float*  zf       = ws + ZF_OFF;
    ushort* zh       = (ushort*)(ws + ZH_OFF);
    ushort* qh       = (ushort*)(ws + QH_OFF);
    float*  wtop     = ws + WT_OFF;
    int*    cand_k   = (int*)(ws + CK_OFF);
    int*    cand_cnt = (int*)(ws + CC_OFF);
    int*    idxf     = (int*)(ws + IDXF_OFF);
    float*  loss_acc = ws + LOSS_OFF;
    float*  out      = (float*)d_out;

    zero_loss<<<1, 1, 0, stream>>>(loss_acc);
    transpose_z<<<dim3(16, 8, 16), 256, 0, stream>>>(z, zf, zh);
    qc_gemm<<<dim3(K_ / 128, C_ / 128), 256, 0, stream>>>(emb, W, bias, qc, qh);
    qnorm_pairwise<<<K_ / 256, 256, 0, stream>>>(qc, qn);
    znorm_pairwise<<<N_ / 256, 256, 0, stream>>>(zf, zn);
    phaseA<<<dim3(N_ / 128, K_ / 128), 256, 0, stream>>>(qh, zh, qn, wtop);
    phaseB<<<N_ / 256, 256, 0, stream>>>(wtop, cand_k, cand_cnt);
    phaseC<<<N_ / 4, 256, 0, stream>>>(zf, qc, zn, qn, cand_k, cand_cnt, idxf, out + OUT_IDX);
    gather_out<<<dim3(16, 8, B_), 256, 0, stream>>>(z, qc, idxf, out + OUT_ZQ, loss_acc);
    finalize<<<1, 1, 0, stream>>>(loss_acc, out + OUT_LOSS);
}

// Round 5
// 643.606 us; speedup vs baseline: 3.2322x; 1.0421x over previous
//
#include <hip/hip_runtime.h>

typedef unsigned int uint;
typedef unsigned short ushort;
typedef __attribute__((ext_vector_type(8))) short short8;
typedef __attribute__((ext_vector_type(4))) float f32x4;

// Problem constants
#define B_   16
#define C_   512     // e_dim
#define HW_  1024    // 32*32
#define N_   16384   // B*H*W
#define K_   8192    // n_e
#define EPS_ 0.25f   // candidate margin (|d~ - d| <~ 0.05 @10sigma; 2*delta << EPS)

// Workspace layout (in float units)
#define QC_OFF    0u
#define QC_SZ     (K_ * C_)            // 4,194,304
#define QN_OFF    (QC_OFF + QC_SZ)
#define QN_SZ     K_
#define ZN_OFF    (QN_OFF + QN_SZ)
#define ZN_SZ     N_
#define ZF_OFF    (ZN_OFF + ZN_SZ)     // z_flat f32 [N][C]
#define ZF_SZ     (N_ * C_)            // 8,388,608
#define ZH_OFF    (ZF_OFF + ZF_SZ)     // z bf16 [N][C] (2 per float)
#define ZH_SZ     (N_ * C_ / 2)
#define QH_OFF    (ZH_OFF + ZH_SZ)     // qc bf16 [K][C]
#define QH_SZ     (K_ * C_ / 2)
#define WT_OFF    (QH_OFF + QH_SZ)     // wtop [64 windows][N] float4 {v1,k1,v2,k2}
#define WT_SZ     (64 * N_ * 4)
#define CK_OFF    (WT_OFF + WT_SZ)     // cand_k [N][16] int
#define CK_SZ     (N_ * 16)
#define CC_OFF    (CK_OFF + CK_SZ)     // cand_cnt [N]
#define CC_SZ     N_
#define IDXF_OFF  (CC_OFF + CC_SZ)
#define IDXF_SZ   N_
#define LOSS_OFF  (IDXF_OFF + IDXF_SZ)

// Output layout (floats)
#define OUT_ZQ    0
#define OUT_LOSS  8388608
#define OUT_IDX   8388609

__device__ __forceinline__ ushort f2bf(float f) {   // RNE f32 -> bf16 (finite data)
    uint x = __float_as_uint(f);
    uint r = x + 0x7fffu + ((x >> 16) & 1u);
    return (ushort)(r >> 16);
}

// ---------------------------------------------------------------------------
// Transpose: z [B][C][HW] f32 -> z_flat [N][C] f32 (exact copy) + zh bf16
// ---------------------------------------------------------------------------
__global__ __launch_bounds__(256) void transpose_z(const float* __restrict__ z,
                                                   float* __restrict__ zf,
                                                   ushort* __restrict__ zh) {
    __shared__ float ld[64][65];
    const int t = threadIdx.x;
    const int mt = blockIdx.x, ct = blockIdx.y, b = blockIdx.z;
    {
        const int cl = t >> 4, m4 = (t & 15) * 4;
#pragma unroll
        for (int cc = 0; cc < 4; ++cc) {
            const int c = ct * 64 + cc * 16 + cl;
            float4 v = *(const float4*)&z[((size_t)(b * 512 + c)) * 1024 + mt * 64 + m4];
            ld[cc * 16 + cl][m4 + 0] = v.x; ld[cc * 16 + cl][m4 + 1] = v.y;
            ld[cc * 16 + cl][m4 + 2] = v.z; ld[cc * 16 + cl][m4 + 3] = v.w;
        }
    }
    __syncthreads();
    {
        const int nl = t >> 4, c4 = (t & 15) * 4;
#pragma unroll
        for (int nn = 0; nn < 4; ++nn) {
            const int n_local = nn * 16 + nl;
            const size_t n = (size_t)b * 1024 + mt * 64 + n_local;
            float4 w;
            w.x = ld[c4 + 0][n_local]; w.y = ld[c4 + 1][n_local];
            w.z = ld[c4 + 2][n_local]; w.w = ld[c4 + 3][n_local];
            *(float4*)&zf[n * 512 + ct * 64 + c4] = w;
            ushort4 h; h.x = f2bf(w.x); h.y = f2bf(w.y); h.z = f2bf(w.z); h.w = f2bf(w.w);
            *(ushort4*)&zh[n * 512 + ct * 64 + c4] = h;
        }
    }
}

// ---------------------------------------------------------------------------
// qc GEMM: 128x128 tile, 8x8 per thread. Per-element math IDENTICAL to the
// passing kernels: single accumulator, d ascending, FMA chain. Fused qh.
// ---------------------------------------------------------------------------
__global__ __launch_bounds__(256) void qc_gemm(const float* __restrict__ emb,
                                               const float* __restrict__ W,
                                               const float* __restrict__ bias,
                                               float* __restrict__ qc,
                                               ushort* __restrict__ qh) {
    __shared__ float As[16][132];   // [d_local][k_local], pad 132
    __shared__ float Bs[16][132];   // [d_local][c_local]
    const int t   = threadIdx.x;
    const int k0  = blockIdx.x * 128;
    const int c0  = blockIdx.y * 128;
    const int ty  = t >> 4, tx = t & 15;
    const int row = t >> 1;          // 0..127 (staging row)
    const int dq  = (t & 1) * 8;     // staging d-offset 0/8

    const float* pa = emb + (size_t)(k0 + row) * 512 + dq;
    const float* pb = W   + (size_t)(c0 + row) * 512 + dq;
    float4 ra0 = *(const float4*)&pa[0];
    float4 ra1 = *(const float4*)&pa[4];
    float4 rb0 = *(const float4*)&pb[0];
    float4 rb1 = *(const float4*)&pb[4];

    float acc[2][2][4][4] = {};   // [ih][jh][i][j]
    for (int d0 = 0; d0 < 512; d0 += 16) {
        __syncthreads();
        As[dq + 0][row] = ra0.x; As[dq + 1][row] = ra0.y;
        As[dq + 2][row] = ra0.z; As[dq + 3][row] = ra0.w;
        As[dq + 4][row] = ra1.x; As[dq + 5][row] = ra1.y;
        As[dq + 6][row] = ra1.z; As[dq + 7][row] = ra1.w;
        Bs[dq + 0][row] = rb0.x; Bs[dq + 1][row] = rb0.y;
        Bs[dq + 2][row] = rb0.z; Bs[dq + 3][row] = rb0.w;
        Bs[dq + 4][row] = rb1.x; Bs[dq + 5][row] = rb1.y;
        Bs[dq + 6][row] = rb1.z; Bs[dq + 7][row] = rb1.w;
        if (d0 + 16 < 512) {   // issue next-tile loads early; consumed next iter
            ra0 = *(const float4*)&pa[d0 + 16];
            ra1 = *(const float4*)&pa[d0 + 20];
            rb0 = *(const float4*)&pb[d0 + 16];
            rb1 = *(const float4*)&pb[d0 + 20];
        }
        __syncthreads();
#pragma unroll
        for (int dd = 0; dd < 16; ++dd) {
            float4 a0 = *(const float4*)&As[dd][ty * 4];
            float4 a1 = *(const float4*)&As[dd][64 + ty * 4];
            float4 b0 = *(const float4*)&Bs[dd][tx * 4];
            float4 b1 = *(const float4*)&Bs[dd][64 + tx * 4];
            float aa[2][4] = {{a0.x, a0.y, a0.z, a0.w}, {a1.x, a1.y, a1.z, a1.w}};
            float bb[2][4] = {{b0.x, b0.y, b0.z, b0.w}, {b1.x, b1.y, b1.z, b1.w}};
#pragma unroll
            for (int ih = 0; ih < 2; ++ih)
#pragma unroll
                for (int jh = 0; jh < 2; ++jh)
#pragma unroll
                    for (int i = 0; i < 4; ++i)
#pragma unroll
                        for (int j = 0; j < 4; ++j)
                            acc[ih][jh][i][j] += aa[ih][i] * bb[jh][j];  // fma, d asc
        }
    }
#pragma unroll
    for (int ih = 0; ih < 2; ++ih)
#pragma unroll
        for (int i = 0; i < 4; ++i) {
            const size_t kr = (size_t)(k0 + ih * 64 + ty * 4 + i) * 512;
#pragma unroll
            for (int jh = 0; jh < 2; ++jh) {
                const int cb = c0 + jh * 64 + tx * 4;
                float4 v;
                v.x = acc[ih][jh][i][0] + bias[cb + 0];
                v.y = acc[ih][jh][i][1] + bias[cb + 1];
                v.z = acc[ih][jh][i][2] + bias[cb + 2];
                v.w = acc[ih][jh][i][3] + bias[cb + 3];
                *(float4*)&qc[kr + cb] = v;
                ushort4 h; h.x = f2bf(v.x); h.y = f2bf(v.y); h.z = f2bf(v.z); h.w = f2bf(v.w);
                *(ushort4*)&qh[kr + cb] = h;
            }
        }
}

// ---------------------------------------------------------------------------
// Row norms, numpy pairwise structure (UNCHANGED rounding).
// ---------------------------------------------------------------------------
__device__ __forceinline__ float pairwise512(const float* __restrict__ row) {
#pragma clang fp contract(off)
    float s128[4];
#pragma unroll
    for (int blk = 0; blk < 4; ++blk) {
        float r[8];
#pragma unroll
        for (int j = 0; j < 8; ++j) { float v = row[blk * 128 + j]; r[j] = v * v; }
#pragma unroll 1
        for (int i = 8; i < 128; i += 8) {
#pragma unroll
            for (int j = 0; j < 8; ++j) {
                float v = row[blk * 128 + i + j];
                float sq = v * v;
                r[j] = r[j] + sq;
            }
        }
        s128[blk] = ((r[0] + r[1]) + (r[2] + r[3])) + ((r[4] + r[5]) + (r[6] + r[7]));
    }
    return (s128[0] + s128[1]) + (s128[2] + s128[3]);
}

__global__ __launch_bounds__(256) void qnorm_pairwise(const float* __restrict__ qc,
                                                      float* __restrict__ qn) {
    const int k = blockIdx.x * 256 + threadIdx.x;
    qn[k] = pairwise512(qc + (size_t)k * C_);
}

__global__ __launch_bounds__(256) void znorm_pairwise(const float* __restrict__ zf,
                                                      float* __restrict__ zn) {
    const int n = blockIdx.x * 256 + threadIdx.x;
    zn[n] = pairwise512(zf + (size_t)n * C_);
}

// ---------------------------------------------------------------------------
// Phase A: MFMA bf16 distance tiles, top-2 per (row n, 128-code window).
// T2 swizzle (round-4) + T3-minimum 2-phase double-buffer: issue next-chunk
// global_load_lds BEFORE computing current chunk; ONE drain+barrier per iter.
// Values bit-identical to round 4 (same inputs, same accumulation order).
// ---------------------------------------------------------------------------
__global__ __launch_bounds__(256) void phaseA(const ushort* __restrict__ qh,
                                              const ushort* __restrict__ zh,
                                              const float* __restrict__ qn,
                                              float* __restrict__ wtop) {
    __shared__ short lq[2][128 * 64];   // [buf][k_local][c 64] bf16, swizzled
    __shared__ short lz[2][128 * 64];   // [buf][n_local][c 64] bf16, swizzled
    const int t    = threadIdx.x;
    const int lane = t & 63;
    const int wv   = t >> 6;
    const int wk   = wv >> 1, wn = wv & 1;
    const int n0   = blockIdx.x * 128;
    const int k0   = blockIdx.y * 128;

    // staging constants (per-thread, loop-invariant)
    const int s_row[4] = { (t + 0)   >> 3, (t + 256) >> 3,
                           (t + 512) >> 3, (t + 768) >> 3 };
    const int s_ch [4] = { t, t + 256, t + 512, t + 768 };

    auto stage = [&](int b, int c0) {
#pragma unroll
        for (int p = 0; p < 4; ++p) {
            const int ch  = s_ch[p];
            const int row = s_row[p];
            const int cs  = ((ch ^ row) & 7) * 8;   // swizzled SOURCE elem offset
            __builtin_amdgcn_global_load_lds(
                (const __attribute__((address_space(1))) uint*)(qh + (size_t)(k0 + row) * 512 + c0 + cs),
                (__attribute__((address_space(3))) uint*)&lq[b][ch * 8], 16, 0, 0);
            __builtin_amdgcn_global_load_lds(
                (const __attribute__((address_space(1))) uint*)(zh + (size_t)(n0 + row) * 512 + c0 + cs),
                (__attribute__((address_space(3))) uint*)&lz[b][ch * 8], 16, 0, 0);
        }
    };

    f32x4 acc[4][4];
#pragma unroll
    for (int i = 0; i < 4; ++i)
#pragma unroll
        for (int j = 0; j < 4; ++j) acc[i][j] = (f32x4){0.f, 0.f, 0.f, 0.f};

    // prologue: stage chunk 0 into buf 0
    stage(0, 0);
    __syncthreads();   // compiler emits vmcnt(0) drain before barrier

    int cur = 0;
    for (int it = 0; it < 8; ++it) {
        if (it < 7) stage(cur ^ 1, (it + 1) * 64);   // prefetch next chunk
        // compute current chunk from buf[cur]
#pragma unroll
        for (int kk = 0; kk < 64; kk += 32) {
            const int co = kk + ((lane >> 4) << 3);   // logical elem offset
            short8 af[4], bf[4];
#pragma unroll
            for (int i = 0; i < 4; ++i) {
                const int rA = wk * 64 + i * 16 + (lane & 15);
                const int rB = wn * 64 + i * 16 + (lane & 15);
                af[i] = *(const short8*)&lq[cur][rA * 64 + (co ^ ((rA & 7) << 3))];
                bf[i] = *(const short8*)&lz[cur][rB * 64 + (co ^ ((rB & 7) << 3))];
            }
#pragma unroll
            for (int i = 0; i < 4; ++i)
#pragma unroll
                for (int j = 0; j < 4; ++j)
                    acc[i][j] = __builtin_amdgcn_mfma_f32_16x16x32_bf16(af[i], bf[j], acc[i][j], 0, 0, 0);
        }
        if (it < 7) {
            __syncthreads();   // drains vmcnt(0): next chunk landed; buf flip safe
            cur ^= 1;
        }
    }
    __syncthreads();   // all LDS reads done before scratch reuse below

    // Epilogue: per n-column top-2 over this wave's 64 k's
    const int q4 = (lane >> 4) * 4;
    float qv[4][4];
#pragma unroll
    for (int ik = 0; ik < 4; ++ik)
#pragma unroll
        for (int r = 0; r < 4; ++r)
            qv[ik][r] = qn[k0 + wk * 64 + ik * 16 + q4 + r];

    float v1[4], v2[4];
    int   k1[4], k2[4];
#pragma unroll
    for (int in = 0; in < 4; ++in) {
        v1[in] = 1e30f; v2[in] = 1e30f; k1[in] = 0; k2[in] = 0;
#pragma unroll
        for (int ik = 0; ik < 4; ++ik) {
#pragma unroll
            for (int r = 0; r < 4; ++r) {
                const float val = qv[ik][r] - 2.0f * acc[ik][in][r];
                const int   kg  = k0 + wk * 64 + ik * 16 + q4 + r;
                if (val < v1[in]) { v2[in] = v1[in]; k2[in] = k1[in]; v1[in] = val; k1[in] = kg; }
                else if (val < v2[in]) { v2[in] = val; k2[in] = kg; }
            }
        }
    }
    // butterfly across the 4 k-subgroups (lane>>4)
#pragma unroll
    for (int m = 16; m <= 32; m <<= 1) {
#pragma unroll
        for (int in = 0; in < 4; ++in) {
            const float ov1 = __shfl_xor(v1[in], m, 64);
            const int   ok1 = __shfl_xor(k1[in], m, 64);
            const float ov2 = __shfl_xor(v2[in], m, 64);
            const int   ok2 = __shfl_xor(k2[in], m, 64);
            float nv1, nv2; int nk1, nk2;
            if (ov1 < v1[in]) {
                nv1 = ov1; nk1 = ok1;
                if (v1[in] < ov2) { nv2 = v1[in]; nk2 = k1[in]; } else { nv2 = ov2; nk2 = ok2; }
            } else {
                nv1 = v1[in]; nk1 = k1[in];
                if (ov1 < v2[in]) { nv2 = ov1; nk2 = ok1; } else { nv2 = v2[in]; nk2 = k2[in]; }
            }
            v1[in] = nv1; k1[in] = nk1; v2[in] = nv2; k2[in] = nk2;
        }
    }
    // cross-wave (wk) merge through LDS
    float* sb = (float*)&lq[0][0];
    if ((lane >> 4) == 0) {
#pragma unroll
        for (int in = 0; in < 4; ++in) {
            const int n_local = wn * 64 + in * 16 + (lane & 15);
            float* sp = sb + (wk * 128 + n_local) * 4;
            sp[0] = v1[in]; sp[1] = __int_as_float(k1[in]);
            sp[2] = v2[in]; sp[3] = __int_as_float(k2[in]);
        }
    }
    __syncthreads();
    if (t < 128) {
        float4 A  = *(float4*)&sb[t * 4];
        float4 Bv = *(float4*)&sb[(128 + t) * 4];
        float r1, r2; int rk1, rk2;
        if (Bv.x < A.x) {
            r1 = Bv.x; rk1 = __float_as_int(Bv.y);
            if (A.x < Bv.z) { r2 = A.x; rk2 = __float_as_int(A.y); }
            else            { r2 = Bv.z; rk2 = __float_as_int(Bv.w); }
        } else {
            r1 = A.x; rk1 = __float_as_int(A.y);
            if (Bv.x < A.z) { r2 = Bv.x; rk2 = __float_as_int(Bv.y); }
            else            { r2 = A.z; rk2 = __float_as_int(A.w); }
        }
        float4 o; o.x = r1; o.y = __int_as_float(rk1); o.z = r2; o.w = __int_as_float(rk2);
        *(float4*)&wtop[((size_t)blockIdx.y * N_ + n0 + t) * 4] = o;
    }
}

// ---------------------------------------------------------------------------
// Phase B: rowmin over windows; collect candidates within EPS of rowmin.
// ---------------------------------------------------------------------------
__global__ __launch_bounds__(256) void phaseB(const float* __restrict__ wtop,
                                              int* __restrict__ cand_k,
                                              int* __restrict__ cand_cnt) {
    const int n = blockIdx.x * 256 + threadIdx.x;
    float rmin = 1e30f;
    for (int w = 0; w < 64; ++w)
        rmin = fminf(rmin, wtop[((size_t)w * N_ + n) * 4]);
    const float thr = rmin + EPS_;
    int cnt = 0;
    for (int w = 0; w < 64; ++w) {
        float4 e = *(const float4*)&wtop[((size_t)w * N_ + n) * 4];
        if (e.x <= thr && cnt < 16) cand_k[n * 16 + cnt++] = __float_as_int(e.y);
        if (e.z <= thr && cnt < 16) cand_k[n * 16 + cnt++] = __float_as_int(e.w);
    }
    cand_cnt[n] = cnt;
}

// ---------------------------------------------------------------------------
// Phase C: exact recheck. Sequential-FMA chain identical (bit-for-bit) to the
// round-2 passing kernel's accumulation.
// ---------------------------------------------------------------------------
__global__ __launch_bounds__(256) void phaseC(const float* __restrict__ zf,
                                              const float* __restrict__ qc,
                                              const float* __restrict__ zn,
                                              const float* __restrict__ qn,
                                              const int* __restrict__ cand_k,
                                              const int* __restrict__ cand_cnt,
                                              int* __restrict__ idxf,
                                              float* __restrict__ out_idx) {
    __shared__ float zr[4][512];
    const int wv   = threadIdx.x >> 6;
    const int lane = threadIdx.x & 63;
    const int r    = blockIdx.x * 4 + wv;
    *(float4*)&zr[wv][lane * 8]     = *(const float4*)&zf[(size_t)r * 512 + lane * 8];
    *(float4*)&zr[wv][lane * 8 + 4] = *(const float4*)&zf[(size_t)r * 512 + lane * 8 + 4];
    __syncthreads();
    const int cnt = cand_cnt[r];
    const float znr = zn[r];
    float bd = 1e30f;
    int   bi = 0x7fffffff;
    for (int ci = 0; ci < cnt; ++ci) {
        const int k = cand_k[r * 16 + ci];
        const float* q = qc + (size_t)k * 512;
        float acc = 0.f;
#pragma unroll 8
        for (int c = 0; c < 512; ++c)
            acc = fmaf(zr[wv][c], q[c], acc);
        const float T = znr + qn[k];
        const float d = T - 2.0f * acc;
        if (d < bd || (d == bd && k < bi)) { bd = d; bi = k; }
    }
    if (lane == 0) { idxf[r] = bi; out_idx[r] = (float)bi; }
}

// ---------------------------------------------------------------------------
// Gather z_q = qc[idx], transpose-write to [B,C,H,W], fused loss.
// ---------------------------------------------------------------------------
__global__ __launch_bounds__(256) void gather_out(const float* __restrict__ z,
                                                  const float* __restrict__ qc,
                                                  const int* __restrict__ idxf,
                                                  float* __restrict__ zq_out,
                                                  float* __restrict__ loss_acc) {
    __shared__ int   idxs[64];
    __shared__ float zqs[64][65];
    __shared__ float wsum[4];
    const int t  = threadIdx.x;
    const int mc = blockIdx.x;
    const int cc = blockIdx.y;
    const int bz = blockIdx.z;

    if (t < 64) idxs[t] = idxf[bz * 1024 + mc * 64 + t];
    __syncthreads();
    {
        const int row  = t >> 2;
        const int coff = (t & 3) * 16;
        const float* src = qc + (size_t)idxs[row] * 512 + cc * 64 + coff;
#pragma unroll
        for (int v = 0; v < 4; ++v) {
            float4 q = *(const float4*)&src[v * 4];
            zqs[row][coff + v * 4 + 0] = q.x;
            zqs[row][coff + v * 4 + 1] = q.y;
            zqs[row][coff + v * 4 + 2] = q.z;
            zqs[row][coff + v * 4 + 3] = q.w;
        }
    }
    __syncthreads();

    float ls = 0.f;
    {
        const int c_local = t >> 2;
        const int mg      = (t & 3) * 16;
        const size_t gbase = ((size_t)(bz * 512 + cc * 64 + c_local)) * 1024 + mc * 64 + mg;
#pragma unroll
        for (int v = 0; v < 4; ++v) {
            const int m = mg + v * 4;
            float4 w;
            w.x = zqs[m + 0][c_local];
            w.y = zqs[m + 1][c_local];
            w.z = zqs[m + 2][c_local];
            w.w = zqs[m + 3][c_local];
            float4 zv = *(const float4*)&z[gbase + v * 4];
            float dx = w.x - zv.x, dy = w.y - zv.y, dz = w.z - zv.z, dw = w.w - zv.w;
            ls += dx * dx + dy * dy + dz * dz + dw * dw;
            *(float4*)&zq_out[gbase + v * 4] = w;
        }
    }
#pragma unroll
    for (int m = 32; m; m >>= 1) ls += __shfl_xor(ls, m, 64);
    const int lane = t & 63, wvv = t >> 6;
    if (lane == 0) wsum[wvv] = ls;
    __syncthreads();
    if (t == 0) atomicAdd(loss_acc, wsum[0] + wsum[1] + wsum[2] + wsum[3]);
}

__global__ void zero_loss(float* __restrict__ loss_acc) { loss_acc[0] = 0.f; }

__global__ void finalize(const float* __restrict__ loss_acc,
                         float* __restrict__ out_loss) {
    out_loss[0] = 1.25f * loss_acc[0] / 8388608.0f;
}

// ---------------------------------------------------------------------------
extern "C" void kernel_launch(void* const* d_in, const int* in_sizes, int n_in,
                              void* d_out, int out_size, void* d_ws, size_t ws_size,
                              hipStream_t stream) {
    const float* z    = (const float*)d_in[0];
    const float* emb  = (const float*)d_in[1];
    const float* W    = (const float*)d_in[2];
    const float* bias = (const float*)d_in[3];
    float* ws = (float*)d_ws;

    float*  qc       = ws + QC_OFF;
    float*  qn       = ws + QN_OFF;
    float*  zn       = ws + ZN_OFF;
    float*  zf       = ws + ZF_OFF;
    ushort* zh       = (ushort*)(ws + ZH_OFF);
    ushort* qh       = (ushort*)(ws + QH_OFF);
    float*  wtop     = ws + WT_OFF;
    int*    cand_k   = (int*)(ws + CK_OFF);
    int*    cand_cnt = (int*)(ws + CC_OFF);
    int*    idxf     = (int*)(ws + IDXF_OFF);
    float*  loss_acc = ws + LOSS_OFF;
    float*  out      = (float*)d_out;

    zero_loss<<<1, 1, 0, stream>>>(loss_acc);
    transpose_z<<<dim3(16, 8, 16), 256, 0, stream>>>(z, zf, zh);
    qc_gemm<<<dim3(K_ / 128, C_ / 128), 256, 0, stream>>>(emb, W, bias, qc, qh);
    qnorm_pairwise<<<K_ / 256, 256, 0, stream>>>(qc, qn);
    znorm_pairwise<<<N_ / 256, 256, 0, stream>>>(zf, zn);
    phaseA<<<dim3(N_ / 128, K_ / 128), 256, 0, stream>>>(qh, zh, qn, wtop);
    phaseB<<<N_ / 256, 256, 0, stream>>>(wtop, cand_k, cand_cnt);
    phaseC<<<N_ / 4, 256, 0, stream>>>(zf, qc, zn, qn, cand_k, cand_cnt, idxf, out + OUT_IDX);
    gather_out<<<dim3(16, 8, B_), 256, 0, stream>>>(z, qc, idxf, out + OUT_ZQ, loss_acc);
    finalize<<<1, 1, 0, stream>>>(loss_acc, out + OUT_LOSS);
}

// Round 6
// 466.983 us; speedup vs baseline: 4.4547x; 1.3782x over previous
//
#include <hip/hip_runtime.h>

typedef unsigned int uint;
typedef unsigned short ushort;
typedef __attribute__((ext_vector_type(8))) short short8;
typedef __attribute__((ext_vector_type(4))) float f32x4;

// Problem constants
#define B_   16
#define C_   512     // e_dim
#define HW_  1024    // 32*32
#define N_   16384   // B*H*W
#define K_   8192    // n_e
#define EPS_ 0.25f   // candidate margin (|d~ - d| <~ 0.05 @10sigma; 2*delta << EPS)

// Workspace layout (in float units)
#define QC_OFF    0u
#define QC_SZ     (K_ * C_)            // 4,194,304
#define QN_OFF    (QC_OFF + QC_SZ)
#define QN_SZ     K_
#define ZN_OFF    (QN_OFF + QN_SZ)
#define ZN_SZ     N_
#define ZF_OFF    (ZN_OFF + ZN_SZ)     // z_flat f32 [N][C]
#define ZF_SZ     (N_ * C_)            // 8,388,608
#define ZH_OFF    (ZF_OFF + ZF_SZ)     // z bf16 [N][C] (2 per float)
#define ZH_SZ     (N_ * C_ / 2)
#define QH_OFF    (ZH_OFF + ZH_SZ)     // qc bf16 [K][C]
#define QH_SZ     (K_ * C_ / 2)
#define WT_OFF    (QH_OFF + QH_SZ)     // wtop [64 windows][N] float4 {v1,k1,v2,k2}
#define WT_SZ     (64 * N_ * 4)
#define CK_OFF    (WT_OFF + WT_SZ)     // cand_k [N][16] int
#define CK_SZ     (N_ * 16)
#define CC_OFF    (CK_OFF + CK_SZ)     // cand_cnt [N]
#define CC_SZ     N_
#define IDXF_OFF  (CC_OFF + CC_SZ)
#define IDXF_SZ   N_
#define LOSS_OFF  (IDXF_OFF + IDXF_SZ)

// Output layout (floats)
#define OUT_ZQ    0
#define OUT_LOSS  8388608
#define OUT_IDX   8388609

__device__ __forceinline__ ushort f2bf(float f) {   // RNE f32 -> bf16 (finite data)
    uint x = __float_as_uint(f);
    uint r = x + 0x7fffu + ((x >> 16) & 1u);
    return (ushort)(r >> 16);
}

// ---------------------------------------------------------------------------
// Transpose: z [B][C][HW] f32 -> z_flat [N][C] f32 (exact copy) + zh bf16
// ---------------------------------------------------------------------------
__global__ __launch_bounds__(256) void transpose_z(const float* __restrict__ z,
                                                   float* __restrict__ zf,
                                                   ushort* __restrict__ zh) {
    __shared__ float ld[64][65];
    const int t = threadIdx.x;
    const int mt = blockIdx.x, ct = blockIdx.y, b = blockIdx.z;
    {
        const int cl = t >> 4, m4 = (t & 15) * 4;
#pragma unroll
        for (int cc = 0; cc < 4; ++cc) {
            const int c = ct * 64 + cc * 16 + cl;
            float4 v = *(const float4*)&z[((size_t)(b * 512 + c)) * 1024 + mt * 64 + m4];
            ld[cc * 16 + cl][m4 + 0] = v.x; ld[cc * 16 + cl][m4 + 1] = v.y;
            ld[cc * 16 + cl][m4 + 2] = v.z; ld[cc * 16 + cl][m4 + 3] = v.w;
        }
    }
    __syncthreads();
    {
        const int nl = t >> 4, c4 = (t & 15) * 4;
#pragma unroll
        for (int nn = 0; nn < 4; ++nn) {
            const int n_local = nn * 16 + nl;
            const size_t n = (size_t)b * 1024 + mt * 64 + n_local;
            float4 w;
            w.x = ld[c4 + 0][n_local]; w.y = ld[c4 + 1][n_local];
            w.z = ld[c4 + 2][n_local]; w.w = ld[c4 + 3][n_local];
            *(float4*)&zf[n * 512 + ct * 64 + c4] = w;
            ushort4 h; h.x = f2bf(w.x); h.y = f2bf(w.y); h.z = f2bf(w.z); h.w = f2bf(w.w);
            *(ushort4*)&zh[n * 512 + ct * 64 + c4] = h;
        }
    }
}

// ---------------------------------------------------------------------------
// qc GEMM: 128x128 tile, 8x8 per thread. Per-element math IDENTICAL to the
// passing kernels: single accumulator, d ascending, FMA chain. Fused qh.
// ---------------------------------------------------------------------------
__global__ __launch_bounds__(256) void qc_gemm(const float* __restrict__ emb,
                                               const float* __restrict__ W,
                                               const float* __restrict__ bias,
                                               float* __restrict__ qc,
                                               ushort* __restrict__ qh) {
    __shared__ float As[16][132];   // [d_local][k_local], pad 132
    __shared__ float Bs[16][132];   // [d_local][c_local]
    const int t   = threadIdx.x;
    const int k0  = blockIdx.x * 128;
    const int c0  = blockIdx.y * 128;
    const int ty  = t >> 4, tx = t & 15;
    const int row = t >> 1;          // 0..127 (staging row)
    const int dq  = (t & 1) * 8;     // staging d-offset 0/8

    const float* pa = emb + (size_t)(k0 + row) * 512 + dq;
    const float* pb = W   + (size_t)(c0 + row) * 512 + dq;
    float4 ra0 = *(const float4*)&pa[0];
    float4 ra1 = *(const float4*)&pa[4];
    float4 rb0 = *(const float4*)&pb[0];
    float4 rb1 = *(const float4*)&pb[4];

    float acc[2][2][4][4] = {};   // [ih][jh][i][j]
    for (int d0 = 0; d0 < 512; d0 += 16) {
        __syncthreads();
        As[dq + 0][row] = ra0.x; As[dq + 1][row] = ra0.y;
        As[dq + 2][row] = ra0.z; As[dq + 3][row] = ra0.w;
        As[dq + 4][row] = ra1.x; As[dq + 5][row] = ra1.y;
        As[dq + 6][row] = ra1.z; As[dq + 7][row] = ra1.w;
        Bs[dq + 0][row] = rb0.x; Bs[dq + 1][row] = rb0.y;
        Bs[dq + 2][row] = rb0.z; Bs[dq + 3][row] = rb0.w;
        Bs[dq + 4][row] = rb1.x; Bs[dq + 5][row] = rb1.y;
        Bs[dq + 6][row] = rb1.z; Bs[dq + 7][row] = rb1.w;
        if (d0 + 16 < 512) {   // issue next-tile loads early; consumed next iter
            ra0 = *(const float4*)&pa[d0 + 16];
            ra1 = *(const float4*)&pa[d0 + 20];
            rb0 = *(const float4*)&pb[d0 + 16];
            rb1 = *(const float4*)&pb[d0 + 20];
        }
        __syncthreads();
#pragma unroll
        for (int dd = 0; dd < 16; ++dd) {
            float4 a0 = *(const float4*)&As[dd][ty * 4];
            float4 a1 = *(const float4*)&As[dd][64 + ty * 4];
            float4 b0 = *(const float4*)&Bs[dd][tx * 4];
            float4 b1 = *(const float4*)&Bs[dd][64 + tx * 4];
            float aa[2][4] = {{a0.x, a0.y, a0.z, a0.w}, {a1.x, a1.y, a1.z, a1.w}};
            float bb[2][4] = {{b0.x, b0.y, b0.z, b0.w}, {b1.x, b1.y, b1.z, b1.w}};
#pragma unroll
            for (int ih = 0; ih < 2; ++ih)
#pragma unroll
                for (int jh = 0; jh < 2; ++jh)
#pragma unroll
                    for (int i = 0; i < 4; ++i)
#pragma unroll
                        for (int j = 0; j < 4; ++j)
                            acc[ih][jh][i][j] += aa[ih][i] * bb[jh][j];  // fma, d asc
        }
    }
#pragma unroll
    for (int ih = 0; ih < 2; ++ih)
#pragma unroll
        for (int i = 0; i < 4; ++i) {
            const size_t kr = (size_t)(k0 + ih * 64 + ty * 4 + i) * 512;
#pragma unroll
            for (int jh = 0; jh < 2; ++jh) {
                const int cb = c0 + jh * 64 + tx * 4;
                float4 v;
                v.x = acc[ih][jh][i][0] + bias[cb + 0];
                v.y = acc[ih][jh][i][1] + bias[cb + 1];
                v.z = acc[ih][jh][i][2] + bias[cb + 2];
                v.w = acc[ih][jh][i][3] + bias[cb + 3];
                *(float4*)&qc[kr + cb] = v;
                ushort4 h; h.x = f2bf(v.x); h.y = f2bf(v.y); h.z = f2bf(v.z); h.w = f2bf(v.w);
                *(ushort4*)&qh[kr + cb] = h;
            }
        }
}

// ---------------------------------------------------------------------------
// Row norms, numpy pairwise structure (UNCHANGED rounding).
// ---------------------------------------------------------------------------
__device__ __forceinline__ float pairwise512(const float* __restrict__ row) {
#pragma clang fp contract(off)
    float s128[4];
#pragma unroll
    for (int blk = 0; blk < 4; ++blk) {
        float r[8];
#pragma unroll
        for (int j = 0; j < 8; ++j) { float v = row[blk * 128 + j]; r[j] = v * v; }
#pragma unroll 1
        for (int i = 8; i < 128; i += 8) {
#pragma unroll
            for (int j = 0; j < 8; ++j) {
                float v = row[blk * 128 + i + j];
                float sq = v * v;
                r[j] = r[j] + sq;
            }
        }
        s128[blk] = ((r[0] + r[1]) + (r[2] + r[3])) + ((r[4] + r[5]) + (r[6] + r[7]));
    }
    return (s128[0] + s128[1]) + (s128[2] + s128[3]);
}

__global__ __launch_bounds__(256) void qnorm_pairwise(const float* __restrict__ qc,
                                                      float* __restrict__ qn) {
    const int k = blockIdx.x * 256 + threadIdx.x;
    qn[k] = pairwise512(qc + (size_t)k * C_);
}

__global__ __launch_bounds__(256) void znorm_pairwise(const float* __restrict__ zf,
                                                      float* __restrict__ zn) {
    const int n = blockIdx.x * 256 + threadIdx.x;
    zn[n] = pairwise512(zf + (size_t)n * C_);
}

// ---------------------------------------------------------------------------
// Phase A: MFMA bf16 distance tiles, top-2 per (row n, 128-code window).
// T2 swizzle + 2-phase double-buffer (unchanged from round 5).
// ---------------------------------------------------------------------------
__global__ __launch_bounds__(256) void phaseA(const ushort* __restrict__ qh,
                                              const ushort* __restrict__ zh,
                                              const float* __restrict__ qn,
                                              float* __restrict__ wtop) {
    __shared__ short lq[2][128 * 64];   // [buf][k_local][c 64] bf16, swizzled
    __shared__ short lz[2][128 * 64];   // [buf][n_local][c 64] bf16, swizzled
    const int t    = threadIdx.x;
    const int lane = t & 63;
    const int wv   = t >> 6;
    const int wk   = wv >> 1, wn = wv & 1;
    const int n0   = blockIdx.x * 128;
    const int k0   = blockIdx.y * 128;

    const int s_row[4] = { (t + 0)   >> 3, (t + 256) >> 3,
                           (t + 512) >> 3, (t + 768) >> 3 };
    const int s_ch [4] = { t, t + 256, t + 512, t + 768 };

    auto stage = [&](int b, int c0) {
#pragma unroll
        for (int p = 0; p < 4; ++p) {
            const int ch  = s_ch[p];
            const int row = s_row[p];
            const int cs  = ((ch ^ row) & 7) * 8;   // swizzled SOURCE elem offset
            __builtin_amdgcn_global_load_lds(
                (const __attribute__((address_space(1))) uint*)(qh + (size_t)(k0 + row) * 512 + c0 + cs),
                (__attribute__((address_space(3))) uint*)&lq[b][ch * 8], 16, 0, 0);
            __builtin_amdgcn_global_load_lds(
                (const __attribute__((address_space(1))) uint*)(zh + (size_t)(n0 + row) * 512 + c0 + cs),
                (__attribute__((address_space(3))) uint*)&lz[b][ch * 8], 16, 0, 0);
        }
    };

    f32x4 acc[4][4];
#pragma unroll
    for (int i = 0; i < 4; ++i)
#pragma unroll
        for (int j = 0; j < 4; ++j) acc[i][j] = (f32x4){0.f, 0.f, 0.f, 0.f};

    stage(0, 0);
    __syncthreads();

    int cur = 0;
    for (int it = 0; it < 8; ++it) {
        if (it < 7) stage(cur ^ 1, (it + 1) * 64);   // prefetch next chunk
#pragma unroll
        for (int kk = 0; kk < 64; kk += 32) {
            const int co = kk + ((lane >> 4) << 3);   // logical elem offset
            short8 af[4], bf[4];
#pragma unroll
            for (int i = 0; i < 4; ++i) {
                const int rA = wk * 64 + i * 16 + (lane & 15);
                const int rB = wn * 64 + i * 16 + (lane & 15);
                af[i] = *(const short8*)&lq[cur][rA * 64 + (co ^ ((rA & 7) << 3))];
                bf[i] = *(const short8*)&lz[cur][rB * 64 + (co ^ ((rB & 7) << 3))];
            }
#pragma unroll
            for (int i = 0; i < 4; ++i)
#pragma unroll
                for (int j = 0; j < 4; ++j)
                    acc[i][j] = __builtin_amdgcn_mfma_f32_16x16x32_bf16(af[i], bf[j], acc[i][j], 0, 0, 0);
        }
        if (it < 7) {
            __syncthreads();
            cur ^= 1;
        }
    }
    __syncthreads();

    // Epilogue: per n-column top-2 over this wave's 64 k's
    const int q4 = (lane >> 4) * 4;
    float qv[4][4];
#pragma unroll
    for (int ik = 0; ik < 4; ++ik)
#pragma unroll
        for (int r = 0; r < 4; ++r)
            qv[ik][r] = qn[k0 + wk * 64 + ik * 16 + q4 + r];

    float v1[4], v2[4];
    int   k1[4], k2[4];
#pragma unroll
    for (int in = 0; in < 4; ++in) {
        v1[in] = 1e30f; v2[in] = 1e30f; k1[in] = 0; k2[in] = 0;
#pragma unroll
        for (int ik = 0; ik < 4; ++ik) {
#pragma unroll
            for (int r = 0; r < 4; ++r) {
                const float val = qv[ik][r] - 2.0f * acc[ik][in][r];
                const int   kg  = k0 + wk * 64 + ik * 16 + q4 + r;
                if (val < v1[in]) { v2[in] = v1[in]; k2[in] = k1[in]; v1[in] = val; k1[in] = kg; }
                else if (val < v2[in]) { v2[in] = val; k2[in] = kg; }
            }
        }
    }
#pragma unroll
    for (int m = 16; m <= 32; m <<= 1) {
#pragma unroll
        for (int in = 0; in < 4; ++in) {
            const float ov1 = __shfl_xor(v1[in], m, 64);
            const int   ok1 = __shfl_xor(k1[in], m, 64);
            const float ov2 = __shfl_xor(v2[in], m, 64);
            const int   ok2 = __shfl_xor(k2[in], m, 64);
            float nv1, nv2; int nk1, nk2;
            if (ov1 < v1[in]) {
                nv1 = ov1; nk1 = ok1;
                if (v1[in] < ov2) { nv2 = v1[in]; nk2 = k1[in]; } else { nv2 = ov2; nk2 = ok2; }
            } else {
                nv1 = v1[in]; nk1 = k1[in];
                if (ov1 < v2[in]) { nv2 = ov1; nk2 = ok1; } else { nv2 = v2[in]; nk2 = k2[in]; }
            }
            v1[in] = nv1; k1[in] = nk1; v2[in] = nv2; k2[in] = nk2;
        }
    }
    float* sb = (float*)&lq[0][0];
    if ((lane >> 4) == 0) {
#pragma unroll
        for (int in = 0; in < 4; ++in) {
            const int n_local = wn * 64 + in * 16 + (lane & 15);
            float* sp = sb + (wk * 128 + n_local) * 4;
            sp[0] = v1[in]; sp[1] = __int_as_float(k1[in]);
            sp[2] = v2[in]; sp[3] = __int_as_float(k2[in]);
        }
    }
    __syncthreads();
    if (t < 128) {
        float4 A  = *(float4*)&sb[t * 4];
        float4 Bv = *(float4*)&sb[(128 + t) * 4];
        float r1, r2; int rk1, rk2;
        if (Bv.x < A.x) {
            r1 = Bv.x; rk1 = __float_as_int(Bv.y);
            if (A.x < Bv.z) { r2 = A.x; rk2 = __float_as_int(A.y); }
            else            { r2 = Bv.z; rk2 = __float_as_int(Bv.w); }
        } else {
            r1 = A.x; rk1 = __float_as_int(A.y);
            if (Bv.x < A.z) { r2 = Bv.x; rk2 = __float_as_int(Bv.y); }
            else            { r2 = A.z; rk2 = __float_as_int(A.w); }
        }
        float4 o; o.x = r1; o.y = __int_as_float(rk1); o.z = r2; o.w = __int_as_float(rk2);
        *(float4*)&wtop[((size_t)blockIdx.y * N_ + n0 + t) * 4] = o;
    }
}

// ---------------------------------------------------------------------------
// Phase B: rowmin over windows; collect candidates within EPS of rowmin.
// ---------------------------------------------------------------------------
__global__ __launch_bounds__(256) void phaseB(const float* __restrict__ wtop,
                                              int* __restrict__ cand_k,
                                              int* __restrict__ cand_cnt) {
    const int n = blockIdx.x * 256 + threadIdx.x;
    float rmin = 1e30f;
    for (int w = 0; w < 64; ++w)
        rmin = fminf(rmin, wtop[((size_t)w * N_ + n) * 4]);
    const float thr = rmin + EPS_;
    int cnt = 0;
    for (int w = 0; w < 64; ++w) {
        float4 e = *(const float4*)&wtop[((size_t)w * N_ + n) * 4];
        if (e.x <= thr && cnt < 16) cand_k[n * 16 + cnt++] = __float_as_int(e.y);
        if (e.z <= thr && cnt < 16) cand_k[n * 16 + cnt++] = __float_as_int(e.w);
    }
    cand_cnt[n] = cnt;
}

// ---------------------------------------------------------------------------
// Phase C v2: exact recheck, restructured.
//  - cnt==1: the lone candidate IS the argmin (true argmin always in set) ->
//    write and exit, no loads.
//  - candidate row staged via coalesced float4 loads into per-group LDS
//    buffer; next candidate prefetched into registers under current chain.
//  - two lane-groups (0-31 / 32-63) process even/odd candidates in parallel;
//    merged with the same exact (d, k) comparator (order-independent).
//  - FMA chain bit-identical to the round-2 passing kernel: single
//    accumulator, c ascending, fmaf; d = (zn + qn[k]) - 2*acc.
//  - NO __syncthreads (per-wave LDS ops are FIFO-ordered) -> early exit safe.
// ---------------------------------------------------------------------------
__global__ __launch_bounds__(256) void phaseC(const float* __restrict__ zf,
                                              const float* __restrict__ qc,
                                              const float* __restrict__ zn,
                                              const float* __restrict__ qn,
                                              const int* __restrict__ cand_k,
                                              const int* __restrict__ cand_cnt,
                                              int* __restrict__ idxf,
                                              float* __restrict__ out_idx) {
    __shared__ float zr[4][512];
    __shared__ float ql[4][2][512];   // [wave][group][c]
    const int wv   = threadIdx.x >> 6;
    const int lane = threadIdx.x & 63;
    const int r    = blockIdx.x * 4 + wv;
    const int cnt  = cand_cnt[r];

    if (cnt == 1) {
        if (lane == 0) { const int k = cand_k[r * 16]; idxf[r] = k; out_idx[r] = (float)k; }
        return;
    }

    // stage z row (wave-local)
    *(float4*)&zr[wv][lane * 8]     = *(const float4*)&zf[(size_t)r * 512 + lane * 8];
    *(float4*)&zr[wv][lane * 8 + 4] = *(const float4*)&zf[(size_t)r * 512 + lane * 8 + 4];

    const int g  = lane >> 5;          // candidate group 0/1
    const int cl = (lane & 31) * 16;   // this lane's 16-float slice
    const int steps = (cnt + 1) >> 1;
    const float znr = zn[r];

    auto cand_of = [&](int s) {        // candidate index for this group at step s
        const int ci = 2 * s + g;
        return cand_k[r * 16 + (ci < cnt ? ci : 0)];
    };

    int k_cur = cand_of(0);
    const float* q0 = qc + (size_t)k_cur * 512 + cl;
    float4 p0 = *(const float4*)&q0[0];
    float4 p1 = *(const float4*)&q0[4];
    float4 p2 = *(const float4*)&q0[8];
    float4 p3 = *(const float4*)&q0[12];

    float bd = 1e30f;
    int   bi = 0x7fffffff;

    for (int s = 0; s < steps; ++s) {
        // write staged candidate into this group's LDS buffer
        *(float4*)&ql[wv][g][cl + 0]  = p0;
        *(float4*)&ql[wv][g][cl + 4]  = p1;
        *(float4*)&ql[wv][g][cl + 8]  = p2;
        *(float4*)&ql[wv][g][cl + 12] = p3;

        int k_next = 0;
        if (s + 1 < steps) {   // prefetch next candidate under the chain
            k_next = cand_of(s + 1);
            const float* qn_ = qc + (size_t)k_next * 512 + cl;
            p0 = *(const float4*)&qn_[0];
            p1 = *(const float4*)&qn_[4];
            p2 = *(const float4*)&qn_[8];
            p3 = *(const float4*)&qn_[12];
        }

        // exact sequential-FMA chain (identical to round-2 math)
        float acc = 0.f;
#pragma unroll 16
        for (int c = 0; c < 512; c += 4) {
            float4 zv = *(const float4*)&zr[wv][c];
            float4 qv = *(const float4*)&ql[wv][g][c];
            acc = fmaf(zv.x, qv.x, acc);
            acc = fmaf(zv.y, qv.y, acc);
            acc = fmaf(zv.z, qv.z, acc);
            acc = fmaf(zv.w, qv.w, acc);
        }
        const float T = znr + qn[k_cur];
        const float d = T - 2.0f * acc;
        const bool valid = (2 * s + g) < cnt;
        if (valid && (d < bd || (d == bd && k_cur < bi))) { bd = d; bi = k_cur; }
        k_cur = k_next;
    }

    // merge the two groups with the same exact comparator
    const float od = __shfl_xor(bd, 32, 64);
    const int   oi = __shfl_xor(bi, 32, 64);
    if (od < bd || (od == bd && oi < bi)) { bd = od; bi = oi; }

    if (lane == 0) { idxf[r] = bi; out_idx[r] = (float)bi; }
}

// ---------------------------------------------------------------------------
// Gather z_q = qc[idx], transpose-write to [B,C,H,W], fused loss.
// ---------------------------------------------------------------------------
__global__ __launch_bounds__(256) void gather_out(const float* __restrict__ z,
                                                  const float* __restrict__ qc,
                                                  const int* __restrict__ idxf,
                                                  float* __restrict__ zq_out,
                                                  float* __restrict__ loss_acc) {
    __shared__ int   idxs[64];
    __shared__ float zqs[64][65];
    __shared__ float wsum[4];
    const int t  = threadIdx.x;
    const int mc = blockIdx.x;
    const int cc = blockIdx.y;
    const int bz = blockIdx.z;

    if (t < 64) idxs[t] = idxf[bz * 1024 + mc * 64 + t];
    __syncthreads();
    {
        const int row  = t >> 2;
        const int coff = (t & 3) * 16;
        const float* src = qc + (size_t)idxs[row] * 512 + cc * 64 + coff;
#pragma unroll
        for (int v = 0; v < 4; ++v) {
            float4 q = *(const float4*)&src[v * 4];
            zqs[row][coff + v * 4 + 0] = q.x;
            zqs[row][coff + v * 4 + 1] = q.y;
            zqs[row][coff + v * 4 + 2] = q.z;
            zqs[row][coff + v * 4 + 3] = q.w;
        }
    }
    __syncthreads();

    float ls = 0.f;
    {
        const int c_local = t >> 2;
        const int mg      = (t & 3) * 16;
        const size_t gbase = ((size_t)(bz * 512 + cc * 64 + c_local)) * 1024 + mc * 64 + mg;
#pragma unroll
        for (int v = 0; v < 4; ++v) {
            const int m = mg + v * 4;
            float4 w;
            w.x = zqs[m + 0][c_local];
            w.y = zqs[m + 1][c_local];
            w.z = zqs[m + 2][c_local];
            w.w = zqs[m + 3][c_local];
            float4 zv = *(const float4*)&z[gbase + v * 4];
            float dx = w.x - zv.x, dy = w.y - zv.y, dz = w.z - zv.z, dw = w.w - zv.w;
            ls += dx * dx + dy * dy + dz * dz + dw * dw;
            *(float4*)&zq_out[gbase + v * 4] = w;
        }
    }
#pragma unroll
    for (int m = 32; m; m >>= 1) ls += __shfl_xor(ls, m, 64);
    const int lane = t & 63, wvv = t >> 6;
    if (lane == 0) wsum[wvv] = ls;
    __syncthreads();
    if (t == 0) atomicAdd(loss_acc, wsum[0] + wsum[1] + wsum[2] + wsum[3]);
}

__global__ void zero_loss(float* __restrict__ loss_acc) { loss_acc[0] = 0.f; }

__global__ void finalize(const float* __restrict__ loss_acc,
                         float* __restrict__ out_loss) {
    out_loss[0] = 1.25f * loss_acc[0] / 8388608.0f;
}

// ---------------------------------------------------------------------------
extern "C" void kernel_launch(void* const* d_in, const int* in_sizes, int n_in,
                              void* d_out, int out_size, void* d_ws, size_t ws_size,
                              hipStream_t stream) {
    const float* z    = (const float*)d_in[0];
    const float* emb  = (const float*)d_in[1];
    const float* W    = (const float*)d_in[2];
    const float* bias = (const float*)d_in[3];
    float* ws = (float*)d_ws;

    float*  qc       = ws + QC_OFF;
    float*  qn       = ws + QN_OFF;
    float*  zn       = ws + ZN_OFF;
    float*  zf       = ws + ZF_OFF;
    ushort* zh       = (ushort*)(ws + ZH_OFF);
    ushort* qh       = (ushort*)(ws + QH_OFF);
    float*  wtop     = ws + WT_OFF;
    int*    cand_k   = (int*)(ws + CK_OFF);
    int*    cand_cnt = (int*)(ws + CC_OFF);
    int*    idxf     = (int*)(ws + IDXF_OFF);
    float*  loss_acc = ws + LOSS_OFF;
    float*  out      = (float*)d_out;

    zero_loss<<<1, 1, 0, stream>>>(loss_acc);
    transpose_z<<<dim3(16, 8, 16), 256, 0, stream>>>(z, zf, zh);
    qc_gemm<<<dim3(K_ / 128, C_ / 128), 256, 0, stream>>>(emb, W, bias, qc, qh);
    qnorm_pairwise<<<K_ / 256, 256, 0, stream>>>(qc, qn);
    znorm_pairwise<<<N_ / 256, 256, 0, stream>>>(zf, zn);
    phaseA<<<dim3(N_ / 128, K_ / 128), 256, 0, stream>>>(qh, zh, qn, wtop);
    phaseB<<<N_ / 256, 256, 0, stream>>>(wtop, cand_k, cand_cnt);
    phaseC<<<N_ / 4, 256, 0, stream>>>(zf, qc, zn, qn, cand_k, cand_cnt, idxf, out + OUT_IDX);
    gather_out<<<dim3(16, 8, B_), 256, 0, stream>>>(z, qc, idxf, out + OUT_ZQ, loss_acc);
    finalize<<<1, 1, 0, stream>>>(loss_acc, out + OUT_LOSS);
}

// Round 7
// 465.247 us; speedup vs baseline: 4.4713x; 1.0037x over previous
//
#include <hip/hip_runtime.h>

typedef unsigned int uint;
typedef unsigned short ushort;
typedef __attribute__((ext_vector_type(8))) short short8;
typedef __attribute__((ext_vector_type(4))) float f32x4;

// Problem constants
#define B_   16
#define C_   512     // e_dim
#define HW_  1024    // 32*32
#define N_   16384   // B*H*W
#define K_   8192    // n_e
#define EPS_ 0.25f   // candidate margin (|d~ - d| <~ 0.05 @10sigma; 2*delta << EPS)

// Workspace layout (in float units)
#define QC_OFF    0u
#define QC_SZ     (K_ * C_)            // 4,194,304
#define QN_OFF    (QC_OFF + QC_SZ)
#define QN_SZ     K_
#define ZN_OFF    (QN_OFF + QN_SZ)
#define ZN_SZ     N_
#define ZF_OFF    (ZN_OFF + ZN_SZ)     // z_flat f32 [N][C]
#define ZF_SZ     (N_ * C_)            // 8,388,608
#define ZH_OFF    (ZF_OFF + ZF_SZ)     // z bf16 [N][C] (2 per float)
#define ZH_SZ     (N_ * C_ / 2)
#define QH_OFF    (ZH_OFF + ZH_SZ)     // qc bf16 [K][C]
#define QH_SZ     (K_ * C_ / 2)
#define WT_OFF    (QH_OFF + QH_SZ)     // wtop [64 windows][N] float4 {v1,k1,v2,k2}
#define WT_SZ     (64 * N_ * 4)
#define CK_OFF    (WT_OFF + WT_SZ)     // cand_k [N][16] int
#define CK_SZ     (N_ * 16)
#define CC_OFF    (CK_OFF + CK_SZ)     // cand_cnt [N]
#define CC_SZ     N_
#define IDXF_OFF  (CC_OFF + CC_SZ)
#define IDXF_SZ   N_
#define LOSS_OFF  (IDXF_OFF + IDXF_SZ)

// Output layout (floats)
#define OUT_ZQ    0
#define OUT_LOSS  8388608
#define OUT_IDX   8388609

__device__ __forceinline__ ushort f2bf(float f) {   // RNE f32 -> bf16 (finite data)
    uint x = __float_as_uint(f);
    uint r = x + 0x7fffu + ((x >> 16) & 1u);
    return (ushort)(r >> 16);
}

// ---------------------------------------------------------------------------
// Transpose: z [B][C][HW] f32 -> z_flat [N][C] f32 (exact copy) + zh bf16
// ---------------------------------------------------------------------------
__global__ __launch_bounds__(256) void transpose_z(const float* __restrict__ z,
                                                   float* __restrict__ zf,
                                                   ushort* __restrict__ zh) {
    __shared__ float ld[64][65];
    const int t = threadIdx.x;
    const int mt = blockIdx.x, ct = blockIdx.y, b = blockIdx.z;
    {
        const int cl = t >> 4, m4 = (t & 15) * 4;
#pragma unroll
        for (int cc = 0; cc < 4; ++cc) {
            const int c = ct * 64 + cc * 16 + cl;
            float4 v = *(const float4*)&z[((size_t)(b * 512 + c)) * 1024 + mt * 64 + m4];
            ld[cc * 16 + cl][m4 + 0] = v.x; ld[cc * 16 + cl][m4 + 1] = v.y;
            ld[cc * 16 + cl][m4 + 2] = v.z; ld[cc * 16 + cl][m4 + 3] = v.w;
        }
    }
    __syncthreads();
    {
        const int nl = t >> 4, c4 = (t & 15) * 4;
#pragma unroll
        for (int nn = 0; nn < 4; ++nn) {
            const int n_local = nn * 16 + nl;
            const size_t n = (size_t)b * 1024 + mt * 64 + n_local;
            float4 w;
            w.x = ld[c4 + 0][n_local]; w.y = ld[c4 + 1][n_local];
            w.z = ld[c4 + 2][n_local]; w.w = ld[c4 + 3][n_local];
            *(float4*)&zf[n * 512 + ct * 64 + c4] = w;
            ushort4 h; h.x = f2bf(w.x); h.y = f2bf(w.y); h.z = f2bf(w.z); h.w = f2bf(w.w);
            *(ushort4*)&zh[n * 512 + ct * 64 + c4] = h;
        }
    }
}

// ---------------------------------------------------------------------------
// qc GEMM: 128x128 tile, 8x8 per thread. Per-element math IDENTICAL to the
// passing kernels: single accumulator, d ascending, FMA chain. Fused qh.
// ---------------------------------------------------------------------------
__global__ __launch_bounds__(256) void qc_gemm(const float* __restrict__ emb,
                                               const float* __restrict__ W,
                                               const float* __restrict__ bias,
                                               float* __restrict__ qc,
                                               ushort* __restrict__ qh) {
    __shared__ float As[16][132];   // [d_local][k_local], pad 132
    __shared__ float Bs[16][132];   // [d_local][c_local]
    const int t   = threadIdx.x;
    const int k0  = blockIdx.x * 128;
    const int c0  = blockIdx.y * 128;
    const int ty  = t >> 4, tx = t & 15;
    const int row = t >> 1;          // 0..127 (staging row)
    const int dq  = (t & 1) * 8;     // staging d-offset 0/8

    const float* pa = emb + (size_t)(k0 + row) * 512 + dq;
    const float* pb = W   + (size_t)(c0 + row) * 512 + dq;
    float4 ra0 = *(const float4*)&pa[0];
    float4 ra1 = *(const float4*)&pa[4];
    float4 rb0 = *(const float4*)&pb[0];
    float4 rb1 = *(const float4*)&pb[4];

    float acc[2][2][4][4] = {};   // [ih][jh][i][j]
    for (int d0 = 0; d0 < 512; d0 += 16) {
        __syncthreads();
        As[dq + 0][row] = ra0.x; As[dq + 1][row] = ra0.y;
        As[dq + 2][row] = ra0.z; As[dq + 3][row] = ra0.w;
        As[dq + 4][row] = ra1.x; As[dq + 5][row] = ra1.y;
        As[dq + 6][row] = ra1.z; As[dq + 7][row] = ra1.w;
        Bs[dq + 0][row] = rb0.x; Bs[dq + 1][row] = rb0.y;
        Bs[dq + 2][row] = rb0.z; Bs[dq + 3][row] = rb0.w;
        Bs[dq + 4][row] = rb1.x; Bs[dq + 5][row] = rb1.y;
        Bs[dq + 6][row] = rb1.z; Bs[dq + 7][row] = rb1.w;
        if (d0 + 16 < 512) {   // issue next-tile loads early; consumed next iter
            ra0 = *(const float4*)&pa[d0 + 16];
            ra1 = *(const float4*)&pa[d0 + 20];
            rb0 = *(const float4*)&pb[d0 + 16];
            rb1 = *(const float4*)&pb[d0 + 20];
        }
        __syncthreads();
#pragma unroll
        for (int dd = 0; dd < 16; ++dd) {
            float4 a0 = *(const float4*)&As[dd][ty * 4];
            float4 a1 = *(const float4*)&As[dd][64 + ty * 4];
            float4 b0 = *(const float4*)&Bs[dd][tx * 4];
            float4 b1 = *(const float4*)&Bs[dd][64 + tx * 4];
            float aa[2][4] = {{a0.x, a0.y, a0.z, a0.w}, {a1.x, a1.y, a1.z, a1.w}};
            float bb[2][4] = {{b0.x, b0.y, b0.z, b0.w}, {b1.x, b1.y, b1.z, b1.w}};
#pragma unroll
            for (int ih = 0; ih < 2; ++ih)
#pragma unroll
                for (int jh = 0; jh < 2; ++jh)
#pragma unroll
                    for (int i = 0; i < 4; ++i)
#pragma unroll
                        for (int j = 0; j < 4; ++j)
                            acc[ih][jh][i][j] += aa[ih][i] * bb[jh][j];  // fma, d asc
        }
    }
#pragma unroll
    for (int ih = 0; ih < 2; ++ih)
#pragma unroll
        for (int i = 0; i < 4; ++i) {
            const size_t kr = (size_t)(k0 + ih * 64 + ty * 4 + i) * 512;
#pragma unroll
            for (int jh = 0; jh < 2; ++jh) {
                const int cb = c0 + jh * 64 + tx * 4;
                float4 v;
                v.x = acc[ih][jh][i][0] + bias[cb + 0];
                v.y = acc[ih][jh][i][1] + bias[cb + 1];
                v.z = acc[ih][jh][i][2] + bias[cb + 2];
                v.w = acc[ih][jh][i][3] + bias[cb + 3];
                *(float4*)&qc[kr + cb] = v;
                ushort4 h; h.x = f2bf(v.x); h.y = f2bf(v.y); h.z = f2bf(v.z); h.w = f2bf(v.w);
                *(ushort4*)&qh[kr + cb] = h;
            }
        }
}

// ---------------------------------------------------------------------------
// Row norms, numpy pairwise structure (UNCHANGED rounding).
// ---------------------------------------------------------------------------
__device__ __forceinline__ float pairwise512(const float* __restrict__ row) {
#pragma clang fp contract(off)
    float s128[4];
#pragma unroll
    for (int blk = 0; blk < 4; ++blk) {
        float r[8];
#pragma unroll
        for (int j = 0; j < 8; ++j) { float v = row[blk * 128 + j]; r[j] = v * v; }
#pragma unroll 1
        for (int i = 8; i < 128; i += 8) {
#pragma unroll
            for (int j = 0; j < 8; ++j) {
                float v = row[blk * 128 + i + j];
                float sq = v * v;
                r[j] = r[j] + sq;
            }
        }
        s128[blk] = ((r[0] + r[1]) + (r[2] + r[3])) + ((r[4] + r[5]) + (r[6] + r[7]));
    }
    return (s128[0] + s128[1]) + (s128[2] + s128[3]);
}

__global__ __launch_bounds__(256) void qnorm_pairwise(const float* __restrict__ qc,
                                                      float* __restrict__ qn) {
    const int k = blockIdx.x * 256 + threadIdx.x;
    qn[k] = pairwise512(qc + (size_t)k * C_);
}

__global__ __launch_bounds__(256) void znorm_pairwise(const float* __restrict__ zf,
                                                      float* __restrict__ zn) {
    const int n = blockIdx.x * 256 + threadIdx.x;
    zn[n] = pairwise512(zf + (size_t)n * C_);
}

// ---------------------------------------------------------------------------
// Phase A v3: m201-geometry. 512 threads / 8 waves, tile 256k x 256n, BK=64,
// double-buffered 128 KB LDS, T2 XOR swizzle (source-permute + read-XOR).
// Per wave: 128k x 64n -> acc[8][4], 64 MFMA per K-step. Each wave covers a
// full 128-code window -> writes its window top-2 directly (no cross-wave
// merge). 2-phase loop: stage(next) -> compute(cur) -> sync -> flip.
// ---------------------------------------------------------------------------
__global__ __launch_bounds__(512, 2) void phaseA(const ushort* __restrict__ qh,
                                                 const ushort* __restrict__ zh,
                                                 const float* __restrict__ qn,
                                                 float* __restrict__ wtop) {
    __shared__ short lq[2][256 * 64];   // [buf][k_local][c 64] bf16, swizzled
    __shared__ short lz[2][256 * 64];   // [buf][n_local][c 64] bf16, swizzled
    const int t    = threadIdx.x;
    const int lane = t & 63;
    const int wv   = t >> 6;        // 0..7
    const int wk   = wv >> 2;       // 0..1  k-half (128 codes = one window)
    const int wn   = wv & 3;        // 0..3  n-quarter (64 rows)
    const int n0   = blockIdx.x * 256;
    const int k0   = blockIdx.y * 256;

    auto stage = [&](int b, int c0) {
#pragma unroll
        for (int p = 0; p < 4; ++p) {
            const int ch  = t + p * 512;            // 0..2047 LDS 16B-chunks
            const int row = ch >> 3;                // 0..255
            const int cs  = ((ch ^ row) & 7) * 8;   // swizzled SOURCE elem offset
            __builtin_amdgcn_global_load_lds(
                (const __attribute__((address_space(1))) uint*)(qh + (size_t)(k0 + row) * 512 + c0 + cs),
                (__attribute__((address_space(3))) uint*)&lq[b][ch * 8], 16, 0, 0);
            __builtin_amdgcn_global_load_lds(
                (const __attribute__((address_space(1))) uint*)(zh + (size_t)(n0 + row) * 512 + c0 + cs),
                (__attribute__((address_space(3))) uint*)&lz[b][ch * 8], 16, 0, 0);
        }
    };

    f32x4 acc[8][4];
#pragma unroll
    for (int i = 0; i < 8; ++i)
#pragma unroll
        for (int j = 0; j < 4; ++j) acc[i][j] = (f32x4){0.f, 0.f, 0.f, 0.f};

    stage(0, 0);
    __syncthreads();

    int cur = 0;
    for (int it = 0; it < 8; ++it) {
        if (it < 7) stage(cur ^ 1, (it + 1) * 64);   // prefetch next c-chunk
#pragma unroll
        for (int kk = 0; kk < 64; kk += 32) {
            const int co = kk + ((lane >> 4) << 3);   // logical elem offset
            short8 af[8], bf[4];
#pragma unroll
            for (int i = 0; i < 8; ++i) {
                const int rA = wk * 128 + i * 16 + (lane & 15);
                af[i] = *(const short8*)&lq[cur][rA * 64 + (co ^ ((rA & 7) << 3))];
            }
#pragma unroll
            for (int j = 0; j < 4; ++j) {
                const int rB = wn * 64 + j * 16 + (lane & 15);
                bf[j] = *(const short8*)&lz[cur][rB * 64 + (co ^ ((rB & 7) << 3))];
            }
#pragma unroll
            for (int i = 0; i < 8; ++i)
#pragma unroll
                for (int j = 0; j < 4; ++j)
                    acc[i][j] = __builtin_amdgcn_mfma_f32_16x16x32_bf16(af[i], bf[j], acc[i][j], 0, 0, 0);
        }
        if (it < 7) {
            __syncthreads();   // drains vmcnt(0): next chunk landed; flip safe
            cur ^= 1;
        }
    }

    // Epilogue: per n-column top-2 over this wave's 128 k's (= one window)
    const int q4 = (lane >> 4) * 4;
    float v1[4], v2[4];
    int   k1[4], k2[4];
#pragma unroll
    for (int in = 0; in < 4; ++in) { v1[in] = 1e30f; v2[in] = 1e30f; k1[in] = 0; k2[in] = 0; }

#pragma unroll
    for (int ik = 0; ik < 8; ++ik) {
        float qv[4];
#pragma unroll
        for (int r = 0; r < 4; ++r)
            qv[r] = qn[k0 + wk * 128 + ik * 16 + q4 + r];
#pragma unroll
        for (int in = 0; in < 4; ++in) {
#pragma unroll
            for (int r = 0; r < 4; ++r) {
                const float val = qv[r] - 2.0f * acc[ik][in][r];
                const int   kg  = k0 + wk * 128 + ik * 16 + q4 + r;
                if (val < v1[in]) { v2[in] = v1[in]; k2[in] = k1[in]; v1[in] = val; k1[in] = kg; }
                else if (val < v2[in]) { v2[in] = val; k2[in] = kg; }
            }
        }
    }
    // butterfly across the 4 k-subgroups (lane>>4)
#pragma unroll
    for (int m = 16; m <= 32; m <<= 1) {
#pragma unroll
        for (int in = 0; in < 4; ++in) {
            const float ov1 = __shfl_xor(v1[in], m, 64);
            const int   ok1 = __shfl_xor(k1[in], m, 64);
            const float ov2 = __shfl_xor(v2[in], m, 64);
            const int   ok2 = __shfl_xor(k2[in], m, 64);
            float nv1, nv2; int nk1, nk2;
            if (ov1 < v1[in]) {
                nv1 = ov1; nk1 = ok1;
                if (v1[in] < ov2) { nv2 = v1[in]; nk2 = k1[in]; } else { nv2 = ov2; nk2 = ok2; }
            } else {
                nv1 = v1[in]; nk1 = k1[in];
                if (ov1 < v2[in]) { nv2 = ov1; nk2 = ok1; } else { nv2 = v2[in]; nk2 = k2[in]; }
            }
            v1[in] = nv1; k1[in] = nk1; v2[in] = nv2; k2[in] = nk2;
        }
    }
    // each wave writes its window's 64 n-columns (lanes 0..15 write)
    if ((lane >> 4) == 0) {
        const int w = blockIdx.y * 2 + wk;
#pragma unroll
        for (int in = 0; in < 4; ++in) {
            const int n = n0 + wn * 64 + in * 16 + (lane & 15);
            float4 o; o.x = v1[in]; o.y = __int_as_float(k1[in]);
            o.z = v2[in]; o.w = __int_as_float(k2[in]);
            *(float4*)&wtop[((size_t)w * N_ + n) * 4] = o;
        }
    }
}

// ---------------------------------------------------------------------------
// Phase B: rowmin over windows; collect candidates within EPS of rowmin.
// ---------------------------------------------------------------------------
__global__ __launch_bounds__(256) void phaseB(const float* __restrict__ wtop,
                                              int* __restrict__ cand_k,
                                              int* __restrict__ cand_cnt) {
    const int n = blockIdx.x * 256 + threadIdx.x;
    float rmin = 1e30f;
    for (int w = 0; w < 64; ++w)
        rmin = fminf(rmin, wtop[((size_t)w * N_ + n) * 4]);
    const float thr = rmin + EPS_;
    int cnt = 0;
    for (int w = 0; w < 64; ++w) {
        float4 e = *(const float4*)&wtop[((size_t)w * N_ + n) * 4];
        if (e.x <= thr && cnt < 16) cand_k[n * 16 + cnt++] = __float_as_int(e.y);
        if (e.z <= thr && cnt < 16) cand_k[n * 16 + cnt++] = __float_as_int(e.w);
    }
    cand_cnt[n] = cnt;
}

// ---------------------------------------------------------------------------
// Phase C v2 (unchanged from round 6): exact recheck with cnt==1 early-exit,
// coalesced LDS staging, 2 lane-groups; FMA chain bit-identical to round 2.
// ---------------------------------------------------------------------------
__global__ __launch_bounds__(256) void phaseC(const float* __restrict__ zf,
                                              const float* __restrict__ qc,
                                              const float* __restrict__ zn,
                                              const float* __restrict__ qn,
                                              const int* __restrict__ cand_k,
                                              const int* __restrict__ cand_cnt,
                                              int* __restrict__ idxf,
                                              float* __restrict__ out_idx) {
    __shared__ float zr[4][512];
    __shared__ float ql[4][2][512];   // [wave][group][c]
    const int wv   = threadIdx.x >> 6;
    const int lane = threadIdx.x & 63;
    const int r    = blockIdx.x * 4 + wv;
    const int cnt  = cand_cnt[r];

    if (cnt == 1) {
        if (lane == 0) { const int k = cand_k[r * 16]; idxf[r] = k; out_idx[r] = (float)k; }
        return;
    }

    *(float4*)&zr[wv][lane * 8]     = *(const float4*)&zf[(size_t)r * 512 + lane * 8];
    *(float4*)&zr[wv][lane * 8 + 4] = *(const float4*)&zf[(size_t)r * 512 + lane * 8 + 4];

    const int g  = lane >> 5;          // candidate group 0/1
    const int cl = (lane & 31) * 16;   // this lane's 16-float slice
    const int steps = (cnt + 1) >> 1;
    const float znr = zn[r];

    auto cand_of = [&](int s) {
        const int ci = 2 * s + g;
        return cand_k[r * 16 + (ci < cnt ? ci : 0)];
    };

    int k_cur = cand_of(0);
    const float* q0 = qc + (size_t)k_cur * 512 + cl;
    float4 p0 = *(const float4*)&q0[0];
    float4 p1 = *(const float4*)&q0[4];
    float4 p2 = *(const float4*)&q0[8];
    float4 p3 = *(const float4*)&q0[12];

    float bd = 1e30f;
    int   bi = 0x7fffffff;

    for (int s = 0; s < steps; ++s) {
        *(float4*)&ql[wv][g][cl + 0]  = p0;
        *(float4*)&ql[wv][g][cl + 4]  = p1;
        *(float4*)&ql[wv][g][cl + 8]  = p2;
        *(float4*)&ql[wv][g][cl + 12] = p3;

        int k_next = 0;
        if (s + 1 < steps) {
            k_next = cand_of(s + 1);
            const float* qn_ = qc + (size_t)k_next * 512 + cl;
            p0 = *(const float4*)&qn_[0];
            p1 = *(const float4*)&qn_[4];
            p2 = *(const float4*)&qn_[8];
            p3 = *(const float4*)&qn_[12];
        }

        float acc = 0.f;
#pragma unroll 16
        for (int c = 0; c < 512; c += 4) {
            float4 zv = *(const float4*)&zr[wv][c];
            float4 qv = *(const float4*)&ql[wv][g][c];
            acc = fmaf(zv.x, qv.x, acc);
            acc = fmaf(zv.y, qv.y, acc);
            acc = fmaf(zv.z, qv.z, acc);
            acc = fmaf(zv.w, qv.w, acc);
        }
        const float T = znr + qn[k_cur];
        const float d = T - 2.0f * acc;
        const bool valid = (2 * s + g) < cnt;
        if (valid && (d < bd || (d == bd && k_cur < bi))) { bd = d; bi = k_cur; }
        k_cur = k_next;
    }

    const float od = __shfl_xor(bd, 32, 64);
    const int   oi = __shfl_xor(bi, 32, 64);
    if (od < bd || (od == bd && oi < bi)) { bd = od; bi = oi; }

    if (lane == 0) { idxf[r] = bi; out_idx[r] = (float)bi; }
}

// ---------------------------------------------------------------------------
// Gather z_q = qc[idx], transpose-write to [B,C,H,W], fused loss.
// ---------------------------------------------------------------------------
__global__ __launch_bounds__(256) void gather_out(const float* __restrict__ z,
                                                  const float* __restrict__ qc,
                                                  const int* __restrict__ idxf,
                                                  float* __restrict__ zq_out,
                                                  float* __restrict__ loss_acc) {
    __shared__ int   idxs[64];
    __shared__ float zqs[64][65];
    __shared__ float wsum[4];
    const int t  = threadIdx.x;
    const int mc = blockIdx.x;
    const int cc = blockIdx.y;
    const int bz = blockIdx.z;

    if (t < 64) idxs[t] = idxf[bz * 1024 + mc * 64 + t];
    __syncthreads();
    {
        const int row  = t >> 2;
        const int coff = (t & 3) * 16;
        const float* src = qc + (size_t)idxs[row] * 512 + cc * 64 + coff;
#pragma unroll
        for (int v = 0; v < 4; ++v) {
            float4 q = *(const float4*)&src[v * 4];
            zqs[row][coff + v * 4 + 0] = q.x;
            zqs[row][coff + v * 4 + 1] = q.y;
            zqs[row][coff + v * 4 + 2] = q.z;
            zqs[row][coff + v * 4 + 3] = q.w;
        }
    }
    __syncthreads();

    float ls = 0.f;
    {
        const int c_local = t >> 2;
        const int mg      = (t & 3) * 16;
        const size_t gbase = ((size_t)(bz * 512 + cc * 64 + c_local)) * 1024 + mc * 64 + mg;
#pragma unroll
        for (int v = 0; v < 4; ++v) {
            const int m = mg + v * 4;
            float4 w;
            w.x = zqs[m + 0][c_local];
            w.y = zqs[m + 1][c_local];
            w.z = zqs[m + 2][c_local];
            w.w = zqs[m + 3][c_local];
            float4 zv = *(const float4*)&z[gbase + v * 4];
            float dx = w.x - zv.x, dy = w.y - zv.y, dz = w.z - zv.z, dw = w.w - zv.w;
            ls += dx * dx + dy * dy + dz * dz + dw * dw;
            *(float4*)&zq_out[gbase + v * 4] = w;
        }
    }
#pragma unroll
    for (int m = 32; m; m >>= 1) ls += __shfl_xor(ls, m, 64);
    const int lane = t & 63, wvv = t >> 6;
    if (lane == 0) wsum[wvv] = ls;
    __syncthreads();
    if (t == 0) atomicAdd(loss_acc, wsum[0] + wsum[1] + wsum[2] + wsum[3]);
}

__global__ void zero_loss(float* __restrict__ loss_acc) { loss_acc[0] = 0.f; }

__global__ void finalize(const float* __restrict__ loss_acc,
                         float* __restrict__ out_loss) {
    out_loss[0] = 1.25f * loss_acc[0] / 8388608.0f;
}

// ---------------------------------------------------------------------------
extern "C" void kernel_launch(void* const* d_in, const int* in_sizes, int n_in,
                              void* d_out, int out_size, void* d_ws, size_t ws_size,
                              hipStream_t stream) {
    const float* z    = (const float*)d_in[0];
    const float* emb  = (const float*)d_in[1];
    const float* W    = (const float*)d_in[2];
    const float* bias = (const float*)d_in[3];
    float* ws = (float*)d_ws;

    float*  qc       = ws + QC_OFF;
    float*  qn       = ws + QN_OFF;
    float*  zn       = ws + ZN_OFF;
    float*  zf       = ws + ZF_OFF;
    ushort* zh       = (ushort*)(ws + ZH_OFF);
    ushort* qh       = (ushort*)(ws + QH_OFF);
    float*  wtop     = ws + WT_OFF;
    int*    cand_k   = (int*)(ws + CK_OFF);
    int*    cand_cnt = (int*)(ws + CC_OFF);
    int*    idxf     = (int*)(ws + IDXF_OFF);
    float*  loss_acc = ws + LOSS_OFF;
    float*  out      = (float*)d_out;

    zero_loss<<<1, 1, 0, stream>>>(loss_acc);
    transpose_z<<<dim3(16, 8, 16), 256, 0, stream>>>(z, zf, zh);
    qc_gemm<<<dim3(K_ / 128, C_ / 128), 256, 0, stream>>>(emb, W, bias, qc, qh);
    qnorm_pairwise<<<K_ / 256, 256, 0, stream>>>(qc, qn);
    znorm_pairwise<<<N_ / 256, 256, 0, stream>>>(zf, zn);
    phaseA<<<dim3(N_ / 256, K_ / 256), 512, 0, stream>>>(qh, zh, qn, wtop);
    phaseB<<<N_ / 256, 256, 0, stream>>>(wtop, cand_k, cand_cnt);
    phaseC<<<N_ / 4, 256, 0, stream>>>(zf, qc, zn, qn, cand_k, cand_cnt, idxf, out + OUT_IDX);
    gather_out<<<dim3(16, 8, B_), 256, 0, stream>>>(z, qc, idxf, out + OUT_ZQ, loss_acc);
    finalize<<<1, 1, 0, stream>>>(loss_acc, out + OUT_LOSS);
}

// Round 8
// 421.091 us; speedup vs baseline: 4.9402x; 1.1049x over previous
//
#include <hip/hip_runtime.h>

typedef unsigned int uint;
typedef unsigned short ushort;
typedef __attribute__((ext_vector_type(8))) short short8;
typedef __attribute__((ext_vector_type(4))) float f32x4;

// Problem constants
#define B_   16
#define C_   512     // e_dim
#define HW_  1024    // 32*32
#define N_   16384   // B*H*W
#define K_   8192    // n_e
#define EPS_ 0.25f   // candidate margin

// Workspace layout (in float units)
#define QC_OFF    0u
#define QC_SZ     (K_ * C_)
#define QN_OFF    (QC_OFF + QC_SZ)
#define QN_SZ     K_
#define ZN_OFF    (QN_OFF + QN_SZ)
#define ZN_SZ     N_
#define ZF_OFF    (ZN_OFF + ZN_SZ)
#define ZF_SZ     (N_ * C_)
#define ZH_OFF    (ZF_OFF + ZF_SZ)
#define ZH_SZ     (N_ * C_ / 2)
#define QH_OFF    (ZH_OFF + ZH_SZ)
#define QH_SZ     (K_ * C_ / 2)
#define WT_OFF    (QH_OFF + QH_SZ)
#define WT_SZ     (64 * N_ * 4)
#define CK_OFF    (WT_OFF + WT_SZ)
#define CK_SZ     (N_ * 16)
#define CC_OFF    (CK_OFF + CK_SZ)
#define CC_SZ     N_
#define IDXF_OFF  (CC_OFF + CC_SZ)
#define IDXF_SZ   N_
#define LOSS_OFF  (IDXF_OFF + IDXF_SZ)

// Output layout (floats)
#define OUT_ZQ    0
#define OUT_LOSS  8388608
#define OUT_IDX   8388609

__device__ __forceinline__ ushort f2bf(float f) {   // RNE f32 -> bf16
    uint x = __float_as_uint(f);
    uint r = x + 0x7fffu + ((x >> 16) & 1u);
    return (ushort)(r >> 16);
}

// ---------------------------------------------------------------------------
// Transpose: z [B][C][HW] f32 -> z_flat [N][C] f32 (exact copy) + zh bf16
// ---------------------------------------------------------------------------
__global__ __launch_bounds__(256) void transpose_z(const float* __restrict__ z,
                                                   float* __restrict__ zf,
                                                   ushort* __restrict__ zh) {
    __shared__ float ld[64][65];
    const int t = threadIdx.x;
    const int mt = blockIdx.x, ct = blockIdx.y, b = blockIdx.z;
    {
        const int cl = t >> 4, m4 = (t & 15) * 4;
#pragma unroll
        for (int cc = 0; cc < 4; ++cc) {
            const int c = ct * 64 + cc * 16 + cl;
            float4 v = *(const float4*)&z[((size_t)(b * 512 + c)) * 1024 + mt * 64 + m4];
            ld[cc * 16 + cl][m4 + 0] = v.x; ld[cc * 16 + cl][m4 + 1] = v.y;
            ld[cc * 16 + cl][m4 + 2] = v.z; ld[cc * 16 + cl][m4 + 3] = v.w;
        }
    }
    __syncthreads();
    {
        const int nl = t >> 4, c4 = (t & 15) * 4;
#pragma unroll
        for (int nn = 0; nn < 4; ++nn) {
            const int n_local = nn * 16 + nl;
            const size_t n = (size_t)b * 1024 + mt * 64 + n_local;
            float4 w;
            w.x = ld[c4 + 0][n_local]; w.y = ld[c4 + 1][n_local];
            w.z = ld[c4 + 2][n_local]; w.w = ld[c4 + 3][n_local];
            *(float4*)&zf[n * 512 + ct * 64 + c4] = w;
            ushort4 h; h.x = f2bf(w.x); h.y = f2bf(w.y); h.z = f2bf(w.z); h.w = f2bf(w.w);
            *(ushort4*)&zh[n * 512 + ct * 64 + c4] = h;
        }
    }
}

// ---------------------------------------------------------------------------
// qc GEMM: unchanged math (single accumulator, d ascending FMA chain) + qh.
// ---------------------------------------------------------------------------
__global__ __launch_bounds__(256) void qc_gemm(const float* __restrict__ emb,
                                               const float* __restrict__ W,
                                               const float* __restrict__ bias,
                                               float* __restrict__ qc,
                                               ushort* __restrict__ qh) {
    __shared__ float As[16][132];
    __shared__ float Bs[16][132];
    const int t   = threadIdx.x;
    const int k0  = blockIdx.x * 128;
    const int c0  = blockIdx.y * 128;
    const int ty  = t >> 4, tx = t & 15;
    const int row = t >> 1;
    const int dq  = (t & 1) * 8;

    const float* pa = emb + (size_t)(k0 + row) * 512 + dq;
    const float* pb = W   + (size_t)(c0 + row) * 512 + dq;
    float4 ra0 = *(const float4*)&pa[0];
    float4 ra1 = *(const float4*)&pa[4];
    float4 rb0 = *(const float4*)&pb[0];
    float4 rb1 = *(const float4*)&pb[4];

    float acc[2][2][4][4] = {};
    for (int d0 = 0; d0 < 512; d0 += 16) {
        __syncthreads();
        As[dq + 0][row] = ra0.x; As[dq + 1][row] = ra0.y;
        As[dq + 2][row] = ra0.z; As[dq + 3][row] = ra0.w;
        As[dq + 4][row] = ra1.x; As[dq + 5][row] = ra1.y;
        As[dq + 6][row] = ra1.z; As[dq + 7][row] = ra1.w;
        Bs[dq + 0][row] = rb0.x; Bs[dq + 1][row] = rb0.y;
        Bs[dq + 2][row] = rb0.z; Bs[dq + 3][row] = rb0.w;
        Bs[dq + 4][row] = rb1.x; Bs[dq + 5][row] = rb1.y;
        Bs[dq + 6][row] = rb1.z; Bs[dq + 7][row] = rb1.w;
        if (d0 + 16 < 512) {
            ra0 = *(const float4*)&pa[d0 + 16];
            ra1 = *(const float4*)&pa[d0 + 20];
            rb0 = *(const float4*)&pb[d0 + 16];
            rb1 = *(const float4*)&pb[d0 + 20];
        }
        __syncthreads();
#pragma unroll
        for (int dd = 0; dd < 16; ++dd) {
            float4 a0 = *(const float4*)&As[dd][ty * 4];
            float4 a1 = *(const float4*)&As[dd][64 + ty * 4];
            float4 b0 = *(const float4*)&Bs[dd][tx * 4];
            float4 b1 = *(const float4*)&Bs[dd][64 + tx * 4];
            float aa[2][4] = {{a0.x, a0.y, a0.z, a0.w}, {a1.x, a1.y, a1.z, a1.w}};
            float bb[2][4] = {{b0.x, b0.y, b0.z, b0.w}, {b1.x, b1.y, b1.z, b1.w}};
#pragma unroll
            for (int ih = 0; ih < 2; ++ih)
#pragma unroll
                for (int jh = 0; jh < 2; ++jh)
#pragma unroll
                    for (int i = 0; i < 4; ++i)
#pragma unroll
                        for (int j = 0; j < 4; ++j)
                            acc[ih][jh][i][j] += aa[ih][i] * bb[jh][j];
        }
    }
#pragma unroll
    for (int ih = 0; ih < 2; ++ih)
#pragma unroll
        for (int i = 0; i < 4; ++i) {
            const size_t kr = (size_t)(k0 + ih * 64 + ty * 4 + i) * 512;
#pragma unroll
            for (int jh = 0; jh < 2; ++jh) {
                const int cb = c0 + jh * 64 + tx * 4;
                float4 v;
                v.x = acc[ih][jh][i][0] + bias[cb + 0];
                v.y = acc[ih][jh][i][1] + bias[cb + 1];
                v.z = acc[ih][jh][i][2] + bias[cb + 2];
                v.w = acc[ih][jh][i][3] + bias[cb + 3];
                *(float4*)&qc[kr + cb] = v;
                ushort4 h; h.x = f2bf(v.x); h.y = f2bf(v.y); h.z = f2bf(v.z); h.w = f2bf(v.w);
                *(ushort4*)&qh[kr + cb] = h;
            }
        }
}

// ---------------------------------------------------------------------------
// Row norms, numpy pairwise structure (UNCHANGED rounding).
// ---------------------------------------------------------------------------
__device__ __forceinline__ float pairwise512(const float* __restrict__ row) {
#pragma clang fp contract(off)
    float s128[4];
#pragma unroll
    for (int blk = 0; blk < 4; ++blk) {
        float r[8];
#pragma unroll
        for (int j = 0; j < 8; ++j) { float v = row[blk * 128 + j]; r[j] = v * v; }
#pragma unroll 1
        for (int i = 8; i < 128; i += 8) {
#pragma unroll
            for (int j = 0; j < 8; ++j) {
                float v = row[blk * 128 + i + j];
                float sq = v * v;
                r[j] = r[j] + sq;
            }
        }
        s128[blk] = ((r[0] + r[1]) + (r[2] + r[3])) + ((r[4] + r[5]) + (r[6] + r[7]));
    }
    return (s128[0] + s128[1]) + (s128[2] + s128[3]);
}

__global__ __launch_bounds__(256) void qnorm_pairwise(const float* __restrict__ qc,
                                                      float* __restrict__ qn) {
    const int k = blockIdx.x * 256 + threadIdx.x;
    qn[k] = pairwise512(qc + (size_t)k * C_);
}

__global__ __launch_bounds__(256) void znorm_pairwise(const float* __restrict__ zf,
                                                      float* __restrict__ zn) {
    const int n = blockIdx.x * 256 + threadIdx.x;
    zn[n] = pairwise512(zf + (size_t)n * C_);
}

// ---------------------------------------------------------------------------
// Phase A v4: m201-style 8-phase schedule. 256k x 256n x BK=64, 8 waves
// (2 k-half x 4 n-quarter), per-wave 128x64, 64 MFMA/K-tile in 4 quadrant
// phases of 16. LDS: 2 bufs x {A,B} x 2 halves (16KB each) = 128KB.
// Counted vmcnt(4) at phases 4/8 ONLY (raw s_barrier everywhere - no
// __syncthreads, which would drain vmcnt(0)). Half-tile h is staged only in
// the phase after its last ds-read + barrier. Tail stays uniform via dummy
// re-stages ((&7) wrap) into dead halves. Accumulation order per acc element
// unchanged vs v3 -> results bit-identical.
// ---------------------------------------------------------------------------
#define PH_BAR()  __builtin_amdgcn_s_barrier()
#define PH_LGKM() asm volatile("s_waitcnt lgkmcnt(0)" ::: "memory")
#define PH_VM4()  asm volatile("s_waitcnt vmcnt(4)" ::: "memory")

__global__ __launch_bounds__(512, 2) void phaseA(const ushort* __restrict__ qh,
                                                 const ushort* __restrict__ zh,
                                                 const float* __restrict__ qn,
                                                 float* __restrict__ wtop) {
    __shared__ short lq[2][2][128 * 64];   // [buf][k-half][row 128][c 64] swizzled
    __shared__ short lz[2][2][128 * 64];   // [buf][n-half][row 128][c 64] swizzled
    const int t    = threadIdx.x;
    const int lane = t & 63;
    const int wv   = t >> 6;        // 0..7
    const int wk   = wv >> 2;       // 0..1  k-half (128 codes = one window)
    const int wn   = wv & 3;        // 0..3  n-quarter (64 rows)
    const int n0   = blockIdx.x * 256;
    const int k0   = blockIdx.y * 256;

    // stage one 16KB half-tile: h = 0,1 -> A halves (qh); 2,3 -> B halves (zh)
    auto stage_half = [&](int b, int h, int cchunk) {
        const int c0 = cchunk * 64;
#pragma unroll
        for (int p = 0; p < 2; ++p) {
            const int ch  = t + p * 512;            // 0..1023 16B chunks
            const int row = ch >> 3;                // 0..127
            const int ce  = (((ch ^ row) & 7) << 3);
            if (h < 2) {
                __builtin_amdgcn_global_load_lds(
                    (const __attribute__((address_space(1))) uint*)(qh + (size_t)(k0 + h * 128 + row) * 512 + c0 + ce),
                    (__attribute__((address_space(3))) uint*)&lq[b][h][ch * 8], 16, 0, 0);
            } else {
                __builtin_amdgcn_global_load_lds(
                    (const __attribute__((address_space(1))) uint*)(zh + (size_t)(n0 + (h - 2) * 128 + row) * 512 + c0 + ce),
                    (__attribute__((address_space(3))) uint*)&lz[b][h - 2][ch * 8], 16, 0, 0);
            }
        }
    };

    auto rdA = [&](int b, int kk, int i) -> short8 {   // i: 0..7 within wave's k-half
        const int rl = i * 16 + (lane & 15);
        const int co = kk * 32 + ((lane >> 4) << 3);
        return *(const short8*)&lq[b][wk][rl * 64 + (co ^ ((rl & 7) << 3))];
    };
    auto rdB = [&](int b, int kk, int j) -> short8 {   // j: 0..3 within wave's 64 n
        const int rg = wn * 64 + j * 16 + (lane & 15);
        const int co = kk * 32 + ((lane >> 4) << 3);
        return *(const short8*)&lz[b][rg >> 7][(rg & 127) * 64 + (co ^ ((rg & 7) << 3))];
    };

    f32x4 acc[8][4];
#pragma unroll
    for (int i = 0; i < 8; ++i)
#pragma unroll
        for (int j = 0; j < 4; ++j) acc[i][j] = (f32x4){0.f, 0.f, 0.f, 0.f};

    // Prologue: buf0 <- chunk 0 (all 4 halves); buf1 A-halves <- chunk 1.
    stage_half(0, 0, 0); stage_half(0, 1, 0); stage_half(0, 2, 0); stage_half(0, 3, 0);
    stage_half(1, 0, 1); stage_half(1, 1, 1);
    PH_VM4();                 // oldest 8 loads (all of buf0) landed
    PH_BAR();

    short8 a0[2][4], a1[2][4], b0[2][2], b1[2][2];

#pragma unroll 1
    for (int I = 0; I < 4; ++I) {
        const int t1 = 2 * I + 1;          // B-halves for buf1's K-tile (this iter)
        const int t2 = (2 * I + 2) & 7;    // buf0 refill chunk (dummy-wraps at tail)
        const int t3 = (2 * I + 3) & 7;    // buf1 A refill chunk (dummy-wraps)

        // ================= K-tile 2I on buf0 =================
        // ph1: reads af[kk][0-3], bf[kk][0-1]; stage B_h0(t1)->buf1
#pragma unroll
        for (int kk = 0; kk < 2; ++kk) {
#pragma unroll
            for (int i = 0; i < 4; ++i) a0[kk][i] = rdA(0, kk, i);
#pragma unroll
            for (int j = 0; j < 2; ++j) b0[kk][j] = rdB(0, kk, j);
        }
        stage_half(1, 2, t1);
        PH_BAR(); PH_LGKM();
        __builtin_amdgcn_s_setprio(1);
#pragma unroll
        for (int kk = 0; kk < 2; ++kk)
#pragma unroll
            for (int i = 0; i < 4; ++i)
#pragma unroll
                for (int j = 0; j < 2; ++j)
                    acc[i][j] = __builtin_amdgcn_mfma_f32_16x16x32_bf16(a0[kk][i], b0[kk][j], acc[i][j], 0, 0, 0);
        __builtin_amdgcn_s_setprio(0);
        PH_BAR();
        // ph2: reads af[kk][4-7]; stage B_h1(t1)->buf1
#pragma unroll
        for (int kk = 0; kk < 2; ++kk)
#pragma unroll
            for (int i = 0; i < 4; ++i) a1[kk][i] = rdA(0, kk, 4 + i);
        stage_half(1, 3, t1);
        PH_BAR(); PH_LGKM();
        __builtin_amdgcn_s_setprio(1);
#pragma unroll
        for (int kk = 0; kk < 2; ++kk)
#pragma unroll
            for (int i = 0; i < 4; ++i)
#pragma unroll
                for (int j = 0; j < 2; ++j)
                    acc[4 + i][j] = __builtin_amdgcn_mfma_f32_16x16x32_bf16(a1[kk][i], b0[kk][j], acc[4 + i][j], 0, 0, 0);
        __builtin_amdgcn_s_setprio(0);
        PH_BAR();
        // ph3: reads bf[kk][2-3]; stage A_h0(t2)->buf0 (A last read ph2)
#pragma unroll
        for (int kk = 0; kk < 2; ++kk)
#pragma unroll
            for (int j = 0; j < 2; ++j) b1[kk][j] = rdB(0, kk, 2 + j);
        stage_half(0, 0, t2);
        PH_BAR(); PH_LGKM();
        __builtin_amdgcn_s_setprio(1);
#pragma unroll
        for (int kk = 0; kk < 2; ++kk)
#pragma unroll
            for (int i = 0; i < 4; ++i)
#pragma unroll
                for (int j = 0; j < 2; ++j)
                    acc[i][2 + j] = __builtin_amdgcn_mfma_f32_16x16x32_bf16(a0[kk][i], b1[kk][j], acc[i][2 + j], 0, 0, 0);
        __builtin_amdgcn_s_setprio(0);
        PH_BAR();
        // ph4: no reads; stage A_h1(t2)->buf0; vmcnt(4) then barrier
        stage_half(0, 1, t2);
        PH_BAR(); PH_LGKM();
        __builtin_amdgcn_s_setprio(1);
#pragma unroll
        for (int kk = 0; kk < 2; ++kk)
#pragma unroll
            for (int i = 0; i < 4; ++i)
#pragma unroll
                for (int j = 0; j < 2; ++j)
                    acc[4 + i][2 + j] = __builtin_amdgcn_mfma_f32_16x16x32_bf16(a1[kk][i], b1[kk][j], acc[4 + i][2 + j], 0, 0, 0);
        __builtin_amdgcn_s_setprio(0);
        PH_VM4();    // everything through ph2 landed -> buf1 complete
        PH_BAR();

        // ================= K-tile 2I+1 on buf1 =================
        // ph5: reads; stage B_h0(t2)->buf0 (buf0 B last read ph3)
#pragma unroll
        for (int kk = 0; kk < 2; ++kk) {
#pragma unroll
            for (int i = 0; i < 4; ++i) a0[kk][i] = rdA(1, kk, i);
#pragma unroll
            for (int j = 0; j < 2; ++j) b0[kk][j] = rdB(1, kk, j);
        }
        stage_half(0, 2, t2);
        PH_BAR(); PH_LGKM();
        __builtin_amdgcn_s_setprio(1);
#pragma unroll
        for (int kk = 0; kk < 2; ++kk)
#pragma unroll
            for (int i = 0; i < 4; ++i)
#pragma unroll
                for (int j = 0; j < 2; ++j)
                    acc[i][j] = __builtin_amdgcn_mfma_f32_16x16x32_bf16(a0[kk][i], b0[kk][j], acc[i][j], 0, 0, 0);
        __builtin_amdgcn_s_setprio(0);
        PH_BAR();
        // ph6: reads af[4-7]; stage B_h1(t2)->buf0
#pragma unroll
        for (int kk = 0; kk < 2; ++kk)
#pragma unroll
            for (int i = 0; i < 4; ++i) a1[kk][i] = rdA(1, kk, 4 + i);
        stage_half(0, 3, t2);
        PH_BAR(); PH_LGKM();
        __builtin_amdgcn_s_setprio(1);
#pragma unroll
        for (int kk = 0; kk < 2; ++kk)
#pragma unroll
            for (int i = 0; i < 4; ++i)
#pragma unroll
                for (int j = 0; j < 2; ++j)
                    acc[4 + i][j] = __builtin_amdgcn_mfma_f32_16x16x32_bf16(a1[kk][i], b0[kk][j], acc[4 + i][j], 0, 0, 0);
        __builtin_amdgcn_s_setprio(0);
        PH_BAR();
        // ph7: reads bf[2-3]; stage A_h0(t3)->buf1 (buf1 A last read ph6)
#pragma unroll
        for (int kk = 0; kk < 2; ++kk)
#pragma unroll
            for (int j = 0; j < 2; ++j) b1[kk][j] = rdB(1, kk, 2 + j);
        stage_half(1, 0, t3);
        PH_BAR(); PH_LGKM();
        __builtin_amdgcn_s_setprio(1);
#pragma unroll
        for (int kk = 0; kk < 2; ++kk)
#pragma unroll
            for (int i = 0; i < 4; ++i)
#pragma unroll
                for (int j = 0; j < 2; ++j)
                    acc[i][2 + j] = __builtin_amdgcn_mfma_f32_16x16x32_bf16(a0[kk][i], b1[kk][j], acc[i][2 + j], 0, 0, 0);
        __builtin_amdgcn_s_setprio(0);
        PH_BAR();
        // ph8: no reads; stage A_h1(t3)->buf1; vmcnt(4) then barrier
        stage_half(1, 1, t3);
        PH_BAR(); PH_LGKM();
        __builtin_amdgcn_s_setprio(1);
#pragma unroll
        for (int kk = 0; kk < 2; ++kk)
#pragma unroll
            for (int i = 0; i < 4; ++i)
#pragma unroll
                for (int j = 0; j < 2; ++j)
                    acc[4 + i][2 + j] = __builtin_amdgcn_mfma_f32_16x16x32_bf16(a1[kk][i], b1[kk][j], acc[4 + i][2 + j], 0, 0, 0);
        __builtin_amdgcn_s_setprio(0);
        PH_VM4();    // everything through ph6 landed -> buf0 complete
        PH_BAR();
    }

    // Epilogue: per n-column top-2 over this wave's 128 k's (= one window)
    const int q4 = (lane >> 4) * 4;
    float v1[4], v2[4];
    int   k1[4], k2[4];
#pragma unroll
    for (int in = 0; in < 4; ++in) { v1[in] = 1e30f; v2[in] = 1e30f; k1[in] = 0; k2[in] = 0; }

#pragma unroll
    for (int ik = 0; ik < 8; ++ik) {
        float qv[4];
#pragma unroll
        for (int r = 0; r < 4; ++r)
            qv[r] = qn[k0 + wk * 128 + ik * 16 + q4 + r];
#pragma unroll
        for (int in = 0; in < 4; ++in) {
#pragma unroll
            for (int r = 0; r < 4; ++r) {
                const float val = qv[r] - 2.0f * acc[ik][in][r];
                const int   kg  = k0 + wk * 128 + ik * 16 + q4 + r;
                if (val < v1[in]) { v2[in] = v1[in]; k2[in] = k1[in]; v1[in] = val; k1[in] = kg; }
                else if (val < v2[in]) { v2[in] = val; k2[in] = kg; }
            }
        }
    }
#pragma unroll
    for (int m = 16; m <= 32; m <<= 1) {
#pragma unroll
        for (int in = 0; in < 4; ++in) {
            const float ov1 = __shfl_xor(v1[in], m, 64);
            const int   ok1 = __shfl_xor(k1[in], m, 64);
            const float ov2 = __shfl_xor(v2[in], m, 64);
            const int   ok2 = __shfl_xor(k2[in], m, 64);
            float nv1, nv2; int nk1, nk2;
            if (ov1 < v1[in]) {
                nv1 = ov1; nk1 = ok1;
                if (v1[in] < ov2) { nv2 = v1[in]; nk2 = k1[in]; } else { nv2 = ov2; nk2 = ok2; }
            } else {
                nv1 = v1[in]; nk1 = k1[in];
                if (ov1 < v2[in]) { nv2 = ov1; nk2 = ok1; } else { nv2 = v2[in]; nk2 = k2[in]; }
            }
            v1[in] = nv1; k1[in] = nk1; v2[in] = nv2; k2[in] = nk2;
        }
    }
    if ((lane >> 4) == 0) {
        const int w = blockIdx.y * 2 + wk;
#pragma unroll
        for (int in = 0; in < 4; ++in) {
            const int n = n0 + wn * 64 + in * 16 + (lane & 15);
            float4 o; o.x = v1[in]; o.y = __int_as_float(k1[in]);
            o.z = v2[in]; o.w = __int_as_float(k2[in]);
            *(float4*)&wtop[((size_t)w * N_ + n) * 4] = o;
        }
    }
}

// ---------------------------------------------------------------------------
// Phase B: rowmin over windows; collect candidates within EPS of rowmin.
// ---------------------------------------------------------------------------
__global__ __launch_bounds__(256) void phaseB(const float* __restrict__ wtop,
                                              int* __restrict__ cand_k,
                                              int* __restrict__ cand_cnt) {
    const int n = blockIdx.x * 256 + threadIdx.x;
    float rmin = 1e30f;
    for (int w = 0; w < 64; ++w)
        rmin = fminf(rmin, wtop[((size_t)w * N_ + n) * 4]);
    const float thr = rmin + EPS_;
    int cnt = 0;
    for (int w = 0; w < 64; ++w) {
        float4 e = *(const float4*)&wtop[((size_t)w * N_ + n) * 4];
        if (e.x <= thr && cnt < 16) cand_k[n * 16 + cnt++] = __float_as_int(e.y);
        if (e.z <= thr && cnt < 16) cand_k[n * 16 + cnt++] = __float_as_int(e.w);
    }
    cand_cnt[n] = cnt;
}

// ---------------------------------------------------------------------------
// Phase C v2 (unchanged): exact recheck, cnt==1 early-exit, FMA chain
// bit-identical to round 2.
// ---------------------------------------------------------------------------
__global__ __launch_bounds__(256) void phaseC(const float* __restrict__ zf,
                                              const float* __restrict__ qc,
                                              const float* __restrict__ zn,
                                              const float* __restrict__ qn,
                                              const int* __restrict__ cand_k,
                                              const int* __restrict__ cand_cnt,
                                              int* __restrict__ idxf,
                                              float* __restrict__ out_idx) {
    __shared__ float zr[4][512];
    __shared__ float ql[4][2][512];
    const int wv   = threadIdx.x >> 6;
    const int lane = threadIdx.x & 63;
    const int r    = blockIdx.x * 4 + wv;
    const int cnt  = cand_cnt[r];

    if (cnt == 1) {
        if (lane == 0) { const int k = cand_k[r * 16]; idxf[r] = k; out_idx[r] = (float)k; }
        return;
    }

    *(float4*)&zr[wv][lane * 8]     = *(const float4*)&zf[(size_t)r * 512 + lane * 8];
    *(float4*)&zr[wv][lane * 8 + 4] = *(const float4*)&zf[(size_t)r * 512 + lane * 8 + 4];

    const int g  = lane >> 5;
    const int cl = (lane & 31) * 16;
    const int steps = (cnt + 1) >> 1;
    const float znr = zn[r];

    auto cand_of = [&](int s) {
        const int ci = 2 * s + g;
        return cand_k[r * 16 + (ci < cnt ? ci : 0)];
    };

    int k_cur = cand_of(0);
    const float* q0 = qc + (size_t)k_cur * 512 + cl;
    float4 p0 = *(const float4*)&q0[0];
    float4 p1 = *(const float4*)&q0[4];
    float4 p2 = *(const float4*)&q0[8];
    float4 p3 = *(const float4*)&q0[12];

    float bd = 1e30f;
    int   bi = 0x7fffffff;

    for (int s = 0; s < steps; ++s) {
        *(float4*)&ql[wv][g][cl + 0]  = p0;
        *(float4*)&ql[wv][g][cl + 4]  = p1;
        *(float4*)&ql[wv][g][cl + 8]  = p2;
        *(float4*)&ql[wv][g][cl + 12] = p3;

        int k_next = 0;
        if (s + 1 < steps) {
            k_next = cand_of(s + 1);
            const float* qn_ = qc + (size_t)k_next * 512 + cl;
            p0 = *(const float4*)&qn_[0];
            p1 = *(const float4*)&qn_[4];
            p2 = *(const float4*)&qn_[8];
            p3 = *(const float4*)&qn_[12];
        }

        float acc = 0.f;
#pragma unroll 16
        for (int c = 0; c < 512; c += 4) {
            float4 zv = *(const float4*)&zr[wv][c];
            float4 qv = *(const float4*)&ql[wv][g][c];
            acc = fmaf(zv.x, qv.x, acc);
            acc = fmaf(zv.y, qv.y, acc);
            acc = fmaf(zv.z, qv.z, acc);
            acc = fmaf(zv.w, qv.w, acc);
        }
        const float T = znr + qn[k_cur];
        const float d = T - 2.0f * acc;
        const bool valid = (2 * s + g) < cnt;
        if (valid && (d < bd || (d == bd && k_cur < bi))) { bd = d; bi = k_cur; }
        k_cur = k_next;
    }

    const float od = __shfl_xor(bd, 32, 64);
    const int   oi = __shfl_xor(bi, 32, 64);
    if (od < bd || (od == bd && oi < bi)) { bd = od; bi = oi; }

    if (lane == 0) { idxf[r] = bi; out_idx[r] = (float)bi; }
}

// ---------------------------------------------------------------------------
// Gather z_q = qc[idx], transpose-write to [B,C,H,W], fused loss.
// ---------------------------------------------------------------------------
__global__ __launch_bounds__(256) void gather_out(const float* __restrict__ z,
                                                  const float* __restrict__ qc,
                                                  const int* __restrict__ idxf,
                                                  float* __restrict__ zq_out,
                                                  float* __restrict__ loss_acc) {
    __shared__ int   idxs[64];
    __shared__ float zqs[64][65];
    __shared__ float wsum[4];
    const int t  = threadIdx.x;
    const int mc = blockIdx.x;
    const int cc = blockIdx.y;
    const int bz = blockIdx.z;

    if (t < 64) idxs[t] = idxf[bz * 1024 + mc * 64 + t];
    __syncthreads();
    {
        const int row  = t >> 2;
        const int coff = (t & 3) * 16;
        const float* src = qc + (size_t)idxs[row] * 512 + cc * 64 + coff;
#pragma unroll
        for (int v = 0; v < 4; ++v) {
            float4 q = *(const float4*)&src[v * 4];
            zqs[row][coff + v * 4 + 0] = q.x;
            zqs[row][coff + v * 4 + 1] = q.y;
            zqs[row][coff + v * 4 + 2] = q.z;
            zqs[row][coff + v * 4 + 3] = q.w;
        }
    }
    __syncthreads();

    float ls = 0.f;
    {
        const int c_local = t >> 2;
        const int mg      = (t & 3) * 16;
        const size_t gbase = ((size_t)(bz * 512 + cc * 64 + c_local)) * 1024 + mc * 64 + mg;
#pragma unroll
        for (int v = 0; v < 4; ++v) {
            const int m = mg + v * 4;
            float4 w;
            w.x = zqs[m + 0][c_local];
            w.y = zqs[m + 1][c_local];
            w.z = zqs[m + 2][c_local];
            w.w = zqs[m + 3][c_local];
            float4 zv = *(const float4*)&z[gbase + v * 4];
            float dx = w.x - zv.x, dy = w.y - zv.y, dz = w.z - zv.z, dw = w.w - zv.w;
            ls += dx * dx + dy * dy + dz * dz + dw * dw;
            *(float4*)&zq_out[gbase + v * 4] = w;
        }
    }
#pragma unroll
    for (int m = 32; m; m >>= 1) ls += __shfl_xor(ls, m, 64);
    const int lane = t & 63, wvv = t >> 6;
    if (lane == 0) wsum[wvv] = ls;
    __syncthreads();
    if (t == 0) atomicAdd(loss_acc, wsum[0] + wsum[1] + wsum[2] + wsum[3]);
}

__global__ void zero_loss(float* __restrict__ loss_acc) { loss_acc[0] = 0.f; }

__global__ void finalize(const float* __restrict__ loss_acc,
                         float* __restrict__ out_loss) {
    out_loss[0] = 1.25f * loss_acc[0] / 8388608.0f;
}

// ---------------------------------------------------------------------------
extern "C" void kernel_launch(void* const* d_in, const int* in_sizes, int n_in,
                              void* d_out, int out_size, void* d_ws, size_t ws_size,
                              hipStream_t stream) {
    const float* z    = (const float*)d_in[0];
    const float* emb  = (const float*)d_in[1];
    const float* W    = (const float*)d_in[2];
    const float* bias = (const float*)d_in[3];
    float* ws = (float*)d_ws;

    float*  qc       = ws + QC_OFF;
    float*  qn       = ws + QN_OFF;
    float*  zn       = ws + ZN_OFF;
    float*  zf       = ws + ZF_OFF;
    ushort* zh       = (ushort*)(ws + ZH_OFF);
    ushort* qh       = (ushort*)(ws + QH_OFF);
    float*  wtop     = ws + WT_OFF;
    int*    cand_k   = (int*)(ws + CK_OFF);
    int*    cand_cnt = (int*)(ws + CC_OFF);
    int*    idxf     = (int*)(ws + IDXF_OFF);
    float*  loss_acc = ws + LOSS_OFF;
    float*  out      = (float*)d_out;

    zero_loss<<<1, 1, 0, stream>>>(loss_acc);
    transpose_z<<<dim3(16, 8, 16), 256, 0, stream>>>(z, zf, zh);
    qc_gemm<<<dim3(K_ / 128, C_ / 128), 256, 0, stream>>>(emb, W, bias, qc, qh);
    qnorm_pairwise<<<K_ / 256, 256, 0, stream>>>(qc, qn);
    znorm_pairwise<<<N_ / 256, 256, 0, stream>>>(zf, zn);
    phaseA<<<dim3(N_ / 256, K_ / 256), 512, 0, stream>>>(qh, zh, qn, wtop);
    phaseB<<<N_ / 256, 256, 0, stream>>>(wtop, cand_k, cand_cnt);
    phaseC<<<N_ / 4, 256, 0, stream>>>(zf, qc, zn, qn, cand_k, cand_cnt, idxf, out + OUT_IDX);
    gather_out<<<dim3(16, 8, B_), 256, 0, stream>>>(z, qc, idxf, out + OUT_ZQ, loss_acc);
    finalize<<<1, 1, 0, stream>>>(loss_acc, out + OUT_LOSS);
}

// Round 9
// 419.740 us; speedup vs baseline: 4.9561x; 1.0032x over previous
//
#include <hip/hip_runtime.h>

typedef unsigned int uint;
typedef unsigned short ushort;
typedef __attribute__((ext_vector_type(8))) short short8;
typedef __attribute__((ext_vector_type(4))) float f32x4;

// Problem constants
#define B_   16
#define C_   512
#define HW_  1024
#define N_   16384
#define K_   8192
#define EPS_ 0.25f

// Workspace layout (float units)
#define QC_OFF    0u
#define QC_SZ     (K_ * C_)
#define QN_OFF    (QC_OFF + QC_SZ)
#define QN_SZ     K_
#define ZN_OFF    (QN_OFF + QN_SZ)
#define ZN_SZ     N_
#define ZF_OFF    (ZN_OFF + ZN_SZ)
#define ZF_SZ     (N_ * C_)
#define ZH_OFF    (ZF_OFF + ZF_SZ)
#define ZH_SZ     (N_ * C_ / 2)
#define QH_OFF    (ZH_OFF + ZH_SZ)
#define QH_SZ     (K_ * C_ / 2)
#define WT_OFF    (QH_OFF + QH_SZ)
#define WT_SZ     (64 * N_ * 4)
#define CK_OFF    (WT_OFF + WT_SZ)
#define CK_SZ     (N_ * 16)
#define CC_OFF    (CK_OFF + CK_SZ)
#define CC_SZ     N_
#define IDXF_OFF  (CC_OFF + CC_SZ)
#define IDXF_SZ   N_
#define LOSS_OFF  (IDXF_OFF + IDXF_SZ)

// Output layout (floats)
#define OUT_ZQ    0
#define OUT_LOSS  8388608
#define OUT_IDX   8388609

__device__ __forceinline__ ushort f2bf(float f) {
    uint x = __float_as_uint(f);
    uint r = x + 0x7fffu + ((x >> 16) & 1u);
    return (ushort)(r >> 16);
}

// ---------------------------------------------------------------------------
// Transpose: z [B][C][HW] f32 -> z_flat [N][C] f32 (exact copy) + zh bf16
// ---------------------------------------------------------------------------
__global__ __launch_bounds__(256) void transpose_z(const float* __restrict__ z,
                                                   float* __restrict__ zf,
                                                   ushort* __restrict__ zh) {
    __shared__ float ld[64][65];
    const int t = threadIdx.x;
    const int mt = blockIdx.x, ct = blockIdx.y, b = blockIdx.z;
    {
        const int cl = t >> 4, m4 = (t & 15) * 4;
#pragma unroll
        for (int cc = 0; cc < 4; ++cc) {
            const int c = ct * 64 + cc * 16 + cl;
            float4 v = *(const float4*)&z[((size_t)(b * 512 + c)) * 1024 + mt * 64 + m4];
            ld[cc * 16 + cl][m4 + 0] = v.x; ld[cc * 16 + cl][m4 + 1] = v.y;
            ld[cc * 16 + cl][m4 + 2] = v.z; ld[cc * 16 + cl][m4 + 3] = v.w;
        }
    }
    __syncthreads();
    {
        const int nl = t >> 4, c4 = (t & 15) * 4;
#pragma unroll
        for (int nn = 0; nn < 4; ++nn) {
            const int n_local = nn * 16 + nl;
            const size_t n = (size_t)b * 1024 + mt * 64 + n_local;
            float4 w;
            w.x = ld[c4 + 0][n_local]; w.y = ld[c4 + 1][n_local];
            w.z = ld[c4 + 2][n_local]; w.w = ld[c4 + 3][n_local];
            *(float4*)&zf[n * 512 + ct * 64 + c4] = w;
            ushort4 h; h.x = f2bf(w.x); h.y = f2bf(w.y); h.z = f2bf(w.z); h.w = f2bf(w.w);
            *(ushort4*)&zh[n * 512 + ct * 64 + c4] = h;
        }
    }
}

// ---------------------------------------------------------------------------
// qc GEMM v3: 128k x 64c tile, 256 threads, 512 blocks (2/CU, 8 waves/CU).
// Per-element math IDENTICAL: single accumulator, d ascending, FMA chain.
// ---------------------------------------------------------------------------
__global__ __launch_bounds__(256) void qc_gemm(const float* __restrict__ emb,
                                               const float* __restrict__ W,
                                               const float* __restrict__ bias,
                                               float* __restrict__ qc,
                                               ushort* __restrict__ qh) {
    __shared__ float As[16][132];   // [d_local][k_local 128]
    __shared__ float Bs[16][68];    // [d_local][c_local 64]
    const int t    = threadIdx.x;
    const int k0   = blockIdx.x * 128;
    const int c0   = blockIdx.y * 64;
    const int ty   = t >> 4, tx = t & 15;
    const int rowA = t >> 1;          // 0..127
    const int dqA  = (t & 1) * 8;     // 0/8
    const int rowB = t >> 2;          // 0..63
    const int dqB  = (t & 3) * 4;     // 0/4/8/12

    const float* pa = emb + (size_t)(k0 + rowA) * 512 + dqA;
    const float* pb = W   + (size_t)(c0 + rowB) * 512 + dqB;
    float4 ra0 = *(const float4*)&pa[0];
    float4 ra1 = *(const float4*)&pa[4];
    float4 rb  = *(const float4*)&pb[0];

    float acc[2][4][4] = {};   // [ih][i][j]
    for (int d0 = 0; d0 < 512; d0 += 16) {
        __syncthreads();
        As[dqA + 0][rowA] = ra0.x; As[dqA + 1][rowA] = ra0.y;
        As[dqA + 2][rowA] = ra0.z; As[dqA + 3][rowA] = ra0.w;
        As[dqA + 4][rowA] = ra1.x; As[dqA + 5][rowA] = ra1.y;
        As[dqA + 6][rowA] = ra1.z; As[dqA + 7][rowA] = ra1.w;
        Bs[dqB + 0][rowB] = rb.x;  Bs[dqB + 1][rowB] = rb.y;
        Bs[dqB + 2][rowB] = rb.z;  Bs[dqB + 3][rowB] = rb.w;
        if (d0 + 16 < 512) {
            ra0 = *(const float4*)&pa[d0 + 16];
            ra1 = *(const float4*)&pa[d0 + 20];
            rb  = *(const float4*)&pb[d0 + 16];
        }
        __syncthreads();
#pragma unroll
        for (int dd = 0; dd < 16; ++dd) {
            float4 a0 = *(const float4*)&As[dd][ty * 4];
            float4 a1 = *(const float4*)&As[dd][64 + ty * 4];
            float4 b0 = *(const float4*)&Bs[dd][tx * 4];
            float aa[2][4] = {{a0.x, a0.y, a0.z, a0.w}, {a1.x, a1.y, a1.z, a1.w}};
            float bb[4] = {b0.x, b0.y, b0.z, b0.w};
#pragma unroll
            for (int ih = 0; ih < 2; ++ih)
#pragma unroll
                for (int i = 0; i < 4; ++i)
#pragma unroll
                    for (int j = 0; j < 4; ++j)
                        acc[ih][i][j] += aa[ih][i] * bb[j];  // fma, d asc
        }
    }
#pragma unroll
    for (int ih = 0; ih < 2; ++ih)
#pragma unroll
        for (int i = 0; i < 4; ++i) {
            const size_t kr = (size_t)(k0 + ih * 64 + ty * 4 + i) * 512;
            const int cb = c0 + tx * 4;
            float4 v;
            v.x = acc[ih][i][0] + bias[cb + 0];
            v.y = acc[ih][i][1] + bias[cb + 1];
            v.z = acc[ih][i][2] + bias[cb + 2];
            v.w = acc[ih][i][3] + bias[cb + 3];
            *(float4*)&qc[kr + cb] = v;
            ushort4 h; h.x = f2bf(v.x); h.y = f2bf(v.y); h.z = f2bf(v.z); h.w = f2bf(v.w);
            *(ushort4*)&qh[kr + cb] = h;
        }
}

// ---------------------------------------------------------------------------
// znorm: round-2 coalesced version — reads ORIGINAL z (bit-identical values),
// numpy pairwise structure, squares rounded before add.
// ---------------------------------------------------------------------------
__global__ __launch_bounds__(256) void znorm_pairwise(const float* __restrict__ z,
                                                      float* __restrict__ zn) {
#pragma clang fp contract(off)
    const int n = blockIdx.x * 256 + threadIdx.x;
    const int b = n >> 10, m = n & 1023;
    const float* base = z + (size_t)b * C_ * HW_ + m;
    float s128[4];
#pragma unroll
    for (int blk = 0; blk < 4; ++blk) {
        float r[8];
#pragma unroll
        for (int j = 0; j < 8; ++j) {
            float v = base[(size_t)(blk * 128 + j) * HW_];
            r[j] = v * v;
        }
#pragma unroll 1
        for (int i = 8; i < 128; i += 8) {
#pragma unroll
            for (int j = 0; j < 8; ++j) {
                float v = base[(size_t)(blk * 128 + i + j) * HW_];
                float sq = v * v;
                r[j] = r[j] + sq;
            }
        }
        s128[blk] = ((r[0] + r[1]) + (r[2] + r[3])) + ((r[4] + r[5]) + (r[6] + r[7]));
    }
    zn[n] = (s128[0] + s128[1]) + (s128[2] + s128[3]);
}

// ---------------------------------------------------------------------------
// qnorm: 8-lane-group version. Lane j owns accumulator r[j]; shfl_xor tree
// reproduces numpy's ((r0+r1)+(r2+r3))+((r4+r5)+(r6+r7)) bitwise
// (fp add is commutative bitwise, so every lane's tree value matches lane 0).
// ---------------------------------------------------------------------------
__global__ __launch_bounds__(256) void qnorm_grouped(const float* __restrict__ qc,
                                                     float* __restrict__ qn) {
#pragma clang fp contract(off)
    const int t   = threadIdx.x;
    const int grp = t >> 3;          // 0..31
    const int j   = t & 7;
    const int k   = blockIdx.x * 32 + grp;
    const float* row = qc + (size_t)k * C_;
    float s[4];
#pragma unroll
    for (int blk = 0; blk < 4; ++blk) {
        float v0 = row[blk * 128 + j];
        float r  = v0 * v0;
#pragma unroll 1
        for (int i = 1; i < 16; ++i) {
            float v  = row[blk * 128 + i * 8 + j];
            float sq = v * v;
            r = r + sq;
        }
        float t1 = r  + __shfl_xor(r, 1, 64);
        float t2 = t1 + __shfl_xor(t1, 2, 64);
        float t3 = t2 + __shfl_xor(t2, 4, 64);
        s[blk] = t3;
    }
    if (j == 0) qn[k] = (s[0] + s[1]) + (s[2] + s[3]);
}

// ---------------------------------------------------------------------------
// Phase A v5: same 8-phase schedule as round 8, with ALL LDS read addresses
// hoisted to 4 base pointers + literal offsets (the XOR term is i/j-
// independent because (row&7) == (lane&15)&7), and staging global bases
// hoisted. Reads/ops identical -> results bit-identical.
// ---------------------------------------------------------------------------
#define PH_BAR()  __builtin_amdgcn_s_barrier()
#define PH_LGKM() asm volatile("s_waitcnt lgkmcnt(0)" ::: "memory")
#define PH_VM4()  asm volatile("s_waitcnt vmcnt(4)" ::: "memory")

__device__ __forceinline__ short8 ld8(const short* p, int off) {
    return *(const short8*)(p + off);
}

__global__ __launch_bounds__(512, 2) void phaseA(const ushort* __restrict__ qh,
                                                 const ushort* __restrict__ zh,
                                                 const float* __restrict__ qn,
                                                 float* __restrict__ wtop) {
    __shared__ short lq[32768];   // [buf2][half2][128 rows][64 c] swizzled
    __shared__ short lz[32768];
    const int t    = threadIdx.x;
    const int lane = t & 63;
    const int wv   = t >> 6;
    const int wk   = wv >> 2;       // 0..1
    const int wn   = wv & 3;        // 0..3
    const int n0   = blockIdx.x * 256;
    const int k0   = blockIdx.y * 256;

    // ---- hoisted LDS read bases (element units; +b*16384 +i*1024 literal) ----
    const int l15 = lane & 15;
    const int hi8 = (lane >> 4) << 3;
    const int xr  = (l15 & 7) << 3;
    const short* pA0 = lq + wk * 8192 + l15 * 64 + ((hi8) ^ xr);
    const short* pA1 = lq + wk * 8192 + l15 * 64 + ((32 + hi8) ^ xr);
    const short* pB0 = lz + (wn >> 1) * 8192 + (wn & 1) * 4096 + l15 * 64 + ((hi8) ^ xr);
    const short* pB1 = lz + (wn >> 1) * 8192 + (wn & 1) * 4096 + l15 * 64 + ((32 + hi8) ^ xr);

    // ---- hoisted staging bases ----
    const int ch0 = t,        row0 = ch0 >> 3;
    const int ch1 = t + 512,  row1 = ch1 >> 3;
    const int ce0 = ((ch0 ^ row0) & 7) << 3;
    const int ce1 = ((ch1 ^ row1) & 7) << 3;
    const ushort* qsrc0 = qh + (size_t)(k0 + row0) * 512 + ce0;
    const ushort* qsrc1 = qh + (size_t)(k0 + row1) * 512 + ce1;
    const ushort* zsrc0 = zh + (size_t)(n0 + row0) * 512 + ce0;
    const ushort* zsrc1 = zh + (size_t)(n0 + row1) * 512 + ce1;
    short* qdst0 = lq + ch0 * 8;
    short* qdst1 = lq + ch1 * 8;
    short* zdst0 = lz + ch0 * 8;
    short* zdst1 = lz + ch1 * 8;

    auto stage_half = [&](int b, int h, int chunk) {
        const int co = chunk * 64;
        if (h < 2) {
            __builtin_amdgcn_global_load_lds(
                (const __attribute__((address_space(1))) uint*)(qsrc0 + h * 65536 + co),
                (__attribute__((address_space(3))) uint*)(qdst0 + (b * 2 + h) * 8192), 16, 0, 0);
            __builtin_amdgcn_global_load_lds(
                (const __attribute__((address_space(1))) uint*)(qsrc1 + h * 65536 + co),
                (__attribute__((address_space(3))) uint*)(qdst1 + (b * 2 + h) * 8192), 16, 0, 0);
        } else {
            __builtin_amdgcn_global_load_lds(
                (const __attribute__((address_space(1))) uint*)(zsrc0 + (h - 2) * 65536 + co),
                (__attribute__((address_space(3))) uint*)(zdst0 + (b * 2 + (h - 2)) * 8192), 16, 0, 0);
            __builtin_amdgcn_global_load_lds(
                (const __attribute__((address_space(1))) uint*)(zsrc1 + (h - 2) * 65536 + co),
                (__attribute__((address_space(3))) uint*)(zdst1 + (b * 2 + (h - 2)) * 8192), 16, 0, 0);
        }
    };

    f32x4 acc[8][4];
#pragma unroll
    for (int i = 0; i < 8; ++i)
#pragma unroll
        for (int j = 0; j < 4; ++j) acc[i][j] = (f32x4){0.f, 0.f, 0.f, 0.f};

    // Prologue
    stage_half(0, 0, 0); stage_half(0, 1, 0); stage_half(0, 2, 0); stage_half(0, 3, 0);
    stage_half(1, 0, 1); stage_half(1, 1, 1);
    PH_VM4();
    PH_BAR();

    short8 a0[2][4], a1[2][4], b0[2][2], b1[2][2];

#pragma unroll 1
    for (int I = 0; I < 4; ++I) {
        const int t1 = 2 * I + 1;
        const int t2 = (2 * I + 2) & 7;
        const int t3 = (2 * I + 3) & 7;

        // ========== K-tile 2I on buf0 ==========
        // ph1
#pragma unroll
        for (int i = 0; i < 4; ++i) { a0[0][i] = ld8(pA0, i * 1024); a0[1][i] = ld8(pA1, i * 1024); }
#pragma unroll
        for (int jj = 0; jj < 2; ++jj) { b0[0][jj] = ld8(pB0, jj * 1024); b0[1][jj] = ld8(pB1, jj * 1024); }
        stage_half(1, 2, t1);
        PH_BAR(); PH_LGKM();
        __builtin_amdgcn_s_setprio(1);
#pragma unroll
        for (int kk = 0; kk < 2; ++kk)
#pragma unroll
            for (int i = 0; i < 4; ++i)
#pragma unroll
                for (int jj = 0; jj < 2; ++jj)
                    acc[i][jj] = __builtin_amdgcn_mfma_f32_16x16x32_bf16(a0[kk][i], b0[kk][jj], acc[i][jj], 0, 0, 0);
        __builtin_amdgcn_s_setprio(0);
        PH_BAR();
        // ph2
#pragma unroll
        for (int i = 0; i < 4; ++i) { a1[0][i] = ld8(pA0, 4096 + i * 1024); a1[1][i] = ld8(pA1, 4096 + i * 1024); }
        stage_half(1, 3, t1);
        PH_BAR(); PH_LGKM();
        __builtin_amdgcn_s_setprio(1);
#pragma unroll
        for (int kk = 0; kk < 2; ++kk)
#pragma unroll
            for (int i = 0; i < 4; ++i)
#pragma unroll
                for (int jj = 0; jj < 2; ++jj)
                    acc[4 + i][jj] = __builtin_amdgcn_mfma_f32_16x16x32_bf16(a1[kk][i], b0[kk][jj], acc[4 + i][jj], 0, 0, 0);
        __builtin_amdgcn_s_setprio(0);
        PH_BAR();
        // ph3
#pragma unroll
        for (int jj = 0; jj < 2; ++jj) { b1[0][jj] = ld8(pB0, 2048 + jj * 1024); b1[1][jj] = ld8(pB1, 2048 + jj * 1024); }
        stage_half(0, 0, t2);
        PH_BAR(); PH_LGKM();
        __builtin_amdgcn_s_setprio(1);
#pragma unroll
        for (int kk = 0; kk < 2; ++kk)
#pragma unroll
            for (int i = 0; i < 4; ++i)
#pragma unroll
                for (int jj = 0; jj < 2; ++jj)
                    acc[i][2 + jj] = __builtin_amdgcn_mfma_f32_16x16x32_bf16(a0[kk][i], b1[kk][jj], acc[i][2 + jj], 0, 0, 0);
        __builtin_amdgcn_s_setprio(0);
        PH_BAR();
        // ph4
        stage_half(0, 1, t2);
        PH_BAR(); PH_LGKM();
        __builtin_amdgcn_s_setprio(1);
#pragma unroll
        for (int kk = 0; kk < 2; ++kk)
#pragma unroll
            for (int i = 0; i < 4; ++i)
#pragma unroll
                for (int jj = 0; jj < 2; ++jj)
                    acc[4 + i][2 + jj] = __builtin_amdgcn_mfma_f32_16x16x32_bf16(a1[kk][i], b1[kk][jj], acc[4 + i][2 + jj], 0, 0, 0);
        __builtin_amdgcn_s_setprio(0);
        PH_VM4();
        PH_BAR();

        // ========== K-tile 2I+1 on buf1 ==========
        // ph5
#pragma unroll
        for (int i = 0; i < 4; ++i) { a0[0][i] = ld8(pA0, 16384 + i * 1024); a0[1][i] = ld8(pA1, 16384 + i * 1024); }
#pragma unroll
        for (int jj = 0; jj < 2; ++jj) { b0[0][jj] = ld8(pB0, 16384 + jj * 1024); b0[1][jj] = ld8(pB1, 16384 + jj * 1024); }
        stage_half(0, 2, t2);
        PH_BAR(); PH_LGKM();
        __builtin_amdgcn_s_setprio(1);
#pragma unroll
        for (int kk = 0; kk < 2; ++kk)
#pragma unroll
            for (int i = 0; i < 4; ++i)
#pragma unroll
                for (int jj = 0; jj < 2; ++jj)
                    acc[i][jj] = __builtin_amdgcn_mfma_f32_16x16x32_bf16(a0[kk][i], b0[kk][jj], acc[i][jj], 0, 0, 0);
        __builtin_amdgcn_s_setprio(0);
        PH_BAR();
        // ph6
#pragma unroll
        for (int i = 0; i < 4; ++i) { a1[0][i] = ld8(pA0, 16384 + 4096 + i * 1024); a1[1][i] = ld8(pA1, 16384 + 4096 + i * 1024); }
        stage_half(0, 3, t2);
        PH_BAR(); PH_LGKM();
        __builtin_amdgcn_s_setprio(1);
#pragma unroll
        for (int kk = 0; kk < 2; ++kk)
#pragma unroll
            for (int i = 0; i < 4; ++i)
#pragma unroll
                for (int jj = 0; jj < 2; ++jj)
                    acc[4 + i][jj] = __builtin_amdgcn_mfma_f32_16x16x32_bf16(a1[kk][i], b0[kk][jj], acc[4 + i][jj], 0, 0, 0);
        __builtin_amdgcn_s_setprio(0);
        PH_BAR();
        // ph7
#pragma unroll
        for (int jj = 0; jj < 2; ++jj) { b1[0][jj] = ld8(pB0, 16384 + 2048 + jj * 1024); b1[1][jj] = ld8(pB1, 16384 + 2048 + jj * 1024); }
        stage_half(1, 0, t3);
        PH_BAR(); PH_LGKM();
        __builtin_amdgcn_s_setprio(1);
#pragma unroll
        for (int kk = 0; kk < 2; ++kk)
#pragma unroll
            for (int i = 0; i < 4; ++i)
#pragma unroll
                for (int jj = 0; jj < 2; ++jj)
                    acc[i][2 + jj] = __builtin_amdgcn_mfma_f32_16x16x32_bf16(a0[kk][i], b1[kk][jj], acc[i][2 + jj], 0, 0, 0);
        __builtin_amdgcn_s_setprio(0);
        PH_BAR();
        // ph8
        stage_half(1, 1, t3);
        PH_BAR(); PH_LGKM();
        __builtin_amdgcn_s_setprio(1);
#pragma unroll
        for (int kk = 0; kk < 2; ++kk)
#pragma unroll
            for (int i = 0; i < 4; ++i)
#pragma unroll
                for (int jj = 0; jj < 2; ++jj)
                    acc[4 + i][2 + jj] = __builtin_amdgcn_mfma_f32_16x16x32_bf16(a1[kk][i], b1[kk][jj], acc[4 + i][2 + jj], 0, 0, 0);
        __builtin_amdgcn_s_setprio(0);
        PH_VM4();
        PH_BAR();
    }

    // Epilogue: per n-column top-2 over this wave's 128 k's (= one window)
    const int q4 = (lane >> 4) * 4;
    float v1[4], v2[4];
    int   k1[4], k2[4];
#pragma unroll
    for (int in = 0; in < 4; ++in) { v1[in] = 1e30f; v2[in] = 1e30f; k1[in] = 0; k2[in] = 0; }

#pragma unroll
    for (int ik = 0; ik < 8; ++ik) {
        float qv[4];
#pragma unroll
        for (int r = 0; r < 4; ++r)
            qv[r] = qn[k0 + wk * 128 + ik * 16 + q4 + r];
#pragma unroll
        for (int in = 0; in < 4; ++in) {
#pragma unroll
            for (int r = 0; r < 4; ++r) {
                const float val = qv[r] - 2.0f * acc[ik][in][r];
                const int   kg  = k0 + wk * 128 + ik * 16 + q4 + r;
                if (val < v1[in]) { v2[in] = v1[in]; k2[in] = k1[in]; v1[in] = val; k1[in] = kg; }
                else if (val < v2[in]) { v2[in] = val; k2[in] = kg; }
            }
        }
    }
#pragma unroll
    for (int m = 16; m <= 32; m <<= 1) {
#pragma unroll
        for (int in = 0; in < 4; ++in) {
            const float ov1 = __shfl_xor(v1[in], m, 64);
            const int   ok1 = __shfl_xor(k1[in], m, 64);
            const float ov2 = __shfl_xor(v2[in], m, 64);
            const int   ok2 = __shfl_xor(k2[in], m, 64);
            float nv1, nv2; int nk1, nk2;
            if (ov1 < v1[in]) {
                nv1 = ov1; nk1 = ok1;
                if (v1[in] < ov2) { nv2 = v1[in]; nk2 = k1[in]; } else { nv2 = ov2; nk2 = ok2; }
            } else {
                nv1 = v1[in]; nk1 = k1[in];
                if (ov1 < v2[in]) { nv2 = ov1; nk2 = ok1; } else { nv2 = v2[in]; nk2 = k2[in]; }
            }
            v1[in] = nv1; k1[in] = nk1; v2[in] = nv2; k2[in] = nk2;
        }
    }
    if ((lane >> 4) == 0) {
        const int w = blockIdx.y * 2 + wk;
#pragma unroll
        for (int in = 0; in < 4; ++in) {
            const int n = n0 + wn * 64 + in * 16 + (lane & 15);
            float4 o; o.x = v1[in]; o.y = __int_as_float(k1[in]);
            o.z = v2[in]; o.w = __int_as_float(k2[in]);
            *(float4*)&wtop[((size_t)w * N_ + n) * 4] = o;
        }
    }
}

// ---------------------------------------------------------------------------
// Phase B: rowmin over windows; collect candidates within EPS; zero loss_acc.
// ---------------------------------------------------------------------------
__global__ __launch_bounds__(256) void phaseB(const float* __restrict__ wtop,
                                              int* __restrict__ cand_k,
                                              int* __restrict__ cand_cnt,
                                              float* __restrict__ loss_acc) {
    const int n = blockIdx.x * 256 + threadIdx.x;
    if (n == 0) loss_acc[0] = 0.f;
    float rmin = 1e30f;
    for (int w = 0; w < 64; ++w)
        rmin = fminf(rmin, wtop[((size_t)w * N_ + n) * 4]);
    const float thr = rmin + EPS_;
    int cnt = 0;
    for (int w = 0; w < 64; ++w) {
        float4 e = *(const float4*)&wtop[((size_t)w * N_ + n) * 4];
        if (e.x <= thr && cnt < 16) cand_k[n * 16 + cnt++] = __float_as_int(e.y);
        if (e.z <= thr && cnt < 16) cand_k[n * 16 + cnt++] = __float_as_int(e.w);
    }
    cand_cnt[n] = cnt;
}

// ---------------------------------------------------------------------------
// Phase C (unchanged): exact recheck, cnt==1 early-exit, FMA chain
// bit-identical to round 2.
// ---------------------------------------------------------------------------
__global__ __launch_bounds__(256) void phaseC(const float* __restrict__ zf,
                                              const float* __restrict__ qc,
                                              const float* __restrict__ zn,
                                              const float* __restrict__ qn,
                                              const int* __restrict__ cand_k,
                                              const int* __restrict__ cand_cnt,
                                              int* __restrict__ idxf,
                                              float* __restrict__ out_idx) {
    __shared__ float zr[4][512];
    __shared__ float ql[4][2][512];
    const int wv   = threadIdx.x >> 6;
    const int lane = threadIdx.x & 63;
    const int r    = blockIdx.x * 4 + wv;
    const int cnt  = cand_cnt[r];

    if (cnt == 1) {
        if (lane == 0) { const int k = cand_k[r * 16]; idxf[r] = k; out_idx[r] = (float)k; }
        return;
    }

    *(float4*)&zr[wv][lane * 8]     = *(const float4*)&zf[(size_t)r * 512 + lane * 8];
    *(float4*)&zr[wv][lane * 8 + 4] = *(const float4*)&zf[(size_t)r * 512 + lane * 8 + 4];

    const int g  = lane >> 5;
    const int cl = (lane & 31) * 16;
    const int steps = (cnt + 1) >> 1;
    const float znr = zn[r];

    auto cand_of = [&](int s) {
        const int ci = 2 * s + g;
        return cand_k[r * 16 + (ci < cnt ? ci : 0)];
    };

    int k_cur = cand_of(0);
    const float* q0 = qc + (size_t)k_cur * 512 + cl;
    float4 p0 = *(const float4*)&q0[0];
    float4 p1 = *(const float4*)&q0[4];
    float4 p2 = *(const float4*)&q0[8];
    float4 p3 = *(const float4*)&q0[12];

    float bd = 1e30f;
    int   bi = 0x7fffffff;

    for (int s = 0; s < steps; ++s) {
        *(float4*)&ql[wv][g][cl + 0]  = p0;
        *(float4*)&ql[wv][g][cl + 4]  = p1;
        *(float4*)&ql[wv][g][cl + 8]  = p2;
        *(float4*)&ql[wv][g][cl + 12] = p3;

        int k_next = 0;
        if (s + 1 < steps) {
            k_next = cand_of(s + 1);
            const float* qn_ = qc + (size_t)k_next * 512 + cl;
            p0 = *(const float4*)&qn_[0];
            p1 = *(const float4*)&qn_[4];
            p2 = *(const float4*)&qn_[8];
            p3 = *(const float4*)&qn_[12];
        }

        float acc = 0.f;
#pragma unroll 16
        for (int c = 0; c < 512; c += 4) {
            float4 zv = *(const float4*)&zr[wv][c];
            float4 qv = *(const float4*)&ql[wv][g][c];
            acc = fmaf(zv.x, qv.x, acc);
            acc = fmaf(zv.y, qv.y, acc);
            acc = fmaf(zv.z, qv.z, acc);
            acc = fmaf(zv.w, qv.w, acc);
        }
        const float T = znr + qn[k_cur];
        const float d = T - 2.0f * acc;
        const bool valid = (2 * s + g) < cnt;
        if (valid && (d < bd || (d == bd && k_cur < bi))) { bd = d; bi = k_cur; }
        k_cur = k_next;
    }

    const float od = __shfl_xor(bd, 32, 64);
    const int   oi = __shfl_xor(bi, 32, 64);
    if (od < bd || (od == bd && oi < bi)) { bd = od; bi = oi; }

    if (lane == 0) { idxf[r] = bi; out_idx[r] = (float)bi; }
}

// ---------------------------------------------------------------------------
// Gather z_q = qc[idx], transpose-write to [B,C,H,W], fused loss.
// ---------------------------------------------------------------------------
__global__ __launch_bounds__(256) void gather_out(const float* __restrict__ z,
                                                  const float* __restrict__ qc,
                                                  const int* __restrict__ idxf,
                                                  float* __restrict__ zq_out,
                                                  float* __restrict__ loss_acc) {
    __shared__ int   idxs[64];
    __shared__ float zqs[64][65];
    __shared__ float wsum[4];
    const int t  = threadIdx.x;
    const int mc = blockIdx.x;
    const int cc = blockIdx.y;
    const int bz = blockIdx.z;

    if (t < 64) idxs[t] = idxf[bz * 1024 + mc * 64 + t];
    __syncthreads();
    {
        const int row  = t >> 2;
        const int coff = (t & 3) * 16;
        const float* src = qc + (size_t)idxs[row] * 512 + cc * 64 + coff;
#pragma unroll
        for (int v = 0; v < 4; ++v) {
            float4 q = *(const float4*)&src[v * 4];
            zqs[row][coff + v * 4 + 0] = q.x;
            zqs[row][coff + v * 4 + 1] = q.y;
            zqs[row][coff + v * 4 + 2] = q.z;
            zqs[row][coff + v * 4 + 3] = q.w;
        }
    }
    __syncthreads();

    float ls = 0.f;
    {
        const int c_local = t >> 2;
        const int mg      = (t & 3) * 16;
        const size_t gbase = ((size_t)(bz * 512 + cc * 64 + c_local)) * 1024 + mc * 64 + mg;
#pragma unroll
        for (int v = 0; v < 4; ++v) {
            const int m = mg + v * 4;
            float4 w;
            w.x = zqs[m + 0][c_local];
            w.y = zqs[m + 1][c_local];
            w.z = zqs[m + 2][c_local];
            w.w = zqs[m + 3][c_local];
            float4 zv = *(const float4*)&z[gbase + v * 4];
            float dx = w.x - zv.x, dy = w.y - zv.y, dz = w.z - zv.z, dw = w.w - zv.w;
            ls += dx * dx + dy * dy + dz * dz + dw * dw;
            *(float4*)&zq_out[gbase + v * 4] = w;
        }
    }
#pragma unroll
    for (int m = 32; m; m >>= 1) ls += __shfl_xor(ls, m, 64);
    const int lane = t & 63, wvv = t >> 6;
    if (lane == 0) wsum[wvv] = ls;
    __syncthreads();
    if (t == 0) atomicAdd(loss_acc, wsum[0] + wsum[1] + wsum[2] + wsum[3]);
}

__global__ void finalize(const float* __restrict__ loss_acc,
                         float* __restrict__ out_loss) {
    out_loss[0] = 1.25f * loss_acc[0] / 8388608.0f;
}

// ---------------------------------------------------------------------------
extern "C" void kernel_launch(void* const* d_in, const int* in_sizes, int n_in,
                              void* d_out, int out_size, void* d_ws, size_t ws_size,
                              hipStream_t stream) {
    const float* z    = (const float*)d_in[0];
    const float* emb  = (const float*)d_in[1];
    const float* W    = (const float*)d_in[2];
    const float* bias = (const float*)d_in[3];
    float* ws = (float*)d_ws;

    float*  qc       = ws + QC_OFF;
    float*  qn       = ws + QN_OFF;
    float*  zn       = ws + ZN_OFF;
    float*  zf       = ws + ZF_OFF;
    ushort* zh       = (ushort*)(ws + ZH_OFF);
    ushort* qh       = (ushort*)(ws + QH_OFF);
    float*  wtop     = ws + WT_OFF;
    int*    cand_k   = (int*)(ws + CK_OFF);
    int*    cand_cnt = (int*)(ws + CC_OFF);
    int*    idxf     = (int*)(ws + IDXF_OFF);
    float*  loss_acc = ws + LOSS_OFF;
    float*  out      = (float*)d_out;

    transpose_z<<<dim3(16, 8, 16), 256, 0, stream>>>(z, zf, zh);
    qc_gemm<<<dim3(K_ / 128, C_ / 64), 256, 0, stream>>>(emb, W, bias, qc, qh);
    qnorm_grouped<<<K_ / 32, 256, 0, stream>>>(qc, qn);
    znorm_pairwise<<<N_ / 256, 256, 0, stream>>>(z, zn);
    phaseA<<<dim3(N_ / 256, K_ / 256), 512, 0, stream>>>(qh, zh, qn, wtop);
    phaseB<<<N_ / 256, 256, 0, stream>>>(wtop, cand_k, cand_cnt, loss_acc);
    phaseC<<<N_ / 4, 256, 0, stream>>>(zf, qc, zn, qn, cand_k, cand_cnt, idxf, out + OUT_IDX);
    gather_out<<<dim3(16, 8, B_), 256, 0, stream>>>(z, qc, idxf, out + OUT_ZQ, loss_acc);
    finalize<<<1, 1, 0, stream>>>(loss_acc, out + OUT_LOSS);
}

// Round 10
// 387.741 us; speedup vs baseline: 5.3651x; 1.0825x over previous
//
#include <hip/hip_runtime.h>

typedef unsigned int uint;
typedef unsigned short ushort;
typedef unsigned long long ulong64;
typedef __attribute__((ext_vector_type(8))) short short8;
typedef __attribute__((ext_vector_type(4))) float f32x4;

// Problem constants
#define B_   16
#define C_   512
#define HW_  1024
#define N_   16384
#define K_   8192
#define EPS_ 0.25f

// Workspace layout (float units)
#define QC_OFF    0u
#define QC_SZ     (K_ * C_)
#define QN_OFF    (QC_OFF + QC_SZ)
#define QN_SZ     K_
#define ZN_OFF    (QN_OFF + QN_SZ)
#define ZN_SZ     N_
#define ZF_OFF    (ZN_OFF + ZN_SZ)
#define ZF_SZ     (N_ * C_)
#define ZH_OFF    (ZF_OFF + ZF_SZ)
#define ZH_SZ     (N_ * C_ / 2)
#define QH_OFF    (ZH_OFF + ZH_SZ)
#define QH_SZ     (K_ * C_ / 2)
#define WT_OFF    (QH_OFF + QH_SZ)     // wtop [N][64 windows] float4 {v1,k1,v2,k2}
#define WT_SZ     (64 * N_ * 4)
#define IDXF_OFF  (WT_OFF + WT_SZ)
#define IDXF_SZ   N_
#define LOSS_OFF  (IDXF_OFF + IDXF_SZ)

// Output layout (floats)
#define OUT_ZQ    0
#define OUT_LOSS  8388608
#define OUT_IDX   8388609

__device__ __forceinline__ ushort f2bf(float f) {
    uint x = __float_as_uint(f);
    uint r = x + 0x7fffu + ((x >> 16) & 1u);
    return (ushort)(r >> 16);
}

// ---------------------------------------------------------------------------
// Transpose: z [B][C][HW] f32 -> z_flat [N][C] f32 (exact copy) + zh bf16
// ---------------------------------------------------------------------------
__global__ __launch_bounds__(256) void transpose_z(const float* __restrict__ z,
                                                   float* __restrict__ zf,
                                                   ushort* __restrict__ zh) {
    __shared__ float ld[64][65];
    const int t = threadIdx.x;
    const int mt = blockIdx.x, ct = blockIdx.y, b = blockIdx.z;
    {
        const int cl = t >> 4, m4 = (t & 15) * 4;
#pragma unroll
        for (int cc = 0; cc < 4; ++cc) {
            const int c = ct * 64 + cc * 16 + cl;
            float4 v = *(const float4*)&z[((size_t)(b * 512 + c)) * 1024 + mt * 64 + m4];
            ld[cc * 16 + cl][m4 + 0] = v.x; ld[cc * 16 + cl][m4 + 1] = v.y;
            ld[cc * 16 + cl][m4 + 2] = v.z; ld[cc * 16 + cl][m4 + 3] = v.w;
        }
    }
    __syncthreads();
    {
        const int nl = t >> 4, c4 = (t & 15) * 4;
#pragma unroll
        for (int nn = 0; nn < 4; ++nn) {
            const int n_local = nn * 16 + nl;
            const size_t n = (size_t)b * 1024 + mt * 64 + n_local;
            float4 w;
            w.x = ld[c4 + 0][n_local]; w.y = ld[c4 + 1][n_local];
            w.z = ld[c4 + 2][n_local]; w.w = ld[c4 + 3][n_local];
            *(float4*)&zf[n * 512 + ct * 64 + c4] = w;
            ushort4 h; h.x = f2bf(w.x); h.y = f2bf(w.y); h.z = f2bf(w.z); h.w = f2bf(w.w);
            *(ushort4*)&zh[n * 512 + ct * 64 + c4] = h;
        }
    }
}

// ---------------------------------------------------------------------------
// qc GEMM (unchanged from round 9): 128k x 64c tile, exact d-ascending chain.
// ---------------------------------------------------------------------------
__global__ __launch_bounds__(256) void qc_gemm(const float* __restrict__ emb,
                                               const float* __restrict__ W,
                                               const float* __restrict__ bias,
                                               float* __restrict__ qc,
                                               ushort* __restrict__ qh) {
    __shared__ float As[16][132];
    __shared__ float Bs[16][68];
    const int t    = threadIdx.x;
    const int k0   = blockIdx.x * 128;
    const int c0   = blockIdx.y * 64;
    const int ty   = t >> 4, tx = t & 15;
    const int rowA = t >> 1;
    const int dqA  = (t & 1) * 8;
    const int rowB = t >> 2;
    const int dqB  = (t & 3) * 4;

    const float* pa = emb + (size_t)(k0 + rowA) * 512 + dqA;
    const float* pb = W   + (size_t)(c0 + rowB) * 512 + dqB;
    float4 ra0 = *(const float4*)&pa[0];
    float4 ra1 = *(const float4*)&pa[4];
    float4 rb  = *(const float4*)&pb[0];

    float acc[2][4][4] = {};
    for (int d0 = 0; d0 < 512; d0 += 16) {
        __syncthreads();
        As[dqA + 0][rowA] = ra0.x; As[dqA + 1][rowA] = ra0.y;
        As[dqA + 2][rowA] = ra0.z; As[dqA + 3][rowA] = ra0.w;
        As[dqA + 4][rowA] = ra1.x; As[dqA + 5][rowA] = ra1.y;
        As[dqA + 6][rowA] = ra1.z; As[dqA + 7][rowA] = ra1.w;
        Bs[dqB + 0][rowB] = rb.x;  Bs[dqB + 1][rowB] = rb.y;
        Bs[dqB + 2][rowB] = rb.z;  Bs[dqB + 3][rowB] = rb.w;
        if (d0 + 16 < 512) {
            ra0 = *(const float4*)&pa[d0 + 16];
            ra1 = *(const float4*)&pa[d0 + 20];
            rb  = *(const float4*)&pb[d0 + 16];
        }
        __syncthreads();
#pragma unroll
        for (int dd = 0; dd < 16; ++dd) {
            float4 a0 = *(const float4*)&As[dd][ty * 4];
            float4 a1 = *(const float4*)&As[dd][64 + ty * 4];
            float4 b0 = *(const float4*)&Bs[dd][tx * 4];
            float aa[2][4] = {{a0.x, a0.y, a0.z, a0.w}, {a1.x, a1.y, a1.z, a1.w}};
            float bb[4] = {b0.x, b0.y, b0.z, b0.w};
#pragma unroll
            for (int ih = 0; ih < 2; ++ih)
#pragma unroll
                for (int i = 0; i < 4; ++i)
#pragma unroll
                    for (int j = 0; j < 4; ++j)
                        acc[ih][i][j] += aa[ih][i] * bb[j];
        }
    }
#pragma unroll
    for (int ih = 0; ih < 2; ++ih)
#pragma unroll
        for (int i = 0; i < 4; ++i) {
            const size_t kr = (size_t)(k0 + ih * 64 + ty * 4 + i) * 512;
            const int cb = c0 + tx * 4;
            float4 v;
            v.x = acc[ih][i][0] + bias[cb + 0];
            v.y = acc[ih][i][1] + bias[cb + 1];
            v.z = acc[ih][i][2] + bias[cb + 2];
            v.w = acc[ih][i][3] + bias[cb + 3];
            *(float4*)&qc[kr + cb] = v;
            ushort4 h; h.x = f2bf(v.x); h.y = f2bf(v.y); h.z = f2bf(v.z); h.w = f2bf(v.w);
            *(ushort4*)&qh[kr + cb] = h;
        }
}

// ---------------------------------------------------------------------------
// Row norms (unchanged rounding).
// ---------------------------------------------------------------------------
__global__ __launch_bounds__(256) void znorm_pairwise(const float* __restrict__ z,
                                                      float* __restrict__ zn) {
#pragma clang fp contract(off)
    const int n = blockIdx.x * 256 + threadIdx.x;
    const int b = n >> 10, m = n & 1023;
    const float* base = z + (size_t)b * C_ * HW_ + m;
    float s128[4];
#pragma unroll
    for (int blk = 0; blk < 4; ++blk) {
        float r[8];
#pragma unroll
        for (int j = 0; j < 8; ++j) {
            float v = base[(size_t)(blk * 128 + j) * HW_];
            r[j] = v * v;
        }
#pragma unroll 1
        for (int i = 8; i < 128; i += 8) {
#pragma unroll
            for (int j = 0; j < 8; ++j) {
                float v = base[(size_t)(blk * 128 + i + j) * HW_];
                float sq = v * v;
                r[j] = r[j] + sq;
            }
        }
        s128[blk] = ((r[0] + r[1]) + (r[2] + r[3])) + ((r[4] + r[5]) + (r[6] + r[7]));
    }
    zn[n] = (s128[0] + s128[1]) + (s128[2] + s128[3]);
}

__global__ __launch_bounds__(256) void qnorm_grouped(const float* __restrict__ qc,
                                                     float* __restrict__ qn) {
#pragma clang fp contract(off)
    const int t   = threadIdx.x;
    const int grp = t >> 3;
    const int j   = t & 7;
    const int k   = blockIdx.x * 32 + grp;
    const float* row = qc + (size_t)k * C_;
    float s[4];
#pragma unroll
    for (int blk = 0; blk < 4; ++blk) {
        float v0 = row[blk * 128 + j];
        float r  = v0 * v0;
#pragma unroll 1
        for (int i = 1; i < 16; ++i) {
            float v  = row[blk * 128 + i * 8 + j];
            float sq = v * v;
            r = r + sq;
        }
        float t1 = r  + __shfl_xor(r, 1, 64);
        float t2 = t1 + __shfl_xor(t1, 2, 64);
        float t3 = t2 + __shfl_xor(t2, 4, 64);
        s[blk] = t3;
    }
    if (j == 0) qn[k] = (s[0] + s[1]) + (s[2] + s[3]);
}

// ---------------------------------------------------------------------------
// Phase A v6: 2 phases per K-tile (32 MFMA each), counted vmcnt(4) per K-tile.
// Rotation: tile t ph1 stages B(t+1)->buf[~t]; ph2 stages A(t+2)->buf[t]
// (its A region was consumed at ph1). vmcnt(4) at ph2 end leaves A(t+2) in
// flight while guaranteeing A(t+1)/B(t+1) landed. Per-element MFMA
// accumulation order unchanged (kk asc, tiles asc) -> acc bit-identical.
// wtop now written TRANSPOSED: [n][w] for coalesced fused phaseBC reads.
// ---------------------------------------------------------------------------
#define PH_BAR()   __builtin_amdgcn_s_barrier()
#define PH_LGKM()  asm volatile("s_waitcnt lgkmcnt(0)" ::: "memory")
#define PH_LGKM8() asm volatile("s_waitcnt lgkmcnt(8)" ::: "memory")
#define PH_VM4()   asm volatile("s_waitcnt vmcnt(4)" ::: "memory")

__device__ __forceinline__ short8 ld8(const short* p, int off) {
    return *(const short8*)(p + off);
}

__global__ __launch_bounds__(512, 2) void phaseA(const ushort* __restrict__ qh,
                                                 const ushort* __restrict__ zh,
                                                 const float* __restrict__ qn,
                                                 float* __restrict__ wtop) {
    __shared__ short lq[32768];   // [buf2][half2][128 rows][64 c] swizzled
    __shared__ short lz[32768];
    const int t    = threadIdx.x;
    const int lane = t & 63;
    const int wv   = t >> 6;
    const int wk   = wv >> 2;       // 0..1
    const int wn   = wv & 3;        // 0..3
    const int n0   = blockIdx.x * 256;
    const int k0   = blockIdx.y * 256;

    // hoisted LDS read bases
    const int l15 = lane & 15;
    const int hi8 = (lane >> 4) << 3;
    const int xr  = (l15 & 7) << 3;
    const short* pA0 = lq + wk * 8192 + l15 * 64 + ((hi8) ^ xr);
    const short* pA1 = lq + wk * 8192 + l15 * 64 + ((32 + hi8) ^ xr);
    const short* pB0 = lz + (wn >> 1) * 8192 + (wn & 1) * 4096 + l15 * 64 + ((hi8) ^ xr);
    const short* pB1 = lz + (wn >> 1) * 8192 + (wn & 1) * 4096 + l15 * 64 + ((32 + hi8) ^ xr);

    // hoisted staging bases
    const int ch0 = t,        row0 = ch0 >> 3;
    const int ch1 = t + 512,  row1 = ch1 >> 3;
    const int ce0 = ((ch0 ^ row0) & 7) << 3;
    const int ce1 = ((ch1 ^ row1) & 7) << 3;
    const ushort* qsrc0 = qh + (size_t)(k0 + row0) * 512 + ce0;
    const ushort* qsrc1 = qh + (size_t)(k0 + row1) * 512 + ce1;
    const ushort* zsrc0 = zh + (size_t)(n0 + row0) * 512 + ce0;
    const ushort* zsrc1 = zh + (size_t)(n0 + row1) * 512 + ce1;
    short* qdst0 = lq + ch0 * 8;
    short* qdst1 = lq + ch1 * 8;
    short* zdst0 = lz + ch0 * 8;
    short* zdst1 = lz + ch1 * 8;

    auto stage_half = [&](int b, int h, int chunk) {
        const int co = chunk * 64;
        if (h < 2) {
            __builtin_amdgcn_global_load_lds(
                (const __attribute__((address_space(1))) uint*)(qsrc0 + h * 65536 + co),
                (__attribute__((address_space(3))) uint*)(qdst0 + (b * 2 + h) * 8192), 16, 0, 0);
            __builtin_amdgcn_global_load_lds(
                (const __attribute__((address_space(1))) uint*)(qsrc1 + h * 65536 + co),
                (__attribute__((address_space(3))) uint*)(qdst1 + (b * 2 + h) * 8192), 16, 0, 0);
        } else {
            __builtin_amdgcn_global_load_lds(
                (const __attribute__((address_space(1))) uint*)(zsrc0 + (h - 2) * 65536 + co),
                (__attribute__((address_space(3))) uint*)(zdst0 + (b * 2 + (h - 2)) * 8192), 16, 0, 0);
            __builtin_amdgcn_global_load_lds(
                (const __attribute__((address_space(1))) uint*)(zsrc1 + (h - 2) * 65536 + co),
                (__attribute__((address_space(3))) uint*)(zdst1 + (b * 2 + (h - 2)) * 8192), 16, 0, 0);
        }
    };

    f32x4 acc[8][4];
#pragma unroll
    for (int i = 0; i < 8; ++i)
#pragma unroll
        for (int j = 0; j < 4; ++j) acc[i][j] = (f32x4){0.f, 0.f, 0.f, 0.f};

    // Prologue: A(0),B(0)->buf0; A(1)->buf1. vmcnt(4): buf0 complete.
    stage_half(0, 0, 0); stage_half(0, 1, 0); stage_half(0, 2, 0); stage_half(0, 3, 0);
    stage_half(1, 0, 1); stage_half(1, 1, 1);
    PH_VM4();
    PH_BAR();

    short8 a0[2][4], a1[2][4], b0[2][2], b1[2][2];

#pragma unroll 1
    for (int I = 0; I < 4; ++I) {
        const int tE = 2 * I;              // even tile on buf0
        const int tO = 2 * I + 1;          // odd tile on buf1

        // ===== tile tE (buf0, bo=0) =====
        // ph1: read A(all)+B01; stage B(tE+1)->buf1
#pragma unroll
        for (int i = 0; i < 4; ++i) {
            a0[0][i] = ld8(pA0, i * 1024);        a0[1][i] = ld8(pA1, i * 1024);
            a1[0][i] = ld8(pA0, 4096 + i * 1024); a1[1][i] = ld8(pA1, 4096 + i * 1024);
        }
#pragma unroll
        for (int jj = 0; jj < 2; ++jj) { b0[0][jj] = ld8(pB0, jj * 1024); b0[1][jj] = ld8(pB1, jj * 1024); }
        stage_half(1, 2, (tO) & 7); stage_half(1, 3, (tO) & 7);
        PH_LGKM8();
        PH_BAR(); PH_LGKM();
        __builtin_amdgcn_s_setprio(1);
#pragma unroll
        for (int kk = 0; kk < 2; ++kk)
#pragma unroll
            for (int i = 0; i < 4; ++i)
#pragma unroll
                for (int jj = 0; jj < 2; ++jj) {
                    acc[i][jj]     = __builtin_amdgcn_mfma_f32_16x16x32_bf16(a0[kk][i], b0[kk][jj], acc[i][jj], 0, 0, 0);
                    acc[4 + i][jj] = __builtin_amdgcn_mfma_f32_16x16x32_bf16(a1[kk][i], b0[kk][jj], acc[4 + i][jj], 0, 0, 0);
                }
        __builtin_amdgcn_s_setprio(0);
        PH_BAR();
        // ph2: read B23; stage A(tE+2)->buf0
#pragma unroll
        for (int jj = 0; jj < 2; ++jj) { b1[0][jj] = ld8(pB0, 2048 + jj * 1024); b1[1][jj] = ld8(pB1, 2048 + jj * 1024); }
        stage_half(0, 0, (tE + 2) & 7); stage_half(0, 1, (tE + 2) & 7);
        PH_BAR(); PH_LGKM();
        __builtin_amdgcn_s_setprio(1);
#pragma unroll
        for (int kk = 0; kk < 2; ++kk)
#pragma unroll
            for (int i = 0; i < 4; ++i)
#pragma unroll
                for (int jj = 0; jj < 2; ++jj) {
                    acc[i][2 + jj]     = __builtin_amdgcn_mfma_f32_16x16x32_bf16(a0[kk][i], b1[kk][jj], acc[i][2 + jj], 0, 0, 0);
                    acc[4 + i][2 + jj] = __builtin_amdgcn_mfma_f32_16x16x32_bf16(a1[kk][i], b1[kk][jj], acc[4 + i][2 + jj], 0, 0, 0);
                }
        __builtin_amdgcn_s_setprio(0);
        PH_VM4();    // A(tE+1), B(tE+1) landed; A(tE+2) may fly
        PH_BAR();

        // ===== tile tO (buf1, bo=16384) =====
        // ph1: read A(all)+B01; stage B(tO+1)->buf0
#pragma unroll
        for (int i = 0; i < 4; ++i) {
            a0[0][i] = ld8(pA0, 16384 + i * 1024);        a0[1][i] = ld8(pA1, 16384 + i * 1024);
            a1[0][i] = ld8(pA0, 16384 + 4096 + i * 1024); a1[1][i] = ld8(pA1, 16384 + 4096 + i * 1024);
        }
#pragma unroll
        for (int jj = 0; jj < 2; ++jj) { b0[0][jj] = ld8(pB0, 16384 + jj * 1024); b0[1][jj] = ld8(pB1, 16384 + jj * 1024); }
        stage_half(0, 2, (tO + 1) & 7); stage_half(0, 3, (tO + 1) & 7);
        PH_LGKM8();
        PH_BAR(); PH_LGKM();
        __builtin_amdgcn_s_setprio(1);
#pragma unroll
        for (int kk = 0; kk < 2; ++kk)
#pragma unroll
            for (int i = 0; i < 4; ++i)
#pragma unroll
                for (int jj = 0; jj < 2; ++jj) {
                    acc[i][jj]     = __builtin_amdgcn_mfma_f32_16x16x32_bf16(a0[kk][i], b0[kk][jj], acc[i][jj], 0, 0, 0);
                    acc[4 + i][jj] = __builtin_amdgcn_mfma_f32_16x16x32_bf16(a1[kk][i], b0[kk][jj], acc[4 + i][jj], 0, 0, 0);
                }
        __builtin_amdgcn_s_setprio(0);
        PH_BAR();
        // ph2: read B23; stage A(tO+2)->buf1
#pragma unroll
        for (int jj = 0; jj < 2; ++jj) { b1[0][jj] = ld8(pB0, 16384 + 2048 + jj * 1024); b1[1][jj] = ld8(pB1, 16384 + 2048 + jj * 1024); }
        stage_half(1, 0, (tO + 2) & 7); stage_half(1, 1, (tO + 2) & 7);
        PH_BAR(); PH_LGKM();
        __builtin_amdgcn_s_setprio(1);
#pragma unroll
        for (int kk = 0; kk < 2; ++kk)
#pragma unroll
            for (int i = 0; i < 4; ++i)
#pragma unroll
                for (int jj = 0; jj < 2; ++jj) {
                    acc[i][2 + jj]     = __builtin_amdgcn_mfma_f32_16x16x32_bf16(a0[kk][i], b1[kk][jj], acc[i][2 + jj], 0, 0, 0);
                    acc[4 + i][2 + jj] = __builtin_amdgcn_mfma_f32_16x16x32_bf16(a1[kk][i], b1[kk][jj], acc[4 + i][2 + jj], 0, 0, 0);
                }
        __builtin_amdgcn_s_setprio(0);
        PH_VM4();
        PH_BAR();
    }

    // Epilogue: per n-column top-2 over this wave's 128 k's (= one window)
    const int q4 = (lane >> 4) * 4;
    float v1[4], v2[4];
    int   k1[4], k2[4];
#pragma unroll
    for (int in = 0; in < 4; ++in) { v1[in] = 1e30f; v2[in] = 1e30f; k1[in] = 0; k2[in] = 0; }

#pragma unroll
    for (int ik = 0; ik < 8; ++ik) {
        float qv[4];
#pragma unroll
        for (int r = 0; r < 4; ++r)
            qv[r] = qn[k0 + wk * 128 + ik * 16 + q4 + r];
#pragma unroll
        for (int in = 0; in < 4; ++in) {
#pragma unroll
            for (int r = 0; r < 4; ++r) {
                const float val = qv[r] - 2.0f * acc[ik][in][r];
                const int   kg  = k0 + wk * 128 + ik * 16 + q4 + r;
                if (val < v1[in]) { v2[in] = v1[in]; k2[in] = k1[in]; v1[in] = val; k1[in] = kg; }
                else if (val < v2[in]) { v2[in] = val; k2[in] = kg; }
            }
        }
    }
#pragma unroll
    for (int m = 16; m <= 32; m <<= 1) {
#pragma unroll
        for (int in = 0; in < 4; ++in) {
            const float ov1 = __shfl_xor(v1[in], m, 64);
            const int   ok1 = __shfl_xor(k1[in], m, 64);
            const float ov2 = __shfl_xor(v2[in], m, 64);
            const int   ok2 = __shfl_xor(k2[in], m, 64);
            float nv1, nv2; int nk1, nk2;
            if (ov1 < v1[in]) {
                nv1 = ov1; nk1 = ok1;
                if (v1[in] < ov2) { nv2 = v1[in]; nk2 = k1[in]; } else { nv2 = ov2; nk2 = ok2; }
            } else {
                nv1 = v1[in]; nk1 = k1[in];
                if (ov1 < v2[in]) { nv2 = ov1; nk2 = ok1; } else { nv2 = v2[in]; nk2 = k2[in]; }
            }
            v1[in] = nv1; k1[in] = nk1; v2[in] = nv2; k2[in] = nk2;
        }
    }
    if ((lane >> 4) == 0) {
        const int w = blockIdx.y * 2 + wk;
#pragma unroll
        for (int in = 0; in < 4; ++in) {
            const int n = n0 + wn * 64 + in * 16 + (lane & 15);
            float4 o; o.x = v1[in]; o.y = __int_as_float(k1[in]);
            o.z = v2[in]; o.w = __int_as_float(k2[in]);
            *(float4*)&wtop[((size_t)n * 64 + w) * 4] = o;   // transposed [n][w]
        }
    }
}

// ---------------------------------------------------------------------------
// Phase BC (fused): per row, build candidate set from wtop[n][w] (coalesced:
// lane w reads window w), then exact recheck. Candidate order is irrelevant
// (exact min with tie->lower k is order-independent); uncapped list is a
// strict superset of the old cap-16 -> identical final indices.
// FMA chain bit-identical to round 2.
// ---------------------------------------------------------------------------
__global__ __launch_bounds__(256) void phaseBC(const float* __restrict__ zf,
                                               const float* __restrict__ qc,
                                               const float* __restrict__ zn,
                                               const float* __restrict__ qn,
                                               const float* __restrict__ wtop,
                                               int* __restrict__ idxf,
                                               float* __restrict__ out_idx,
                                               float* __restrict__ loss_acc) {
    __shared__ float zr[4][512];
    __shared__ float ql[4][2][512];
    __shared__ int   clist[4][128];
    const int wv   = threadIdx.x >> 6;
    const int lane = threadIdx.x & 63;
    const int r    = blockIdx.x * 4 + wv;
    if (blockIdx.x == 0 && threadIdx.x == 0) loss_acc[0] = 0.f;

    // lane = window index; coalesced 16B reads
    float4 e = *(const float4*)&wtop[((size_t)r * 64 + lane) * 4];
    float rmin = e.x;
#pragma unroll
    for (int m = 1; m <= 32; m <<= 1) rmin = fminf(rmin, __shfl_xor(rmin, m, 64));
    const float thr = rmin + EPS_;
    const bool h1 = (e.x <= thr), h2 = (e.z <= thr);
    const ulong64 m1 = __ballot(h1);
    const ulong64 m2 = __ballot(h2);
    const int c1  = __popcll(m1);
    const int cnt = c1 + __popcll(m2);

    if (cnt == 1) {
        // exactly one candidate somewhere; its owning lane writes
        if (h1) { const int k = __float_as_int(e.y); idxf[r] = k; out_idx[r] = (float)k; }
        else if (h2) { const int k = __float_as_int(e.w); idxf[r] = k; out_idx[r] = (float)k; }
        return;
    }

    const ulong64 below = (lane == 63) ? ~0ull >> 1 : ((1ull << lane) - 1);
    if (h1) clist[wv][__popcll(m1 & below)] = __float_as_int(e.y);
    if (h2) clist[wv][c1 + __popcll(m2 & below)] = __float_as_int(e.w);

    // stage z row
    *(float4*)&zr[wv][lane * 8]     = *(const float4*)&zf[(size_t)r * 512 + lane * 8];
    *(float4*)&zr[wv][lane * 8 + 4] = *(const float4*)&zf[(size_t)r * 512 + lane * 8 + 4];
    asm volatile("s_waitcnt lgkmcnt(0)" ::: "memory");   // clist + zr visible wave-wide

    const int g  = lane >> 5;
    const int cl = (lane & 31) * 16;
    const int steps = (cnt + 1) >> 1;
    const float znr = zn[r];

    auto cand_of = [&](int s) {
        const int ci = 2 * s + g;
        return clist[wv][ci < cnt ? ci : 0];
    };

    int k_cur = cand_of(0);
    const float* q0 = qc + (size_t)k_cur * 512 + cl;
    float4 p0 = *(const float4*)&q0[0];
    float4 p1 = *(const float4*)&q0[4];
    float4 p2 = *(const float4*)&q0[8];
    float4 p3 = *(const float4*)&q0[12];

    float bd = 1e30f;
    int   bi = 0x7fffffff;

    for (int s = 0; s < steps; ++s) {
        *(float4*)&ql[wv][g][cl + 0]  = p0;
        *(float4*)&ql[wv][g][cl + 4]  = p1;
        *(float4*)&ql[wv][g][cl + 8]  = p2;
        *(float4*)&ql[wv][g][cl + 12] = p3;

        int k_next = 0;
        if (s + 1 < steps) {
            k_next = cand_of(s + 1);
            const float* qn_ = qc + (size_t)k_next * 512 + cl;
            p0 = *(const float4*)&qn_[0];
            p1 = *(const float4*)&qn_[4];
            p2 = *(const float4*)&qn_[8];
            p3 = *(const float4*)&qn_[12];
        }

        float acc = 0.f;
#pragma unroll 16
        for (int c = 0; c < 512; c += 4) {
            float4 zv = *(const float4*)&zr[wv][c];
            float4 qv = *(const float4*)&ql[wv][g][c];
            acc = fmaf(zv.x, qv.x, acc);
            acc = fmaf(zv.y, qv.y, acc);
            acc = fmaf(zv.z, qv.z, acc);
            acc = fmaf(zv.w, qv.w, acc);
        }
        const float T = znr + qn[k_cur];
        const float d = T - 2.0f * acc;
        const bool valid = (2 * s + g) < cnt;
        if (valid && (d < bd || (d == bd && k_cur < bi))) { bd = d; bi = k_cur; }
        k_cur = k_next;
    }

    const float od = __shfl_xor(bd, 32, 64);
    const int   oi = __shfl_xor(bi, 32, 64);
    if (od < bd || (od == bd && oi < bi)) { bd = od; bi = oi; }

    if (lane == 0) { idxf[r] = bi; out_idx[r] = (float)bi; }
}

// ---------------------------------------------------------------------------
// Gather z_q = qc[idx], transpose-write to [B,C,H,W], fused loss.
// ---------------------------------------------------------------------------
__global__ __launch_bounds__(256) void gather_out(const float* __restrict__ z,
                                                  const float* __restrict__ qc,
                                                  const int* __restrict__ idxf,
                                                  float* __restrict__ zq_out,
                                                  float* __restrict__ loss_acc) {
    __shared__ int   idxs[64];
    __shared__ float zqs[64][65];
    __shared__ float wsum[4];
    const int t  = threadIdx.x;
    const int mc = blockIdx.x;
    const int cc = blockIdx.y;
    const int bz = blockIdx.z;

    if (t < 64) idxs[t] = idxf[bz * 1024 + mc * 64 + t];
    __syncthreads();
    {
        const int row  = t >> 2;
        const int coff = (t & 3) * 16;
        const float* src = qc + (size_t)idxs[row] * 512 + cc * 64 + coff;
#pragma unroll
        for (int v = 0; v < 4; ++v) {
            float4 q = *(const float4*)&src[v * 4];
            zqs[row][coff + v * 4 + 0] = q.x;
            zqs[row][coff + v * 4 + 1] = q.y;
            zqs[row][coff + v * 4 + 2] = q.z;
            zqs[row][coff + v * 4 + 3] = q.w;
        }
    }
    __syncthreads();

    float ls = 0.f;
    {
        const int c_local = t >> 2;
        const int mg      = (t & 3) * 16;
        const size_t gbase = ((size_t)(bz * 512 + cc * 64 + c_local)) * 1024 + mc * 64 + mg;
#pragma unroll
        for (int v = 0; v < 4; ++v) {
            const int m = mg + v * 4;
            float4 w;
            w.x = zqs[m + 0][c_local];
            w.y = zqs[m + 1][c_local];
            w.z = zqs[m + 2][c_local];
            w.w = zqs[m + 3][c_local];
            float4 zv = *(const float4*)&z[gbase + v * 4];
            float dx = w.x - zv.x, dy = w.y - zv.y, dz = w.z - zv.z, dw = w.w - zv.w;
            ls += dx * dx + dy * dy + dz * dz + dw * dw;
            *(float4*)&zq_out[gbase + v * 4] = w;
        }
    }
#pragma unroll
    for (int m = 32; m; m >>= 1) ls += __shfl_xor(ls, m, 64);
    const int lane = t & 63, wvv = t >> 6;
    if (lane == 0) wsum[wvv] = ls;
    __syncthreads();
    if (t == 0) atomicAdd(loss_acc, wsum[0] + wsum[1] + wsum[2] + wsum[3]);
}

__global__ void finalize(const float* __restrict__ loss_acc,
                         float* __restrict__ out_loss) {
    out_loss[0] = 1.25f * loss_acc[0] / 8388608.0f;
}

// ---------------------------------------------------------------------------
extern "C" void kernel_launch(void* const* d_in, const int* in_sizes, int n_in,
                              void* d_out, int out_size, void* d_ws, size_t ws_size,
                              hipStream_t stream) {
    const float* z    = (const float*)d_in[0];
    const float* emb  = (const float*)d_in[1];
    const float* W    = (const float*)d_in[2];
    const float* bias = (const float*)d_in[3];
    float* ws = (float*)d_ws;

    float*  qc       = ws + QC_OFF;
    float*  qn       = ws + QN_OFF;
    float*  zn       = ws + ZN_OFF;
    float*  zf       = ws + ZF_OFF;
    ushort* zh       = (ushort*)(ws + ZH_OFF);
    ushort* qh       = (ushort*)(ws + QH_OFF);
    float*  wtop     = ws + WT_OFF;
    int*    idxf     = (int*)(ws + IDXF_OFF);
    float*  loss_acc = ws + LOSS_OFF;
    float*  out      = (float*)d_out;

    transpose_z<<<dim3(16, 8, 16), 256, 0, stream>>>(z, zf, zh);
    qc_gemm<<<dim3(K_ / 128, C_ / 64), 256, 0, stream>>>(emb, W, bias, qc, qh);
    qnorm_grouped<<<K_ / 32, 256, 0, stream>>>(qc, qn);
    znorm_pairwise<<<N_ / 256, 256, 0, stream>>>(z, zn);
    phaseA<<<dim3(N_ / 256, K_ / 256), 512, 0, stream>>>(qh, zh, qn, wtop);
    phaseBC<<<N_ / 4, 256, 0, stream>>>(zf, qc, zn, qn, wtop, idxf, out + OUT_IDX, loss_acc);
    gather_out<<<dim3(16, 8, B_), 256, 0, stream>>>(z, qc, idxf, out + OUT_ZQ, loss_acc);
    finalize<<<1, 1, 0, stream>>>(loss_acc, out + OUT_LOSS);
}